// Round 9
// baseline (194.943 us; speedup 1.0000x reference)
//
#include <hip/hip_runtime.h>
#include <hip/hip_bf16.h>
#include <cmath>

typedef __attribute__((ext_vector_type(8))) short bf16x8;
typedef __attribute__((ext_vector_type(4))) float f32x4;
typedef __attribute__((ext_vector_type(4))) short short4v;

#define MFMA16(a,b,c) __builtin_amdgcn_mfma_f32_16x16x32_bf16((a),(b),(c),0,0,0)
#define EXP2F(x) __builtin_amdgcn_exp2f(x)

__device__ __forceinline__ short f2bf(float x){
  unsigned u = __float_as_uint(x);
  u += 0x7fffu + ((u >> 16) & 1u);          // RNE
  return (short)(u >> 16);
}
__device__ __forceinline__ float bf2f(short h){
  return __uint_as_float(((unsigned)(unsigned short)h) << 16);
}
// 16B-chunk XOR swizzle within a [rows][64-short] tile; unit = 8 shorts
__device__ __forceinline__ int swz(int row, int c){ return (row << 3) | (c ^ (row & 7)); }

// ---------------- split kernels ----------------
__global__ void split_mat(const float* __restrict__ src, short* __restrict__ hi,
                          short* __restrict__ lo, int n){
  int i = blockIdx.x * 256 + threadIdx.x;
  if(i >= n) return;
  float x = src[i];
  short h = f2bf(x);
  hi[i] = h;
  if(lo) lo[i] = f2bf(x - bf2f(h));
}

// q,k,v -> hi/lo (v: hi only), one dispatch, float4-vectorized
__global__ void split3(const float* __restrict__ q, const float* __restrict__ k,
                       const float* __restrict__ v,
                       short* __restrict__ q_hi, short* __restrict__ q_lo,
                       short* __restrict__ k_hi, short* __restrict__ k_lo,
                       short* __restrict__ v_hi){
  int y = blockIdx.y;
  int i4 = (blockIdx.x * 256 + threadIdx.x) * 4;
  if(y == 0){
    float4 x = *(const float4*)(q + i4);
    short4v hi, lo;
    float xs[4] = {x.x, x.y, x.z, x.w};
    #pragma unroll
    for(int r=0;r<4;r++){ short h = f2bf(xs[r]); hi[r]=h; lo[r]=f2bf(xs[r]-bf2f(h)); }
    *(short4v*)(q_hi + i4) = hi; *(short4v*)(q_lo + i4) = lo;
  } else if(y == 1){
    float4 x = *(const float4*)(k + i4);
    short4v hi, lo;
    float xs[4] = {x.x, x.y, x.z, x.w};
    #pragma unroll
    for(int r=0;r<4;r++){ short h = f2bf(xs[r]); hi[r]=h; lo[r]=f2bf(xs[r]-bf2f(h)); }
    *(short4v*)(k_hi + i4) = hi; *(short4v*)(k_lo + i4) = lo;
  } else {
    float4 x = *(const float4*)(v + i4);
    short4v hi;
    float xs[4] = {x.x, x.y, x.z, x.w};
    #pragma unroll
    for(int r=0;r<4;r++) hi[r] = f2bf(xs[r]);
    *(short4v*)(v_hi + i4) = hi;
  }
}

// proj [8][512][64] -> BT [512][512], BT[h*64+c][d] = proj[h][d][c]; 3 projections fused
__global__ void split_proj3(const float* __restrict__ qp, const float* __restrict__ kp,
                            const float* __restrict__ vp,
                            short* __restrict__ BqHi, short* __restrict__ BqLo,
                            short* __restrict__ BkHi, short* __restrict__ BkLo,
                            short* __restrict__ BvHi){
  int y = blockIdx.y;
  int i = blockIdx.x * 256 + threadIdx.x;   // i = n*512 + d
  int n = i >> 9, d = i & 511;
  int h = n >> 6, c = n & 63;
  long si = (long)((h << 15) | (d << 6) | c);
  if(y == 0){
    float x = qp[si]; short hh = f2bf(x);
    BqHi[i] = hh; BqLo[i] = f2bf(x - bf2f(hh));
  } else if(y == 1){
    float x = kp[si]; short hh = f2bf(x);
    BkHi[i] = hh; BkLo[i] = f2bf(x - bf2f(hh));
  } else {
    BvHi[i] = f2bf(vp[si]);
  }
}

// ---------------- fused projection GEMM (q,k,v in one dispatch via z) ----------------
// C[4096x512] = A[4096x512] * BT[512x512]^T
// z=0: q (3-prod, hi/lo out, scale 0.125*log2e); z=1: k (3-prod, hi/lo out); z=2: v (1-prod, vt out)
__global__ __launch_bounds__(256) void gemm_qkv(
    const short* __restrict__ q_hi, const short* __restrict__ q_lo,
    const short* __restrict__ k_hi, const short* __restrict__ k_lo,
    const short* __restrict__ v_hi,
    const short* __restrict__ BqHi, const short* __restrict__ BqLo,
    const short* __restrict__ BkHi, const short* __restrict__ BkLo,
    const short* __restrict__ BvHi,
    short* __restrict__ qhHi, short* __restrict__ qhLo,
    short* __restrict__ khHi, short* __restrict__ khLo,
    short* __restrict__ vt)
{
  constexpr int K = 512;
  __shared__ __attribute__((aligned(16))) short sAhi[128*64];
  __shared__ __attribute__((aligned(16))) short sBhi[64*64];
  __shared__ __attribute__((aligned(16))) short sAlo[128*64];
  __shared__ __attribute__((aligned(16))) short sBlo[64*64];
  const int tid = threadIdx.x;
  const int z = blockIdx.z;
  const bool three = (z < 2);
  const short* Ahi = z==0 ? q_hi : z==1 ? k_hi : v_hi;
  const short* Alo = z==0 ? q_lo : k_lo;
  const short* Bhi = z==0 ? BqHi : z==1 ? BkHi : BvHi;
  const short* Blo = z==0 ? BqLo : BkLo;
  const float scale = z==0 ? 0.125f*1.44269504f : 1.f;   // fold log2(e) -> exp2 softmax domain
  const int m0 = blockIdx.x * 128, n0 = blockIdx.y * 64;
  const int w = tid >> 6, lane = tid & 63;
  const int wm = (w >> 1) * 64, wn = (w & 1) * 32;
  const int lr = lane & 15, lg = lane >> 4;

  f32x4 acc[4][2];
  for(int i=0;i<4;i++) for(int j=0;j<2;j++) acc[i][j] = f32x4{0.f,0.f,0.f,0.f};

  for(int kt = 0; kt < K; kt += 64){
    __syncthreads();
    for(int u = tid; u < 1024; u += 256){
      int row = u >> 3, c = u & 7;
      long ga = (long)(m0 + row) * K + kt + c*8;
      *(bf16x8*)(sAhi + swz(row,c)*8) = *(const bf16x8*)(Ahi + ga);
      if(three)
        *(bf16x8*)(sAlo + swz(row,c)*8) = *(const bf16x8*)(Alo + ga);
    }
    for(int u = tid; u < 512; u += 256){
      int row = u >> 3, c = u & 7;
      long ga = (long)(n0 + row) * K + kt + c*8;
      *(bf16x8*)(sBhi + swz(row,c)*8) = *(const bf16x8*)(Bhi + ga);
      if(three)
        *(bf16x8*)(sBlo + swz(row,c)*8) = *(const bf16x8*)(Blo + ga);
    }
    __syncthreads();
    #pragma unroll
    for(int ks = 0; ks < 2; ks++){
      bf16x8 ah[4], al[4], bh[2], bl[2];
      #pragma unroll
      for(int i=0;i<4;i++){
        int row = wm + i*16 + lr, c = ks*4 + lg;
        ah[i] = *(const bf16x8*)(sAhi + swz(row,c)*8);
        if(three) al[i] = *(const bf16x8*)(sAlo + swz(row,c)*8);
      }
      #pragma unroll
      for(int j=0;j<2;j++){
        int row = wn + j*16 + lr, c = ks*4 + lg;
        bh[j] = *(const bf16x8*)(sBhi + swz(row,c)*8);
        if(three) bl[j] = *(const bf16x8*)(sBlo + swz(row,c)*8);
      }
      #pragma unroll
      for(int i=0;i<4;i++)
        #pragma unroll
        for(int j=0;j<2;j++){
          acc[i][j] = MFMA16(ah[i], bh[j], acc[i][j]);
          if(three){
            acc[i][j] = MFMA16(ah[i], bl[j], acc[i][j]);
            acc[i][j] = MFMA16(al[i], bh[j], acc[i][j]);
          }
        }
    }
  }
  // epilogue
  #pragma unroll
  for(int i=0;i<4;i++){
    #pragma unroll
    for(int j=0;j<2;j++){
      int row = m0 + wm + i*16 + lg*4;
      int col = n0 + wn + j*16 + lr;
      if(z == 2){
        int bb = row >> 11;
        int hh = col >> 6, cc = col & 63;
        short4v pk;
        #pragma unroll
        for(int r=0;r<4;r++) pk[r] = f2bf(acc[i][j][r]);
        long idx = ((long)((bb*8 + hh)*64 + cc) << 11) + (row & 2047);
        *(short4v*)(vt + idx) = pk;
      } else {
        short* O0 = z==0 ? qhHi : khHi;
        short* O1 = z==0 ? qhLo : khLo;
        #pragma unroll
        for(int r=0;r<4;r++){
          float v = acc[i][j][r] * scale;
          long idx = (long)(row + r) * 512 + col;
          short hh = f2bf(v);
          O0[idx] = hh;
          O1[idx] = f2bf(v - bf2f(hh));
        }
      }
    }
  }
}

// ---------------- GEMM template (used for the final GEMM) ----------------
template<int NPROD, int EPI>
__global__ __launch_bounds__(256) void gemm_k(
    const short* __restrict__ Ahi, const short* __restrict__ Alo,
    const short* __restrict__ Bhi, const short* __restrict__ Blo,
    short* __restrict__ O0, short* __restrict__ O1,
    float* __restrict__ Of, const float* __restrict__ bias, float scale)
{
  constexpr int K = 512;
  __shared__ __attribute__((aligned(16))) short sAhi[128*64];
  __shared__ __attribute__((aligned(16))) short sBhi[64*64];
  __shared__ __attribute__((aligned(16))) short sAlo[NPROD==3 ? 128*64 : 8];
  __shared__ __attribute__((aligned(16))) short sBlo[NPROD==3 ? 64*64 : 8];
  const int tid = threadIdx.x;
  const int m0 = blockIdx.x * 128, n0 = blockIdx.y * 64;
  const int w = tid >> 6, lane = tid & 63;
  const int wm = (w >> 1) * 64, wn = (w & 1) * 32;
  const int lr = lane & 15, lg = lane >> 4;

  f32x4 acc[4][2];
  for(int i=0;i<4;i++) for(int j=0;j<2;j++) acc[i][j] = f32x4{0.f,0.f,0.f,0.f};

  for(int kt = 0; kt < K; kt += 64){
    __syncthreads();
    for(int u = tid; u < 1024; u += 256){
      int row = u >> 3, c = u & 7;
      long ga = (long)(m0 + row) * K + kt + c*8;
      *(bf16x8*)(sAhi + swz(row,c)*8) = *(const bf16x8*)(Ahi + ga);
      if(NPROD == 3)
        *(bf16x8*)(sAlo + swz(row,c)*8) = *(const bf16x8*)(Alo + ga);
    }
    for(int u = tid; u < 512; u += 256){
      int row = u >> 3, c = u & 7;
      long ga = (long)(n0 + row) * K + kt + c*8;
      *(bf16x8*)(sBhi + swz(row,c)*8) = *(const bf16x8*)(Bhi + ga);
      if(NPROD == 3)
        *(bf16x8*)(sBlo + swz(row,c)*8) = *(const bf16x8*)(Blo + ga);
    }
    __syncthreads();
    #pragma unroll
    for(int ks = 0; ks < 2; ks++){
      bf16x8 ah[4], al[4], bh[2], bl[2];
      #pragma unroll
      for(int i=0;i<4;i++){
        int row = wm + i*16 + lr, c = ks*4 + lg;
        ah[i] = *(const bf16x8*)(sAhi + swz(row,c)*8);
        if(NPROD==3) al[i] = *(const bf16x8*)(sAlo + swz(row,c)*8);
      }
      #pragma unroll
      for(int j=0;j<2;j++){
        int row = wn + j*16 + lr, c = ks*4 + lg;
        bh[j] = *(const bf16x8*)(sBhi + swz(row,c)*8);
        if(NPROD==3) bl[j] = *(const bf16x8*)(sBlo + swz(row,c)*8);
      }
      #pragma unroll
      for(int i=0;i<4;i++)
        #pragma unroll
        for(int j=0;j<2;j++){
          acc[i][j] = MFMA16(ah[i], bh[j], acc[i][j]);
          if(NPROD==3){
            acc[i][j] = MFMA16(ah[i], bl[j], acc[i][j]);
            acc[i][j] = MFMA16(al[i], bh[j], acc[i][j]);
          }
        }
    }
  }
  #pragma unroll
  for(int i=0;i<4;i++){
    #pragma unroll
    for(int j=0;j<2;j++){
      int row = m0 + wm + i*16 + lg*4;
      int col = n0 + wn + j*16 + lr;
      if(EPI == 1){
        int bb = row >> 11;
        int hh = col >> 6, cc = col & 63;
        short4v pk;
        #pragma unroll
        for(int r=0;r<4;r++) pk[r] = f2bf(acc[i][j][r] * scale);
        long idx = ((long)((bb*8 + hh)*64 + cc) << 11) + (row & 2047);
        *(short4v*)(O0 + idx) = pk;
      } else {
        #pragma unroll
        for(int r=0;r<4;r++){
          float v = acc[i][j][r] * scale;
          long idx = (long)(row + r) * 512 + col;
          if(EPI == 0){
            short hh = f2bf(v);
            O0[idx] = hh;
            O1[idx] = f2bf(v - bf2f(hh));
          } else {
            Of[idx] = v + bias[col];
          }
        }
      }
    }
  }
}

// ---------------- fused attention (r8 skeleton; KVBLK=128) ----------------
struct SpreadArgs { float sig2[8]; float nine[8]; float inv2[8]; };

__global__ __launch_bounds__(256) void attn_k(
    const short* __restrict__ qhHi, const short* __restrict__ qhLo,
    const short* __restrict__ khHi, const short* __restrict__ khLo,
    const short* __restrict__ vt,
    const float* __restrict__ coords,
    const unsigned char* __restrict__ kpm,
    short* __restrict__ Xhi, short* __restrict__ Xlo,
    SpreadArgs sa)
{
  __shared__ __attribute__((aligned(16))) short sKhi[128*64];
  __shared__ __attribute__((aligned(16))) short sKlo[128*64];
  __shared__ __attribute__((aligned(16))) short sV[2*64*64];   // two [64][64] j-subtiles
  __shared__ float sCj[128][4];
  __shared__ float sM[128];
  __shared__ __attribute__((aligned(16))) short sP[4][16][136]; // per-wave P tile (128 wide), padded

  const int tid = threadIdx.x, w = tid >> 6, lane = tid & 63;
  const int lr = lane & 15, lg = lane >> 4;
  // XCD-locality swizzle (index-only): each XCD owns 2 (b,h) pairs, 32 i-blocks each.
  const int L = blockIdx.x;
  const int xcd = L & 7, ix = L >> 3;          // ix in [0,64)
  const int pair = xcd*2 + (ix >> 5);          // [0,16)
  const int b = pair >> 3, h = pair & 7, i0 = (ix & 31) * 64;
  const float sig2 = sa.sig2[h], nine = sa.nine[h], inv2 = sa.inv2[h];
  // constant RBF factors for the (dominant) d2<=sig2 regime — bit-identical to slow path
  const float argc = sig2 * inv2;
  const float E0 = __expf(-argc), E1 = __expf(argc);
  bf16x8 ones8;
  #pragma unroll
  for(int i=0;i<8;i++) ones8[i] = (short)0x3F80;   // bf16 1.0

  // Q fragments resident in registers (A-frag: row = lane&15, k = (lane>>4)*8)
  long qrow = (long)(b*2048 + i0 + w*16 + lr) * 512 + h*64;
  bf16x8 qhi[2], qlo[2];
  #pragma unroll
  for(int ks=0; ks<2; ks++){
    qhi[ks] = *(const bf16x8*)(qhHi + qrow + ks*32 + lg*8);
    qlo[ks] = *(const bf16x8*)(qhLo + qrow + ks*32 + lg*8);
  }
  // coords of this lane's 4 C-rows + their squared norms
  float ci[4][3], ni[4];
  {
    int r0 = b*2048 + i0 + w*16 + lg*4;
    #pragma unroll
    for(int r=0;r<4;r++){
      ci[r][0] = coords[(long)(r0+r)*3 + 0];
      ci[r][1] = coords[(long)(r0+r)*3 + 1];
      ci[r][2] = coords[(long)(r0+r)*3 + 2];
      ni[r] = ci[r][0]*ci[r][0] + ci[r][1]*ci[r][1] + ci[r][2]*ci[r][2];
    }
  }
  f32x4 oacc[4];
  for(int c=0;c<4;c++) oacc[c] = f32x4{0.f,0.f,0.f,0.f};
  float m[4], l[4];
  for(int r=0;r<4;r++){ m[r] = -1e30f; l[r] = 0.f; }

  for(int jt=0; jt<16; jt++){
    int j0 = jt*128;
    // stage K (128 rows x 64) hi/lo
    for(int u=tid; u<1024; u+=256){
      int row = u>>3, cc = u&7;
      long gk = (long)(b*2048 + j0 + row)*512 + h*64 + cc*8;
      *(bf16x8*)(sKhi + swz(row,cc)*8) = *(const bf16x8*)(khHi + gk);
      *(bf16x8*)(sKlo + swz(row,cc)*8) = *(const bf16x8*)(khLo + gk);
    }
    // stage V^T (64 c-rows x 128 j) as two [64][64] subtiles
    for(int u=tid; u<1024; u+=256){
      int sub = u>>9, row = (u>>3)&63, cc = u&7;
      long gv = ((long)((b*8+h)*64 + row) << 11) + j0 + sub*64 + cc*8;
      *(bf16x8*)(sV + sub*4096 + swz(row,cc)*8) = *(const bf16x8*)(vt + gv);
    }
    if(tid < 128){
      long cb = (long)(b*2048 + j0 + tid)*3;
      float cx = coords[cb], cy = coords[cb+1], cz = coords[cb+2];
      sCj[tid][0] = cx; sCj[tid][1] = cy; sCj[tid][2] = cz;
      sCj[tid][3] = cx*cx + cy*cy + cz*cz;
      sM[tid] = kpm[b*2048 + j0 + tid] ? 1.f : 0.f;
    }
    __syncthreads();

    // S2 = (QK^T)/8*log2e, 3-product hi/lo split (scales folded into qh)
    f32x4 s[8];
    #pragma unroll
    for(int jf=0;jf<8;jf++){
      f32x4 t = f32x4{0.f,0.f,0.f,0.f};
      #pragma unroll
      for(int ks=0;ks<2;ks++){
        int row = jf*16 + lr, c = ks*4 + lg;
        bf16x8 bh = *(const bf16x8*)(sKhi + swz(row,c)*8);
        bf16x8 bl = *(const bf16x8*)(sKlo + swz(row,c)*8);
        t = MFMA16(qhi[ks], bh, t);
        t = MFMA16(qhi[ks], bl, t);
        t = MFMA16(qlo[ks], bh, t);
      }
      s[jf] = t;
    }
    // RBF modulation + mask in two 4-jf half-passes (keeps register arrays small)
    #pragma unroll
    for(int hp=0; hp<2; hp++){
      float d2a[4][4], kmv[4];
      int ok = 1;
      #pragma unroll
      for(int jq=0;jq<4;jq++){
        int jf = hp*4 + jq;
        int j = jf*16 + lr;
        float cjx = sCj[j][0], cjy = sCj[j][1], cjz = sCj[j][2], nj = sCj[j][3];
        kmv[jq] = sM[j];
        ok &= (kmv[jq] == 0.f);
        #pragma unroll
        for(int r=0;r<4;r++){
          float dot = ci[r][0]*cjx + ci[r][1]*cjy + ci[r][2]*cjz;
          float d2 = fmaf(-2.f, dot, ni[r] + nj);
          d2a[jq][r] = d2;
          ok &= (d2 <= sig2);
        }
      }
      if(__all(ok)){
        #pragma unroll
        for(int jq=0;jq<4;jq++){
          int jf = hp*4 + jq;
          #pragma unroll
          for(int r=0;r<4;r++){
            float sv = s[jf][r];
            s[jf][r] = sv * (sv < 0.f ? E1 : E0);
          }
        }
      } else {
        #pragma unroll
        for(int jq=0;jq<4;jq++){
          int jf = hp*4 + jq;
          float km = kmv[jq];
          #pragma unroll
          for(int r=0;r<4;r++){
            float d2 = d2a[jq][r];
            float tt = fminf(fmaxf(d2, sig2), nine);
            float arg = tt * inv2;
            float sv = s[jf][r];
            sv *= __expf(sv < 0.f ? arg : -arg);
            if(d2 > nine || km != 0.f) sv = -1e30f;
            s[jf][r] = sv;
          }
        }
      }
    }
    // online softmax in exp2 domain (logits pre-scaled by log2e)
    float pm[4];
    #pragma unroll
    for(int r=0;r<4;r++){
      float a0 = fmaxf(fmaxf(s[0][r], s[1][r]), fmaxf(s[2][r], s[3][r]));
      float a1 = fmaxf(fmaxf(s[4][r], s[5][r]), fmaxf(s[6][r], s[7][r]));
      pm[r] = fmaxf(a0, a1);
    }
    #pragma unroll
    for(int d=1; d<16; d<<=1){
      #pragma unroll
      for(int r=0;r<4;r++) pm[r] = fmaxf(pm[r], __shfl_xor(pm[r], d));
    }
    float fr[4];
    #pragma unroll
    for(int r=0;r<4;r++){
      float mn = fmaxf(m[r], pm[r]);
      fr[r] = EXP2F(m[r] - mn);
      m[r] = mn;
      l[r] *= fr[r];
    }
    #pragma unroll
    for(int jf=0;jf<8;jf++)
      #pragma unroll
      for(int r=0;r<4;r++)
        s[jf][r] = EXP2F(s[jf][r] - m[r]);
    #pragma unroll
    for(int c=0;c<4;c++)
      #pragma unroll
      for(int r=0;r<4;r++) oacc[c][r] *= fr[r];
    // P -> per-wave LDS (C-layout write, A-layout read; same-wave so no barrier)
    #pragma unroll
    for(int jf=0;jf<8;jf++)
      #pragma unroll
      for(int r=0;r<4;r++)
        sP[w][lg*4 + r][jf*16 + lr] = f2bf(s[jf][r]);
    // PV + row-sum of P via a spare MFMA against an all-ones B fragment
    f32x4 psacc = f32x4{0.f,0.f,0.f,0.f};
    #pragma unroll
    for(int js=0;js<4;js++){
      union { bf16x8 v8; short4v h4[2]; } pa;
      pa.h4[0] = *(const short4v*)(&sP[w][lr][js*32 + lg*8]);
      pa.h4[1] = *(const short4v*)(&sP[w][lr][js*32 + lg*8 + 4]);
      const int sub = js >> 1, vcs = (js & 1)*4 + lg;
      #pragma unroll
      for(int cf=0; cf<4; cf++){
        int vrow = cf*16 + lr;
        bf16x8 vb = *(const bf16x8*)(sV + sub*4096 + swz(vrow,vcs)*8);
        oacc[cf] = MFMA16(pa.v8, vb, oacc[cf]);
      }
      psacc = MFMA16(pa.v8, ones8, psacc);
    }
    #pragma unroll
    for(int r=0;r<4;r++) l[r] += psacc[r];
    __syncthreads();
  }
  // epilogue: X[b*2048+i][h*64+c] as hi/lo split for the final GEMM
  #pragma unroll
  for(int cf=0; cf<4; cf++){
    #pragma unroll
    for(int r=0;r<4;r++){
      float v = oacc[cf][r] / l[r];
      long idx = (long)(b*2048 + i0 + w*16 + lg*4 + r)*512 + h*64 + cf*16 + lr;
      short hh = f2bf(v);
      Xhi[idx] = hh;
      Xlo[idx] = f2bf(v - bf2f(hh));
    }
  }
}

// ---------------- host ----------------
extern "C" void kernel_launch(void* const* d_in, const int* in_sizes, int n_in,
                              void* d_out, int out_size, void* d_ws, size_t ws_size,
                              hipStream_t stream){
  const float* q  = (const float*)d_in[0];
  const float* k  = (const float*)d_in[1];
  const float* v  = (const float*)d_in[2];
  const float* coords = (const float*)d_in[3];
  const unsigned char* kpm = (const unsigned char*)d_in[4];
  const float* qp = (const float*)d_in[5];
  const float* kp = (const float*)d_in[6];
  const float* vp = (const float*)d_in[7];
  const float* ow = (const float*)d_in[8];
  const float* ob = (const float*)d_in[9];
  float* out = (float*)d_out;

  char* ws = (char*)d_ws;
  const size_t S = (size_t)4096*512*2;      // one bf16 [4096][512] plane
  const size_t P = (size_t)512*512*2;       // one bf16 [512][512] plane
  if(ws_size < 12*S + 7*P) return;
  short* q_hi = (short*)(ws + 0*S);
  short* q_lo = (short*)(ws + 1*S);
  short* k_hi = (short*)(ws + 2*S);
  short* k_lo = (short*)(ws + 3*S);
  short* v_hi = (short*)(ws + 4*S);
  short* qhHi = (short*)(ws + 5*S);
  short* qhLo = (short*)(ws + 6*S);
  short* khHi = (short*)(ws + 7*S);
  short* khLo = (short*)(ws + 8*S);
  short* vt   = (short*)(ws + 9*S);
  short* Xhi  = (short*)(ws + 10*S);
  short* Xlo  = (short*)(ws + 11*S);
  char* ws2 = ws + 12*S;
  short* BqHi = (short*)(ws2 + 0*P);
  short* BqLo = (short*)(ws2 + 1*P);
  short* BkHi = (short*)(ws2 + 2*P);
  short* BkLo = (short*)(ws2 + 3*P);
  short* BvHi = (short*)(ws2 + 4*P);
  short* WHi  = (short*)(ws2 + 5*P);
  short* WLo  = (short*)(ws2 + 6*P);

  SpreadArgs sa;
  for(int hh=0; hh<8; hh++){
    double t  = (1.0 - 0.02) * (double)hh / 7.0;
    double lg = pow(20.0, t);
    double sp = 3.7 + (lg - 1.0) / 19.0 * (20.0 - 3.7);
    float spf = (float)sp;
    sa.sig2[hh] = spf*spf;
    sa.nine[hh] = 9.f*spf*spf;
    sa.inv2[hh] = 1.f/(2.f*spf*spf);
  }

  const int NQ = 4096*512;
  split3<<<dim3(NQ/1024, 3), dim3(256), 0, stream>>>(q, k, v, q_hi, q_lo, k_hi, k_lo, v_hi);
  split_mat<<<dim3(1024), dim3(256), 0, stream>>>(ow, WHi, WLo, 512*512);
  split_proj3<<<dim3(1024, 3), dim3(256), 0, stream>>>(qp, kp, vp, BqHi, BqLo, BkHi, BkLo, BvHi);

  gemm_qkv<<<dim3(32, 8, 3), dim3(256), 0, stream>>>(
      q_hi, q_lo, k_hi, k_lo, v_hi,
      BqHi, BqLo, BkHi, BkLo, BvHi,
      qhHi, qhLo, khHi, khLo, vt);

  attn_k<<<dim3(512), dim3(256), 0, stream>>>(qhHi, qhLo, khHi, khLo, vt,
        coords, kpm, Xhi, Xlo, sa);

  gemm_k<3,2><<<dim3(32, 8), dim3(256), 0, stream>>>(Xhi, Xlo, WHi, WLo,
        nullptr, nullptr, out, ob, 1.f);
}

// Round 10
// 158.285 us; speedup vs baseline: 1.2316x; 1.2316x over previous
//
#include <hip/hip_runtime.h>
#include <hip/hip_bf16.h>
#include <cmath>

typedef __attribute__((ext_vector_type(8))) short bf16x8;
typedef __attribute__((ext_vector_type(4))) float f32x4;
typedef __attribute__((ext_vector_type(4))) short short4v;

#define MFMA16(a,b,c) __builtin_amdgcn_mfma_f32_16x16x32_bf16((a),(b),(c),0,0,0)
#define EXP2F(x) __builtin_amdgcn_exp2f(x)
// async global->LDS 16B: LDS dest is lane-ordered linear; source carries the swizzle
#define GLOAD_LDS16(g, l) __builtin_amdgcn_global_load_lds( \
    (const __attribute__((address_space(1))) unsigned int*)(g), \
    (__attribute__((address_space(3))) unsigned int*)(l), 16, 0, 0)

__device__ __forceinline__ short f2bf(float x){
  unsigned u = __float_as_uint(x);
  u += 0x7fffu + ((u >> 16) & 1u);          // RNE
  return (short)(u >> 16);
}
__device__ __forceinline__ float bf2f(short h){
  return __uint_as_float(((unsigned)(unsigned short)h) << 16);
}
// 16B-chunk XOR swizzle within a [rows][64-short] tile; unit = 8 shorts
__device__ __forceinline__ int swz(int row, int c){ return (row << 3) | (c ^ (row & 7)); }

// ---------------- split kernels ----------------
__global__ void split_mat(const float* __restrict__ src, short* __restrict__ hi,
                          short* __restrict__ lo, int n){
  int i = blockIdx.x * 256 + threadIdx.x;
  if(i >= n) return;
  float x = src[i];
  short h = f2bf(x);
  hi[i] = h;
  if(lo) lo[i] = f2bf(x - bf2f(h));
}

// q,k,v -> hi/lo (v: hi only), one dispatch, float4-vectorized
__global__ void split3(const float* __restrict__ q, const float* __restrict__ k,
                       const float* __restrict__ v,
                       short* __restrict__ q_hi, short* __restrict__ q_lo,
                       short* __restrict__ k_hi, short* __restrict__ k_lo,
                       short* __restrict__ v_hi){
  int y = blockIdx.y;
  int i4 = (blockIdx.x * 256 + threadIdx.x) * 4;
  if(y == 0){
    float4 x = *(const float4*)(q + i4);
    short4v hi, lo;
    float xs[4] = {x.x, x.y, x.z, x.w};
    #pragma unroll
    for(int r=0;r<4;r++){ short h = f2bf(xs[r]); hi[r]=h; lo[r]=f2bf(xs[r]-bf2f(h)); }
    *(short4v*)(q_hi + i4) = hi; *(short4v*)(q_lo + i4) = lo;
  } else if(y == 1){
    float4 x = *(const float4*)(k + i4);
    short4v hi, lo;
    float xs[4] = {x.x, x.y, x.z, x.w};
    #pragma unroll
    for(int r=0;r<4;r++){ short h = f2bf(xs[r]); hi[r]=h; lo[r]=f2bf(xs[r]-bf2f(h)); }
    *(short4v*)(k_hi + i4) = hi; *(short4v*)(k_lo + i4) = lo;
  } else {
    float4 x = *(const float4*)(v + i4);
    short4v hi;
    float xs[4] = {x.x, x.y, x.z, x.w};
    #pragma unroll
    for(int r=0;r<4;r++) hi[r] = f2bf(xs[r]);
    *(short4v*)(v_hi + i4) = hi;
  }
}

// proj [8][512][64] -> BT [512][512], BT[h*64+c][d] = proj[h][d][c]; 3 projections fused
__global__ void split_proj3(const float* __restrict__ qp, const float* __restrict__ kp,
                            const float* __restrict__ vp,
                            short* __restrict__ BqHi, short* __restrict__ BqLo,
                            short* __restrict__ BkHi, short* __restrict__ BkLo,
                            short* __restrict__ BvHi){
  int y = blockIdx.y;
  int i = blockIdx.x * 256 + threadIdx.x;   // i = n*512 + d
  int n = i >> 9, d = i & 511;
  int h = n >> 6, c = n & 63;
  long si = (long)((h << 15) | (d << 6) | c);
  if(y == 0){
    float x = qp[si]; short hh = f2bf(x);
    BqHi[i] = hh; BqLo[i] = f2bf(x - bf2f(hh));
  } else if(y == 1){
    float x = kp[si]; short hh = f2bf(x);
    BkHi[i] = hh; BkLo[i] = f2bf(x - bf2f(hh));
  } else {
    BvHi[i] = f2bf(vp[si]);
  }
}

// ---------------- fused projection GEMM (q,k,v in one dispatch via z) ----------------
// C[4096x512] = A[4096x512] * BT[512x512]^T
// z=0: q (3-prod, hi/lo out, scale 0.125*log2e); z=1: k (3-prod, hi/lo out); z=2: v (1-prod, vt out)
__global__ __launch_bounds__(256) void gemm_qkv(
    const short* __restrict__ q_hi, const short* __restrict__ q_lo,
    const short* __restrict__ k_hi, const short* __restrict__ k_lo,
    const short* __restrict__ v_hi,
    const short* __restrict__ BqHi, const short* __restrict__ BqLo,
    const short* __restrict__ BkHi, const short* __restrict__ BkLo,
    const short* __restrict__ BvHi,
    short* __restrict__ qhHi, short* __restrict__ qhLo,
    short* __restrict__ khHi, short* __restrict__ khLo,
    short* __restrict__ vt)
{
  constexpr int K = 512;
  __shared__ __attribute__((aligned(16))) short sAhi[128*64];
  __shared__ __attribute__((aligned(16))) short sBhi[64*64];
  __shared__ __attribute__((aligned(16))) short sAlo[128*64];
  __shared__ __attribute__((aligned(16))) short sBlo[64*64];
  const int tid = threadIdx.x;
  const int z = blockIdx.z;
  const bool three = (z < 2);
  const short* Ahi = z==0 ? q_hi : z==1 ? k_hi : v_hi;
  const short* Alo = z==0 ? q_lo : k_lo;
  const short* Bhi = z==0 ? BqHi : z==1 ? BkHi : BvHi;
  const short* Blo = z==0 ? BqLo : BkLo;
  const float scale = z==0 ? 0.125f*1.44269504f : 1.f;   // fold log2(e) -> exp2 softmax domain
  const int m0 = blockIdx.x * 128, n0 = blockIdx.y * 64;
  const int w = tid >> 6, lane = tid & 63;
  const int wm = (w >> 1) * 64, wn = (w & 1) * 32;
  const int lr = lane & 15, lg = lane >> 4;

  f32x4 acc[4][2];
  for(int i=0;i<4;i++) for(int j=0;j<2;j++) acc[i][j] = f32x4{0.f,0.f,0.f,0.f};

  for(int kt = 0; kt < K; kt += 64){
    __syncthreads();
    // async staging: LDS written linearly (lane order); source column pre-swizzled
    for(int u = tid; u < 1024; u += 256){
      int row = u >> 3, c = u & 7;
      long ga = (long)(m0 + row) * K + kt + (c ^ (row & 7))*8;
      GLOAD_LDS16(Ahi + ga, sAhi + u*8);
      if(three) GLOAD_LDS16(Alo + ga, sAlo + u*8);
    }
    for(int u = tid; u < 512; u += 256){
      int row = u >> 3, c = u & 7;
      long ga = (long)(n0 + row) * K + kt + (c ^ (row & 7))*8;
      GLOAD_LDS16(Bhi + ga, sBhi + u*8);
      if(three) GLOAD_LDS16(Blo + ga, sBlo + u*8);
    }
    __syncthreads();
    #pragma unroll
    for(int ks = 0; ks < 2; ks++){
      bf16x8 ah[4], al[4], bh[2], bl[2];
      #pragma unroll
      for(int i=0;i<4;i++){
        int row = wm + i*16 + lr, c = ks*4 + lg;
        ah[i] = *(const bf16x8*)(sAhi + swz(row,c)*8);
        if(three) al[i] = *(const bf16x8*)(sAlo + swz(row,c)*8);
      }
      #pragma unroll
      for(int j=0;j<2;j++){
        int row = wn + j*16 + lr, c = ks*4 + lg;
        bh[j] = *(const bf16x8*)(sBhi + swz(row,c)*8);
        if(three) bl[j] = *(const bf16x8*)(sBlo + swz(row,c)*8);
      }
      #pragma unroll
      for(int i=0;i<4;i++)
        #pragma unroll
        for(int j=0;j<2;j++){
          acc[i][j] = MFMA16(ah[i], bh[j], acc[i][j]);
          if(three){
            acc[i][j] = MFMA16(ah[i], bl[j], acc[i][j]);
            acc[i][j] = MFMA16(al[i], bh[j], acc[i][j]);
          }
        }
    }
  }
  // epilogue
  #pragma unroll
  for(int i=0;i<4;i++){
    #pragma unroll
    for(int j=0;j<2;j++){
      int row = m0 + wm + i*16 + lg*4;
      int col = n0 + wn + j*16 + lr;
      if(z == 2){
        int bb = row >> 11;
        int hh = col >> 6, cc = col & 63;
        short4v pk;
        #pragma unroll
        for(int r=0;r<4;r++) pk[r] = f2bf(acc[i][j][r]);
        long idx = ((long)((bb*8 + hh)*64 + cc) << 11) + (row & 2047);
        *(short4v*)(vt + idx) = pk;
      } else {
        short* O0 = z==0 ? qhHi : khHi;
        short* O1 = z==0 ? qhLo : khLo;
        #pragma unroll
        for(int r=0;r<4;r++){
          float v = acc[i][j][r] * scale;
          long idx = (long)(row + r) * 512 + col;
          short hh = f2bf(v);
          O0[idx] = hh;
          O1[idx] = f2bf(v - bf2f(hh));
        }
      }
    }
  }
}

// ---------------- GEMM template (used for the final GEMM) ----------------
template<int NPROD, int EPI>
__global__ __launch_bounds__(256) void gemm_k(
    const short* __restrict__ Ahi, const short* __restrict__ Alo,
    const short* __restrict__ Bhi, const short* __restrict__ Blo,
    short* __restrict__ O0, short* __restrict__ O1,
    float* __restrict__ Of, const float* __restrict__ bias, float scale)
{
  constexpr int K = 512;
  __shared__ __attribute__((aligned(16))) short sAhi[128*64];
  __shared__ __attribute__((aligned(16))) short sBhi[64*64];
  __shared__ __attribute__((aligned(16))) short sAlo[NPROD==3 ? 128*64 : 8];
  __shared__ __attribute__((aligned(16))) short sBlo[NPROD==3 ? 64*64 : 8];
  const int tid = threadIdx.x;
  const int m0 = blockIdx.x * 128, n0 = blockIdx.y * 64;
  const int w = tid >> 6, lane = tid & 63;
  const int wm = (w >> 1) * 64, wn = (w & 1) * 32;
  const int lr = lane & 15, lg = lane >> 4;

  f32x4 acc[4][2];
  for(int i=0;i<4;i++) for(int j=0;j<2;j++) acc[i][j] = f32x4{0.f,0.f,0.f,0.f};

  for(int kt = 0; kt < K; kt += 64){
    __syncthreads();
    for(int u = tid; u < 1024; u += 256){
      int row = u >> 3, c = u & 7;
      long ga = (long)(m0 + row) * K + kt + (c ^ (row & 7))*8;
      GLOAD_LDS16(Ahi + ga, sAhi + u*8);
      if(NPROD == 3) GLOAD_LDS16(Alo + ga, sAlo + u*8);
    }
    for(int u = tid; u < 512; u += 256){
      int row = u >> 3, c = u & 7;
      long ga = (long)(n0 + row) * K + kt + (c ^ (row & 7))*8;
      GLOAD_LDS16(Bhi + ga, sBhi + u*8);
      if(NPROD == 3) GLOAD_LDS16(Blo + ga, sBlo + u*8);
    }
    __syncthreads();
    #pragma unroll
    for(int ks = 0; ks < 2; ks++){
      bf16x8 ah[4], al[4], bh[2], bl[2];
      #pragma unroll
      for(int i=0;i<4;i++){
        int row = wm + i*16 + lr, c = ks*4 + lg;
        ah[i] = *(const bf16x8*)(sAhi + swz(row,c)*8);
        if(NPROD==3) al[i] = *(const bf16x8*)(sAlo + swz(row,c)*8);
      }
      #pragma unroll
      for(int j=0;j<2;j++){
        int row = wn + j*16 + lr, c = ks*4 + lg;
        bh[j] = *(const bf16x8*)(sBhi + swz(row,c)*8);
        if(NPROD==3) bl[j] = *(const bf16x8*)(sBlo + swz(row,c)*8);
      }
      #pragma unroll
      for(int i=0;i<4;i++)
        #pragma unroll
        for(int j=0;j<2;j++){
          acc[i][j] = MFMA16(ah[i], bh[j], acc[i][j]);
          if(NPROD==3){
            acc[i][j] = MFMA16(ah[i], bl[j], acc[i][j]);
            acc[i][j] = MFMA16(al[i], bh[j], acc[i][j]);
          }
        }
    }
  }
  #pragma unroll
  for(int i=0;i<4;i++){
    #pragma unroll
    for(int j=0;j<2;j++){
      int row = m0 + wm + i*16 + lg*4;
      int col = n0 + wn + j*16 + lr;
      if(EPI == 1){
        int bb = row >> 11;
        int hh = col >> 6, cc = col & 63;
        short4v pk;
        #pragma unroll
        for(int r=0;r<4;r++) pk[r] = f2bf(acc[i][j][r] * scale);
        long idx = ((long)((bb*8 + hh)*64 + cc) << 11) + (row & 2047);
        *(short4v*)(O0 + idx) = pk;
      } else {
        #pragma unroll
        for(int r=0;r<4;r++){
          float v = acc[i][j][r] * scale;
          long idx = (long)(row + r) * 512 + col;
          if(EPI == 0){
            short hh = f2bf(v);
            O0[idx] = hh;
            O1[idx] = f2bf(v - bf2f(hh));
          } else {
            Of[idx] = v + bias[col];
          }
        }
      }
    }
  }
}

// ---------------- fused attention (r8 version, verbatim: KVBLK=64) ----------------
struct SpreadArgs { float sig2[8]; float nine[8]; float inv2[8]; };

__global__ __launch_bounds__(256) void attn_k(
    const short* __restrict__ qhHi, const short* __restrict__ qhLo,
    const short* __restrict__ khHi, const short* __restrict__ khLo,
    const short* __restrict__ vt,
    const float* __restrict__ coords,
    const unsigned char* __restrict__ kpm,
    short* __restrict__ Xhi, short* __restrict__ Xlo,
    SpreadArgs sa)
{
  __shared__ __attribute__((aligned(16))) short sKhi[64*64];
  __shared__ __attribute__((aligned(16))) short sKlo[64*64];
  __shared__ __attribute__((aligned(16))) short sV[64*64];
  __shared__ float sCj[64][4];
  __shared__ float sM[64];
  __shared__ __attribute__((aligned(16))) short sP[4][16][72]; // per-wave P tile, padded

  const int tid = threadIdx.x, w = tid >> 6, lane = tid & 63;
  const int lr = lane & 15, lg = lane >> 4;
  // XCD-locality swizzle (index-only): each XCD owns 2 (b,h) pairs, 32 i-blocks each.
  const int L = blockIdx.x;
  const int xcd = L & 7, ix = L >> 3;          // ix in [0,64)
  const int pair = xcd*2 + (ix >> 5);          // [0,16)
  const int b = pair >> 3, h = pair & 7, i0 = (ix & 31) * 64;
  const float sig2 = sa.sig2[h], nine = sa.nine[h], inv2 = sa.inv2[h];
  // constant RBF factors for the (dominant) d2<=sig2 regime — bit-identical to slow path
  const float argc = sig2 * inv2;
  const float E0 = __expf(-argc), E1 = __expf(argc);
  bf16x8 ones8;
  #pragma unroll
  for(int i=0;i<8;i++) ones8[i] = (short)0x3F80;   // bf16 1.0

  // Q fragments resident in registers (A-frag: row = lane&15, k = (lane>>4)*8)
  long qrow = (long)(b*2048 + i0 + w*16 + lr) * 512 + h*64;
  bf16x8 qhi[2], qlo[2];
  #pragma unroll
  for(int ks=0; ks<2; ks++){
    qhi[ks] = *(const bf16x8*)(qhHi + qrow + ks*32 + lg*8);
    qlo[ks] = *(const bf16x8*)(qhLo + qrow + ks*32 + lg*8);
  }
  // coords of this lane's 4 C-rows + their squared norms
  float ci[4][3], ni[4];
  {
    int r0 = b*2048 + i0 + w*16 + lg*4;
    #pragma unroll
    for(int r=0;r<4;r++){
      ci[r][0] = coords[(long)(r0+r)*3 + 0];
      ci[r][1] = coords[(long)(r0+r)*3 + 1];
      ci[r][2] = coords[(long)(r0+r)*3 + 2];
      ni[r] = ci[r][0]*ci[r][0] + ci[r][1]*ci[r][1] + ci[r][2]*ci[r][2];
    }
  }
  f32x4 oacc[4];
  for(int c=0;c<4;c++) oacc[c] = f32x4{0.f,0.f,0.f,0.f};
  float m[4], l[4];
  for(int r=0;r<4;r++){ m[r] = -1e30f; l[r] = 0.f; }

  for(int jt=0; jt<32; jt++){
    int j0 = jt*64;
    for(int u=tid; u<512; u+=256){
      int row = u>>3, cc = u&7;
      long gk = (long)(b*2048 + j0 + row)*512 + h*64 + cc*8;
      *(bf16x8*)(sKhi + swz(row,cc)*8) = *(const bf16x8*)(khHi + gk);
      *(bf16x8*)(sKlo + swz(row,cc)*8) = *(const bf16x8*)(khLo + gk);
      long gv = ((long)((b*8+h)*64 + row) << 11) + j0 + cc*8;
      *(bf16x8*)(sV + swz(row,cc)*8) = *(const bf16x8*)(vt + gv);
    }
    if(tid < 64){
      long cb = (long)(b*2048 + j0 + tid)*3;
      float cx = coords[cb], cy = coords[cb+1], cz = coords[cb+2];
      sCj[tid][0] = cx; sCj[tid][1] = cy; sCj[tid][2] = cz;
      sCj[tid][3] = cx*cx + cy*cy + cz*cz;
      sM[tid] = kpm[b*2048 + j0 + tid] ? 1.f : 0.f;
    }
    __syncthreads();

    // S2 = (QK^T)/8*log2e, 3-product hi/lo split (scales folded into qh)
    f32x4 s[4];
    #pragma unroll
    for(int jf=0;jf<4;jf++){
      f32x4 t = f32x4{0.f,0.f,0.f,0.f};
      #pragma unroll
      for(int ks=0;ks<2;ks++){
        int row = jf*16 + lr, c = ks*4 + lg;
        bf16x8 bh = *(const bf16x8*)(sKhi + swz(row,c)*8);
        bf16x8 bl = *(const bf16x8*)(sKlo + swz(row,c)*8);
        t = MFMA16(qhi[ks], bh, t);
        t = MFMA16(qhi[ks], bl, t);
        t = MFMA16(qlo[ks], bh, t);
      }
      s[jf] = t;
    }
    // RBF modulation + mask (multiplicative factor commutes with log2e scaling)
    float d2a[4][4], kmv[4];
    int ok = 1;
    #pragma unroll
    for(int jf=0;jf<4;jf++){
      int j = jf*16 + lr;
      float cjx = sCj[j][0], cjy = sCj[j][1], cjz = sCj[j][2], nj = sCj[j][3];
      kmv[jf] = sM[j];
      ok &= (kmv[jf] == 0.f);
      #pragma unroll
      for(int r=0;r<4;r++){
        float dot = ci[r][0]*cjx + ci[r][1]*cjy + ci[r][2]*cjz;
        float d2 = fmaf(-2.f, dot, ni[r] + nj);
        d2a[jf][r] = d2;
        ok &= (d2 <= sig2);
      }
    }
    if(__all(ok)){
      #pragma unroll
      for(int jf=0;jf<4;jf++)
        #pragma unroll
        for(int r=0;r<4;r++){
          float sv = s[jf][r];
          s[jf][r] = sv * (sv < 0.f ? E1 : E0);
        }
    } else {
      #pragma unroll
      for(int jf=0;jf<4;jf++){
        float km = kmv[jf];
        #pragma unroll
        for(int r=0;r<4;r++){
          float d2 = d2a[jf][r];
          float tt = fminf(fmaxf(d2, sig2), nine);
          float arg = tt * inv2;
          float sv = s[jf][r];
          sv *= __expf(sv < 0.f ? arg : -arg);
          if(d2 > nine || km != 0.f) sv = -1e30f;
          s[jf][r] = sv;
        }
      }
    }
    // online softmax in exp2 domain (logits pre-scaled by log2e)
    float pm[4];
    #pragma unroll
    for(int r=0;r<4;r++)
      pm[r] = fmaxf(fmaxf(s[0][r], s[1][r]), fmaxf(s[2][r], s[3][r]));
    #pragma unroll
    for(int d=1; d<16; d<<=1){
      #pragma unroll
      for(int r=0;r<4;r++) pm[r] = fmaxf(pm[r], __shfl_xor(pm[r], d));
    }
    float fr[4];
    #pragma unroll
    for(int r=0;r<4;r++){
      float mn = fmaxf(m[r], pm[r]);
      fr[r] = EXP2F(m[r] - mn);
      m[r] = mn;
      l[r] *= fr[r];
    }
    #pragma unroll
    for(int jf=0;jf<4;jf++)
      #pragma unroll
      for(int r=0;r<4;r++)
        s[jf][r] = EXP2F(s[jf][r] - m[r]);
    #pragma unroll
    for(int c=0;c<4;c++)
      #pragma unroll
      for(int r=0;r<4;r++) oacc[c][r] *= fr[r];
    // P -> per-wave LDS (C-layout write, A-layout read; same-wave so no barrier)
    #pragma unroll
    for(int jf=0;jf<4;jf++)
      #pragma unroll
      for(int r=0;r<4;r++)
        sP[w][lg*4 + r][jf*16 + lr] = f2bf(s[jf][r]);
    // PV + row-sum of P via a spare MFMA against an all-ones B fragment
    f32x4 psacc = f32x4{0.f,0.f,0.f,0.f};
    #pragma unroll
    for(int js=0;js<2;js++){
      union { bf16x8 v8; short4v h4[2]; } pa;
      pa.h4[0] = *(const short4v*)(&sP[w][lr][js*32 + lg*8]);
      pa.h4[1] = *(const short4v*)(&sP[w][lr][js*32 + lg*8 + 4]);
      #pragma unroll
      for(int cf=0; cf<4; cf++){
        int vrow = cf*16 + lr, vc = js*4 + lg;
        bf16x8 vb = *(const bf16x8*)(sV + swz(vrow,vc)*8);
        oacc[cf] = MFMA16(pa.v8, vb, oacc[cf]);
      }
      psacc = MFMA16(pa.v8, ones8, psacc);
    }
    #pragma unroll
    for(int r=0;r<4;r++) l[r] += psacc[r];
    __syncthreads();
  }
  // epilogue: X[b*2048+i][h*64+c] as hi/lo split for the final GEMM
  #pragma unroll
  for(int cf=0; cf<4; cf++){
    #pragma unroll
    for(int r=0;r<4;r++){
      float v = oacc[cf][r] / l[r];
      long idx = (long)(b*2048 + i0 + w*16 + lg*4 + r)*512 + h*64 + cf*16 + lr;
      short hh = f2bf(v);
      Xhi[idx] = hh;
      Xlo[idx] = f2bf(v - bf2f(hh));
    }
  }
}

// ---------------- host ----------------
extern "C" void kernel_launch(void* const* d_in, const int* in_sizes, int n_in,
                              void* d_out, int out_size, void* d_ws, size_t ws_size,
                              hipStream_t stream){
  const float* q  = (const float*)d_in[0];
  const float* k  = (const float*)d_in[1];
  const float* v  = (const float*)d_in[2];
  const float* coords = (const float*)d_in[3];
  const unsigned char* kpm = (const unsigned char*)d_in[4];
  const float* qp = (const float*)d_in[5];
  const float* kp = (const float*)d_in[6];
  const float* vp = (const float*)d_in[7];
  const float* ow = (const float*)d_in[8];
  const float* ob = (const float*)d_in[9];
  float* out = (float*)d_out;

  char* ws = (char*)d_ws;
  const size_t S = (size_t)4096*512*2;      // one bf16 [4096][512] plane
  const size_t P = (size_t)512*512*2;       // one bf16 [512][512] plane
  if(ws_size < 12*S + 7*P) return;
  short* q_hi = (short*)(ws + 0*S);
  short* q_lo = (short*)(ws + 1*S);
  short* k_hi = (short*)(ws + 2*S);
  short* k_lo = (short*)(ws + 3*S);
  short* v_hi = (short*)(ws + 4*S);
  short* qhHi = (short*)(ws + 5*S);
  short* qhLo = (short*)(ws + 6*S);
  short* khHi = (short*)(ws + 7*S);
  short* khLo = (short*)(ws + 8*S);
  short* vt   = (short*)(ws + 9*S);
  short* Xhi  = (short*)(ws + 10*S);
  short* Xlo  = (short*)(ws + 11*S);
  char* ws2 = ws + 12*S;
  short* BqHi = (short*)(ws2 + 0*P);
  short* BqLo = (short*)(ws2 + 1*P);
  short* BkHi = (short*)(ws2 + 2*P);
  short* BkLo = (short*)(ws2 + 3*P);
  short* BvHi = (short*)(ws2 + 4*P);
  short* WHi  = (short*)(ws2 + 5*P);
  short* WLo  = (short*)(ws2 + 6*P);

  SpreadArgs sa;
  for(int hh=0; hh<8; hh++){
    double t  = (1.0 - 0.02) * (double)hh / 7.0;
    double lg = pow(20.0, t);
    double sp = 3.7 + (lg - 1.0) / 19.0 * (20.0 - 3.7);
    float spf = (float)sp;
    sa.sig2[hh] = spf*spf;
    sa.nine[hh] = 9.f*spf*spf;
    sa.inv2[hh] = 1.f/(2.f*spf*spf);
  }

  const int NQ = 4096*512;
  split3<<<dim3(NQ/1024, 3), dim3(256), 0, stream>>>(q, k, v, q_hi, q_lo, k_hi, k_lo, v_hi);
  split_mat<<<dim3(1024), dim3(256), 0, stream>>>(ow, WHi, WLo, 512*512);
  split_proj3<<<dim3(1024, 3), dim3(256), 0, stream>>>(qp, kp, vp, BqHi, BqLo, BkHi, BkLo, BvHi);

  gemm_qkv<<<dim3(32, 8, 3), dim3(256), 0, stream>>>(
      q_hi, q_lo, k_hi, k_lo, v_hi,
      BqHi, BqLo, BkHi, BkLo, BvHi,
      qhHi, qhLo, khHi, khLo, vt);

  attn_k<<<dim3(512), dim3(256), 0, stream>>>(qhHi, qhLo, khHi, khLo, vt,
        coords, kpm, Xhi, Xlo, sa);

  gemm_k<3,2><<<dim3(32, 8), dim3(256), 0, stream>>>(Xhi, Xlo, WHi, WLo,
        nullptr, nullptr, out, ob, 1.f);
}

// Round 11
// 149.791 us; speedup vs baseline: 1.3014x; 1.0567x over previous
//
#include <hip/hip_runtime.h>
#include <hip/hip_bf16.h>
#include <cmath>

typedef __attribute__((ext_vector_type(8))) short bf16x8;
typedef __attribute__((ext_vector_type(4))) float f32x4;
typedef __attribute__((ext_vector_type(4))) short short4v;

#define MFMA16(a,b,c) __builtin_amdgcn_mfma_f32_16x16x32_bf16((a),(b),(c),0,0,0)
#define EXP2F(x) __builtin_amdgcn_exp2f(x)
// async global->LDS 16B: LDS dest is lane-ordered linear; source carries the swizzle
#define GLOAD_LDS16(g, l) __builtin_amdgcn_global_load_lds( \
    (const __attribute__((address_space(1))) unsigned int*)(g), \
    (__attribute__((address_space(3))) unsigned int*)(l), 16, 0, 0)

__device__ __forceinline__ short f2bf(float x){
  unsigned u = __float_as_uint(x);
  u += 0x7fffu + ((u >> 16) & 1u);          // RNE
  return (short)(u >> 16);
}
__device__ __forceinline__ float bf2f(short h){
  return __uint_as_float(((unsigned)(unsigned short)h) << 16);
}
// 16B-chunk XOR swizzle within a [rows][64-short] tile; unit = 8 shorts
__device__ __forceinline__ int swz(int row, int c){ return (row << 3) | (c ^ (row & 7)); }

// ---------------- split kernels ----------------
// q,k,v -> hi/lo (v: hi only), one dispatch, float4-vectorized
__global__ void split3(const float* __restrict__ q, const float* __restrict__ k,
                       const float* __restrict__ v,
                       short* __restrict__ q_hi, short* __restrict__ q_lo,
                       short* __restrict__ k_hi, short* __restrict__ k_lo,
                       short* __restrict__ v_hi){
  int y = blockIdx.y;
  int i4 = (blockIdx.x * 256 + threadIdx.x) * 4;
  if(y == 0){
    float4 x = *(const float4*)(q + i4);
    short4v hi, lo;
    float xs[4] = {x.x, x.y, x.z, x.w};
    #pragma unroll
    for(int r=0;r<4;r++){ short h = f2bf(xs[r]); hi[r]=h; lo[r]=f2bf(xs[r]-bf2f(h)); }
    *(short4v*)(q_hi + i4) = hi; *(short4v*)(q_lo + i4) = lo;
  } else if(y == 1){
    float4 x = *(const float4*)(k + i4);
    short4v hi, lo;
    float xs[4] = {x.x, x.y, x.z, x.w};
    #pragma unroll
    for(int r=0;r<4;r++){ short h = f2bf(xs[r]); hi[r]=h; lo[r]=f2bf(xs[r]-bf2f(h)); }
    *(short4v*)(k_hi + i4) = hi; *(short4v*)(k_lo + i4) = lo;
  } else {
    float4 x = *(const float4*)(v + i4);
    short4v hi;
    float xs[4] = {x.x, x.y, x.z, x.w};
    #pragma unroll
    for(int r=0;r<4;r++) hi[r] = f2bf(xs[r]);
    *(short4v*)(v_hi + i4) = hi;
  }
}

// proj [8][512][64] -> BT [512][512], BT[h*64+c][d] = proj[h][d][c]; + ow split (y=3)
__global__ void split_proj4(const float* __restrict__ qp, const float* __restrict__ kp,
                            const float* __restrict__ vp, const float* __restrict__ ow,
                            short* __restrict__ BqHi, short* __restrict__ BqLo,
                            short* __restrict__ BkHi, short* __restrict__ BkLo,
                            short* __restrict__ BvHi,
                            short* __restrict__ WHi,  short* __restrict__ WLo){
  int y = blockIdx.y;
  int i = blockIdx.x * 256 + threadIdx.x;   // i = n*512 + d
  int n = i >> 9, d = i & 511;
  int h = n >> 6, c = n & 63;
  long si = (long)((h << 15) | (d << 6) | c);
  if(y == 0){
    float x = qp[si]; short hh = f2bf(x);
    BqHi[i] = hh; BqLo[i] = f2bf(x - bf2f(hh));
  } else if(y == 1){
    float x = kp[si]; short hh = f2bf(x);
    BkHi[i] = hh; BkLo[i] = f2bf(x - bf2f(hh));
  } else if(y == 2){
    BvHi[i] = f2bf(vp[si]);
  } else {
    float x = ow[i]; short hh = f2bf(x);    // ow [512][512] row-major used as BT directly
    WHi[i] = hh; WLo[i] = f2bf(x - bf2f(hh));
  }
}

// ---------------- fused projection GEMM (q,k,v in one dispatch via z) ----------------
// C[4096x512] = A[4096x512] * BT[512x512]^T
// z=0: q (3-prod, hi/lo out, scale 0.125*log2e); z=1: k (3-prod, hi/lo out); z=2: v (1-prod, vt out)
__global__ __launch_bounds__(256) void gemm_qkv(
    const short* __restrict__ q_hi, const short* __restrict__ q_lo,
    const short* __restrict__ k_hi, const short* __restrict__ k_lo,
    const short* __restrict__ v_hi,
    const short* __restrict__ BqHi, const short* __restrict__ BqLo,
    const short* __restrict__ BkHi, const short* __restrict__ BkLo,
    const short* __restrict__ BvHi,
    short* __restrict__ qhHi, short* __restrict__ qhLo,
    short* __restrict__ khHi, short* __restrict__ khLo,
    short* __restrict__ vt)
{
  constexpr int K = 512;
  __shared__ __attribute__((aligned(16))) short sAhi[128*64];
  __shared__ __attribute__((aligned(16))) short sBhi[64*64];
  __shared__ __attribute__((aligned(16))) short sAlo[128*64];
  __shared__ __attribute__((aligned(16))) short sBlo[64*64];
  const int tid = threadIdx.x;
  const int z = blockIdx.z;
  const bool three = (z < 2);
  const short* Ahi = z==0 ? q_hi : z==1 ? k_hi : v_hi;
  const short* Alo = z==0 ? q_lo : k_lo;
  const short* Bhi = z==0 ? BqHi : z==1 ? BkHi : BvHi;
  const short* Blo = z==0 ? BqLo : BkLo;
  const float scale = z==0 ? 0.125f*1.44269504f : 1.f;   // fold log2(e) -> exp2 softmax domain
  const int m0 = blockIdx.x * 128, n0 = blockIdx.y * 64;
  const int w = tid >> 6, lane = tid & 63;
  const int wm = (w >> 1) * 64, wn = (w & 1) * 32;
  const int lr = lane & 15, lg = lane >> 4;

  f32x4 acc[4][2];
  for(int i=0;i<4;i++) for(int j=0;j<2;j++) acc[i][j] = f32x4{0.f,0.f,0.f,0.f};

  for(int kt = 0; kt < K; kt += 64){
    __syncthreads();
    // async staging: LDS written linearly (lane order); source column pre-swizzled
    for(int u = tid; u < 1024; u += 256){
      int row = u >> 3, c = u & 7;
      long ga = (long)(m0 + row) * K + kt + (c ^ (row & 7))*8;
      GLOAD_LDS16(Ahi + ga, sAhi + u*8);
      if(three) GLOAD_LDS16(Alo + ga, sAlo + u*8);
    }
    for(int u = tid; u < 512; u += 256){
      int row = u >> 3, c = u & 7;
      long ga = (long)(n0 + row) * K + kt + (c ^ (row & 7))*8;
      GLOAD_LDS16(Bhi + ga, sBhi + u*8);
      if(three) GLOAD_LDS16(Blo + ga, sBlo + u*8);
    }
    __syncthreads();
    #pragma unroll
    for(int ks = 0; ks < 2; ks++){
      bf16x8 ah[4], al[4], bh[2], bl[2];
      #pragma unroll
      for(int i=0;i<4;i++){
        int row = wm + i*16 + lr, c = ks*4 + lg;
        ah[i] = *(const bf16x8*)(sAhi + swz(row,c)*8);
        if(three) al[i] = *(const bf16x8*)(sAlo + swz(row,c)*8);
      }
      #pragma unroll
      for(int j=0;j<2;j++){
        int row = wn + j*16 + lr, c = ks*4 + lg;
        bh[j] = *(const bf16x8*)(sBhi + swz(row,c)*8);
        if(three) bl[j] = *(const bf16x8*)(sBlo + swz(row,c)*8);
      }
      #pragma unroll
      for(int i=0;i<4;i++)
        #pragma unroll
        for(int j=0;j<2;j++){
          acc[i][j] = MFMA16(ah[i], bh[j], acc[i][j]);
          if(three){
            acc[i][j] = MFMA16(ah[i], bl[j], acc[i][j]);
            acc[i][j] = MFMA16(al[i], bh[j], acc[i][j]);
          }
        }
    }
  }
  // epilogue
  #pragma unroll
  for(int i=0;i<4;i++){
    #pragma unroll
    for(int j=0;j<2;j++){
      int row = m0 + wm + i*16 + lg*4;
      int col = n0 + wn + j*16 + lr;
      if(z == 2){
        int bb = row >> 11;
        int hh = col >> 6, cc = col & 63;
        short4v pk;
        #pragma unroll
        for(int r=0;r<4;r++) pk[r] = f2bf(acc[i][j][r]);
        long idx = ((long)((bb*8 + hh)*64 + cc) << 11) + (row & 2047);
        *(short4v*)(vt + idx) = pk;
      } else {
        short* O0 = z==0 ? qhHi : khHi;
        short* O1 = z==0 ? qhLo : khLo;
        #pragma unroll
        for(int r=0;r<4;r++){
          float v = acc[i][j][r] * scale;
          long idx = (long)(row + r) * 512 + col;
          short hh = f2bf(v);
          O0[idx] = hh;
          O1[idx] = f2bf(v - bf2f(hh));
        }
      }
    }
  }
}

// ---------------- GEMM template (used for the final GEMM) ----------------
template<int NPROD, int EPI>
__global__ __launch_bounds__(256) void gemm_k(
    const short* __restrict__ Ahi, const short* __restrict__ Alo,
    const short* __restrict__ Bhi, const short* __restrict__ Blo,
    short* __restrict__ O0, short* __restrict__ O1,
    float* __restrict__ Of, const float* __restrict__ bias, float scale)
{
  constexpr int K = 512;
  __shared__ __attribute__((aligned(16))) short sAhi[128*64];
  __shared__ __attribute__((aligned(16))) short sBhi[64*64];
  __shared__ __attribute__((aligned(16))) short sAlo[NPROD==3 ? 128*64 : 8];
  __shared__ __attribute__((aligned(16))) short sBlo[NPROD==3 ? 64*64 : 8];
  const int tid = threadIdx.x;
  const int m0 = blockIdx.x * 128, n0 = blockIdx.y * 64;
  const int w = tid >> 6, lane = tid & 63;
  const int wm = (w >> 1) * 64, wn = (w & 1) * 32;
  const int lr = lane & 15, lg = lane >> 4;

  f32x4 acc[4][2];
  for(int i=0;i<4;i++) for(int j=0;j<2;j++) acc[i][j] = f32x4{0.f,0.f,0.f,0.f};

  for(int kt = 0; kt < K; kt += 64){
    __syncthreads();
    for(int u = tid; u < 1024; u += 256){
      int row = u >> 3, c = u & 7;
      long ga = (long)(m0 + row) * K + kt + (c ^ (row & 7))*8;
      GLOAD_LDS16(Ahi + ga, sAhi + u*8);
      if(NPROD == 3) GLOAD_LDS16(Alo + ga, sAlo + u*8);
    }
    for(int u = tid; u < 512; u += 256){
      int row = u >> 3, c = u & 7;
      long ga = (long)(n0 + row) * K + kt + (c ^ (row & 7))*8;
      GLOAD_LDS16(Bhi + ga, sBhi + u*8);
      if(NPROD == 3) GLOAD_LDS16(Blo + ga, sBlo + u*8);
    }
    __syncthreads();
    #pragma unroll
    for(int ks = 0; ks < 2; ks++){
      bf16x8 ah[4], al[4], bh[2], bl[2];
      #pragma unroll
      for(int i=0;i<4;i++){
        int row = wm + i*16 + lr, c = ks*4 + lg;
        ah[i] = *(const bf16x8*)(sAhi + swz(row,c)*8);
        if(NPROD==3) al[i] = *(const bf16x8*)(sAlo + swz(row,c)*8);
      }
      #pragma unroll
      for(int j=0;j<2;j++){
        int row = wn + j*16 + lr, c = ks*4 + lg;
        bh[j] = *(const bf16x8*)(sBhi + swz(row,c)*8);
        if(NPROD==3) bl[j] = *(const bf16x8*)(sBlo + swz(row,c)*8);
      }
      #pragma unroll
      for(int i=0;i<4;i++)
        #pragma unroll
        for(int j=0;j<2;j++){
          acc[i][j] = MFMA16(ah[i], bh[j], acc[i][j]);
          if(NPROD==3){
            acc[i][j] = MFMA16(ah[i], bl[j], acc[i][j]);
            acc[i][j] = MFMA16(al[i], bh[j], acc[i][j]);
          }
        }
    }
  }
  #pragma unroll
  for(int i=0;i<4;i++){
    #pragma unroll
    for(int j=0;j<2;j++){
      int row = m0 + wm + i*16 + lg*4;
      int col = n0 + wn + j*16 + lr;
      if(EPI == 1){
        int bb = row >> 11;
        int hh = col >> 6, cc = col & 63;
        short4v pk;
        #pragma unroll
        for(int r=0;r<4;r++) pk[r] = f2bf(acc[i][j][r] * scale);
        long idx = ((long)((bb*8 + hh)*64 + cc) << 11) + (row & 2047);
        *(short4v*)(O0 + idx) = pk;
      } else {
        #pragma unroll
        for(int r=0;r<4;r++){
          float v = acc[i][j][r] * scale;
          long idx = (long)(row + r) * 512 + col;
          if(EPI == 0){
            short hh = f2bf(v);
            O0[idx] = hh;
            O1[idx] = f2bf(v - bf2f(hh));
          } else {
            Of[idx] = v + bias[col];
          }
        }
      }
    }
  }
}

// ---------------- fused attention (r8 skeleton; async K/V staging via gload_lds) ----------------
struct SpreadArgs { float sig2[8]; float nine[8]; float inv2[8]; };

__global__ __launch_bounds__(256) void attn_k(
    const short* __restrict__ qhHi, const short* __restrict__ qhLo,
    const short* __restrict__ khHi, const short* __restrict__ khLo,
    const short* __restrict__ vt,
    const float* __restrict__ coords,
    const unsigned char* __restrict__ kpm,
    short* __restrict__ Xhi, short* __restrict__ Xlo,
    SpreadArgs sa)
{
  __shared__ __attribute__((aligned(16))) short sKhi[64*64];
  __shared__ __attribute__((aligned(16))) short sKlo[64*64];
  __shared__ __attribute__((aligned(16))) short sV[64*64];
  __shared__ float sCj[64][4];
  __shared__ float sM[64];
  __shared__ __attribute__((aligned(16))) short sP[4][16][72]; // per-wave P tile, padded

  const int tid = threadIdx.x, w = tid >> 6, lane = tid & 63;
  const int lr = lane & 15, lg = lane >> 4;
  // XCD-locality swizzle (index-only): each XCD owns 2 (b,h) pairs, 32 i-blocks each.
  const int L = blockIdx.x;
  const int xcd = L & 7, ix = L >> 3;          // ix in [0,64)
  const int pair = xcd*2 + (ix >> 5);          // [0,16)
  const int b = pair >> 3, h = pair & 7, i0 = (ix & 31) * 64;
  const float sig2 = sa.sig2[h], nine = sa.nine[h], inv2 = sa.inv2[h];
  // constant RBF factors for the (dominant) d2<=sig2 regime — bit-identical to slow path
  const float argc = sig2 * inv2;
  const float E0 = __expf(-argc), E1 = __expf(argc);
  bf16x8 ones8;
  #pragma unroll
  for(int i=0;i<8;i++) ones8[i] = (short)0x3F80;   // bf16 1.0

  // Q fragments resident in registers (A-frag: row = lane&15, k = (lane>>4)*8)
  long qrow = (long)(b*2048 + i0 + w*16 + lr) * 512 + h*64;
  bf16x8 qhi[2], qlo[2];
  #pragma unroll
  for(int ks=0; ks<2; ks++){
    qhi[ks] = *(const bf16x8*)(qhHi + qrow + ks*32 + lg*8);
    qlo[ks] = *(const bf16x8*)(qhLo + qrow + ks*32 + lg*8);
  }
  // coords of this lane's 4 C-rows + their squared norms
  float ci[4][3], ni[4];
  {
    int r0 = b*2048 + i0 + w*16 + lg*4;
    #pragma unroll
    for(int r=0;r<4;r++){
      ci[r][0] = coords[(long)(r0+r)*3 + 0];
      ci[r][1] = coords[(long)(r0+r)*3 + 1];
      ci[r][2] = coords[(long)(r0+r)*3 + 2];
      ni[r] = ci[r][0]*ci[r][0] + ci[r][1]*ci[r][1] + ci[r][2]*ci[r][2];
    }
  }
  f32x4 oacc[4];
  for(int c=0;c<4;c++) oacc[c] = f32x4{0.f,0.f,0.f,0.f};
  float m[4], l[4];
  for(int r=0;r<4;r++){ m[r] = -1e30f; l[r] = 0.f; }

  for(int jt=0; jt<32; jt++){
    int j0 = jt*64;
    // async staging (r10-proven mapping): LDS dest linear, source col inverse-swizzled
    for(int u=tid; u<512; u+=256){
      int row = u>>3, cc = u&7;
      int cs = cc ^ (row & 7);
      long gk = (long)(b*2048 + j0 + row)*512 + h*64 + cs*8;
      GLOAD_LDS16(khHi + gk, sKhi + u*8);
      GLOAD_LDS16(khLo + gk, sKlo + u*8);
      long gv = ((long)((b*8+h)*64 + row) << 11) + j0 + cs*8;
      GLOAD_LDS16(vt + gv, sV + u*8);
    }
    if(tid < 64){
      long cb = (long)(b*2048 + j0 + tid)*3;
      float cx = coords[cb], cy = coords[cb+1], cz = coords[cb+2];
      sCj[tid][0] = cx; sCj[tid][1] = cy; sCj[tid][2] = cz;
      sCj[tid][3] = cx*cx + cy*cy + cz*cz;
      sM[tid] = kpm[b*2048 + j0 + tid] ? 1.f : 0.f;
    }
    __syncthreads();

    // S2 = (QK^T)/8*log2e, 3-product hi/lo split (scales folded into qh)
    f32x4 s[4];
    #pragma unroll
    for(int jf=0;jf<4;jf++){
      f32x4 t = f32x4{0.f,0.f,0.f,0.f};
      #pragma unroll
      for(int ks=0;ks<2;ks++){
        int row = jf*16 + lr, c = ks*4 + lg;
        bf16x8 bh = *(const bf16x8*)(sKhi + swz(row,c)*8);
        bf16x8 bl = *(const bf16x8*)(sKlo + swz(row,c)*8);
        t = MFMA16(qhi[ks], bh, t);
        t = MFMA16(qhi[ks], bl, t);
        t = MFMA16(qlo[ks], bh, t);
      }
      s[jf] = t;
    }
    // RBF modulation + mask (multiplicative factor commutes with log2e scaling)
    float d2a[4][4], kmv[4];
    int ok = 1;
    #pragma unroll
    for(int jf=0;jf<4;jf++){
      int j = jf*16 + lr;
      float cjx = sCj[j][0], cjy = sCj[j][1], cjz = sCj[j][2], nj = sCj[j][3];
      kmv[jf] = sM[j];
      ok &= (kmv[jf] == 0.f);
      #pragma unroll
      for(int r=0;r<4;r++){
        float dot = ci[r][0]*cjx + ci[r][1]*cjy + ci[r][2]*cjz;
        float d2 = fmaf(-2.f, dot, ni[r] + nj);
        d2a[jf][r] = d2;
        ok &= (d2 <= sig2);
      }
    }
    if(__all(ok)){
      #pragma unroll
      for(int jf=0;jf<4;jf++)
        #pragma unroll
        for(int r=0;r<4;r++){
          float sv = s[jf][r];
          s[jf][r] = sv * (sv < 0.f ? E1 : E0);
        }
    } else {
      #pragma unroll
      for(int jf=0;jf<4;jf++){
        float km = kmv[jf];
        #pragma unroll
        for(int r=0;r<4;r++){
          float d2 = d2a[jf][r];
          float tt = fminf(fmaxf(d2, sig2), nine);
          float arg = tt * inv2;
          float sv = s[jf][r];
          sv *= __expf(sv < 0.f ? arg : -arg);
          if(d2 > nine || km != 0.f) sv = -1e30f;
          s[jf][r] = sv;
        }
      }
    }
    // online softmax in exp2 domain (logits pre-scaled by log2e)
    float pm[4];
    #pragma unroll
    for(int r=0;r<4;r++)
      pm[r] = fmaxf(fmaxf(s[0][r], s[1][r]), fmaxf(s[2][r], s[3][r]));
    #pragma unroll
    for(int d=1; d<16; d<<=1){
      #pragma unroll
      for(int r=0;r<4;r++) pm[r] = fmaxf(pm[r], __shfl_xor(pm[r], d));
    }
    float fr[4];
    #pragma unroll
    for(int r=0;r<4;r++){
      float mn = fmaxf(m[r], pm[r]);
      fr[r] = EXP2F(m[r] - mn);
      m[r] = mn;
      l[r] *= fr[r];
    }
    #pragma unroll
    for(int jf=0;jf<4;jf++)
      #pragma unroll
      for(int r=0;r<4;r++)
        s[jf][r] = EXP2F(s[jf][r] - m[r]);
    #pragma unroll
    for(int c=0;c<4;c++)
      #pragma unroll
      for(int r=0;r<4;r++) oacc[c][r] *= fr[r];
    // P -> per-wave LDS (C-layout write, A-layout read; same-wave so no barrier)
    #pragma unroll
    for(int jf=0;jf<4;jf++)
      #pragma unroll
      for(int r=0;r<4;r++)
        sP[w][lg*4 + r][jf*16 + lr] = f2bf(s[jf][r]);
    // PV + row-sum of P via a spare MFMA against an all-ones B fragment
    f32x4 psacc = f32x4{0.f,0.f,0.f,0.f};
    #pragma unroll
    for(int js=0;js<2;js++){
      union { bf16x8 v8; short4v h4[2]; } pa;
      pa.h4[0] = *(const short4v*)(&sP[w][lr][js*32 + lg*8]);
      pa.h4[1] = *(const short4v*)(&sP[w][lr][js*32 + lg*8 + 4]);
      #pragma unroll
      for(int cf=0; cf<4; cf++){
        int vrow = cf*16 + lr, vc = js*4 + lg;
        bf16x8 vb = *(const bf16x8*)(sV + swz(vrow,vc)*8);
        oacc[cf] = MFMA16(pa.v8, vb, oacc[cf]);
      }
      psacc = MFMA16(pa.v8, ones8, psacc);
    }
    #pragma unroll
    for(int r=0;r<4;r++) l[r] += psacc[r];
    __syncthreads();
  }
  // epilogue: X[b*2048+i][h*64+c] as hi/lo split for the final GEMM
  #pragma unroll
  for(int cf=0; cf<4; cf++){
    #pragma unroll
    for(int r=0;r<4;r++){
      float v = oacc[cf][r] / l[r];
      long idx = (long)(b*2048 + i0 + w*16 + lg*4 + r)*512 + h*64 + cf*16 + lr;
      short hh = f2bf(v);
      Xhi[idx] = hh;
      Xlo[idx] = f2bf(v - bf2f(hh));
    }
  }
}

// ---------------- host ----------------
extern "C" void kernel_launch(void* const* d_in, const int* in_sizes, int n_in,
                              void* d_out, int out_size, void* d_ws, size_t ws_size,
                              hipStream_t stream){
  const float* q  = (const float*)d_in[0];
  const float* k  = (const float*)d_in[1];
  const float* v  = (const float*)d_in[2];
  const float* coords = (const float*)d_in[3];
  const unsigned char* kpm = (const unsigned char*)d_in[4];
  const float* qp = (const float*)d_in[5];
  const float* kp = (const float*)d_in[6];
  const float* vp = (const float*)d_in[7];
  const float* ow = (const float*)d_in[8];
  const float* ob = (const float*)d_in[9];
  float* out = (float*)d_out;

  char* ws = (char*)d_ws;
  const size_t S = (size_t)4096*512*2;      // one bf16 [4096][512] plane
  const size_t P = (size_t)512*512*2;       // one bf16 [512][512] plane
  if(ws_size < 12*S + 7*P) return;
  short* q_hi = (short*)(ws + 0*S);
  short* q_lo = (short*)(ws + 1*S);
  short* k_hi = (short*)(ws + 2*S);
  short* k_lo = (short*)(ws + 3*S);
  short* v_hi = (short*)(ws + 4*S);
  short* qhHi = (short*)(ws + 5*S);
  short* qhLo = (short*)(ws + 6*S);
  short* khHi = (short*)(ws + 7*S);
  short* khLo = (short*)(ws + 8*S);
  short* vt   = (short*)(ws + 9*S);
  short* Xhi  = (short*)(ws + 10*S);
  short* Xlo  = (short*)(ws + 11*S);
  char* ws2 = ws + 12*S;
  short* BqHi = (short*)(ws2 + 0*P);
  short* BqLo = (short*)(ws2 + 1*P);
  short* BkHi = (short*)(ws2 + 2*P);
  short* BkLo = (short*)(ws2 + 3*P);
  short* BvHi = (short*)(ws2 + 4*P);
  short* WHi  = (short*)(ws2 + 5*P);
  short* WLo  = (short*)(ws2 + 6*P);

  SpreadArgs sa;
  for(int hh=0; hh<8; hh++){
    double t  = (1.0 - 0.02) * (double)hh / 7.0;
    double lg = pow(20.0, t);
    double sp = 3.7 + (lg - 1.0) / 19.0 * (20.0 - 3.7);
    float spf = (float)sp;
    sa.sig2[hh] = spf*spf;
    sa.nine[hh] = 9.f*spf*spf;
    sa.inv2[hh] = 1.f/(2.f*spf*spf);
  }

  const int NQ = 4096*512;
  split3<<<dim3(NQ/1024, 3), dim3(256), 0, stream>>>(q, k, v, q_hi, q_lo, k_hi, k_lo, v_hi);
  split_proj4<<<dim3(1024, 4), dim3(256), 0, stream>>>(qp, kp, vp, ow,
      BqHi, BqLo, BkHi, BkLo, BvHi, WHi, WLo);

  gemm_qkv<<<dim3(32, 8, 3), dim3(256), 0, stream>>>(
      q_hi, q_lo, k_hi, k_lo, v_hi,
      BqHi, BqLo, BkHi, BkLo, BvHi,
      qhHi, qhLo, khHi, khLo, vt);

  attn_k<<<dim3(512), dim3(256), 0, stream>>>(qhHi, qhLo, khHi, khLo, vt,
        coords, kpm, Xhi, Xlo, sa);

  gemm_k<3,2><<<dim3(32, 8), dim3(256), 0, stream>>>(Xhi, Xlo, WHi, WLo,
        nullptr, nullptr, out, ob, 1.f);
}

// Round 13
// 144.296 us; speedup vs baseline: 1.3510x; 1.0381x over previous
//
#include <hip/hip_runtime.h>
#include <hip/hip_bf16.h>
#include <cmath>

typedef __attribute__((ext_vector_type(8))) short bf16x8;
typedef __attribute__((ext_vector_type(4))) float f32x4;
typedef __attribute__((ext_vector_type(4))) short short4v;

#define MFMA16(a,b,c) __builtin_amdgcn_mfma_f32_16x16x32_bf16((a),(b),(c),0,0,0)
#define EXP2F(x) __builtin_amdgcn_exp2f(x)
// async global->LDS 16B: LDS dest is lane-ordered linear; source carries the swizzle
#define GLOAD_LDS16(g, l) __builtin_amdgcn_global_load_lds( \
    (const __attribute__((address_space(1))) unsigned int*)(g), \
    (__attribute__((address_space(3))) unsigned int*)(l), 16, 0, 0)

__device__ __forceinline__ short f2bf(float x){
  unsigned u = __float_as_uint(x);
  u += 0x7fffu + ((u >> 16) & 1u);          // RNE
  return (short)(u >> 16);
}
__device__ __forceinline__ float bf2f(short h){
  return __uint_as_float(((unsigned)(unsigned short)h) << 16);
}
// 16B-chunk XOR swizzle within a [rows][64-short] tile; unit = 8 shorts
__device__ __forceinline__ int swz(int row, int c){ return (row << 3) | (c ^ (row & 7)); }

// ---------------- split kernels ----------------
// q,k,v -> hi/lo (v: hi only), one dispatch, float4-vectorized
__global__ void split3(const float* __restrict__ q, const float* __restrict__ k,
                       const float* __restrict__ v,
                       short* __restrict__ q_hi, short* __restrict__ q_lo,
                       short* __restrict__ k_hi, short* __restrict__ k_lo,
                       short* __restrict__ v_hi){
  int y = blockIdx.y;
  int i4 = (blockIdx.x * 256 + threadIdx.x) * 4;
  if(y == 0){
    float4 x = *(const float4*)(q + i4);
    short4v hi, lo;
    float xs[4] = {x.x, x.y, x.z, x.w};
    #pragma unroll
    for(int r=0;r<4;r++){ short h = f2bf(xs[r]); hi[r]=h; lo[r]=f2bf(xs[r]-bf2f(h)); }
    *(short4v*)(q_hi + i4) = hi; *(short4v*)(q_lo + i4) = lo;
  } else if(y == 1){
    float4 x = *(const float4*)(k + i4);
    short4v hi, lo;
    float xs[4] = {x.x, x.y, x.z, x.w};
    #pragma unroll
    for(int r=0;r<4;r++){ short h = f2bf(xs[r]); hi[r]=h; lo[r]=f2bf(xs[r]-bf2f(h)); }
    *(short4v*)(k_hi + i4) = hi; *(short4v*)(k_lo + i4) = lo;
  } else {
    float4 x = *(const float4*)(v + i4);
    short4v hi;
    float xs[4] = {x.x, x.y, x.z, x.w};
    #pragma unroll
    for(int r=0;r<4;r++) hi[r] = f2bf(xs[r]);
    *(short4v*)(v_hi + i4) = hi;
  }
}

// proj [8][512][64] -> BT [512][512], BT[h*64+c][d] = proj[h][d][c]; + ow split (y=3)
__global__ void split_proj4(const float* __restrict__ qp, const float* __restrict__ kp,
                            const float* __restrict__ vp, const float* __restrict__ ow,
                            short* __restrict__ BqHi, short* __restrict__ BqLo,
                            short* __restrict__ BkHi, short* __restrict__ BkLo,
                            short* __restrict__ BvHi,
                            short* __restrict__ WHi,  short* __restrict__ WLo){
  int y = blockIdx.y;
  int i = blockIdx.x * 256 + threadIdx.x;   // i = n*512 + d
  int n = i >> 9, d = i & 511;
  int h = n >> 6, c = n & 63;
  long si = (long)((h << 15) | (d << 6) | c);
  if(y == 0){
    float x = qp[si]; short hh = f2bf(x);
    BqHi[i] = hh; BqLo[i] = f2bf(x - bf2f(hh));
  } else if(y == 1){
    float x = kp[si]; short hh = f2bf(x);
    BkHi[i] = hh; BkLo[i] = f2bf(x - bf2f(hh));
  } else if(y == 2){
    BvHi[i] = f2bf(vp[si]);
  } else {
    float x = ow[i]; short hh = f2bf(x);    // ow [512][512] row-major used as BT directly
    WHi[i] = hh; WLo[i] = f2bf(x - bf2f(hh));
  }
}

// ---------------- fused projection GEMM (q,k,v in one dispatch via z) ----------------
// C[4096x512] = A[4096x512] * BT[512x512]^T
// z=0: q (3-prod, hi/lo out, scale 0.125*log2e); z=1: k (3-prod, hi/lo out); z=2: v (1-prod, vt out)
__global__ __launch_bounds__(256) void gemm_qkv(
    const short* __restrict__ q_hi, const short* __restrict__ q_lo,
    const short* __restrict__ k_hi, const short* __restrict__ k_lo,
    const short* __restrict__ v_hi,
    const short* __restrict__ BqHi, const short* __restrict__ BqLo,
    const short* __restrict__ BkHi, const short* __restrict__ BkLo,
    const short* __restrict__ BvHi,
    short* __restrict__ qhHi, short* __restrict__ qhLo,
    short* __restrict__ khHi, short* __restrict__ khLo,
    short* __restrict__ vt)
{
  constexpr int K = 512;
  __shared__ __attribute__((aligned(16))) short sAhi[128*64];
  __shared__ __attribute__((aligned(16))) short sBhi[64*64];
  __shared__ __attribute__((aligned(16))) short sAlo[128*64];
  __shared__ __attribute__((aligned(16))) short sBlo[64*64];
  const int tid = threadIdx.x;
  const int z = blockIdx.z;
  const bool three = (z < 2);
  const short* Ahi = z==0 ? q_hi : z==1 ? k_hi : v_hi;
  const short* Alo = z==0 ? q_lo : k_lo;
  const short* Bhi = z==0 ? BqHi : z==1 ? BkHi : BvHi;
  const short* Blo = z==0 ? BqLo : BkLo;
  const float scale = z==0 ? 0.125f*1.44269504f : 1.f;   // fold log2(e) -> exp2 softmax domain
  const int m0 = blockIdx.x * 128, n0 = blockIdx.y * 64;
  const int w = tid >> 6, lane = tid & 63;
  const int wm = (w >> 1) * 64, wn = (w & 1) * 32;
  const int lr = lane & 15, lg = lane >> 4;

  f32x4 acc[4][2];
  for(int i=0;i<4;i++) for(int j=0;j<2;j++) acc[i][j] = f32x4{0.f,0.f,0.f,0.f};

  for(int kt = 0; kt < K; kt += 64){
    __syncthreads();
    // async staging: LDS written linearly (lane order); source column pre-swizzled
    for(int u = tid; u < 1024; u += 256){
      int row = u >> 3, c = u & 7;
      long ga = (long)(m0 + row) * K + kt + (c ^ (row & 7))*8;
      GLOAD_LDS16(Ahi + ga, sAhi + u*8);
      if(three) GLOAD_LDS16(Alo + ga, sAlo + u*8);
    }
    for(int u = tid; u < 512; u += 256){
      int row = u >> 3, c = u & 7;
      long ga = (long)(n0 + row) * K + kt + (c ^ (row & 7))*8;
      GLOAD_LDS16(Bhi + ga, sBhi + u*8);
      if(three) GLOAD_LDS16(Blo + ga, sBlo + u*8);
    }
    __syncthreads();
    #pragma unroll
    for(int ks = 0; ks < 2; ks++){
      bf16x8 ah[4], al[4], bh[2], bl[2];
      #pragma unroll
      for(int i=0;i<4;i++){
        int row = wm + i*16 + lr, c = ks*4 + lg;
        ah[i] = *(const bf16x8*)(sAhi + swz(row,c)*8);
        if(three) al[i] = *(const bf16x8*)(sAlo + swz(row,c)*8);
      }
      #pragma unroll
      for(int j=0;j<2;j++){
        int row = wn + j*16 + lr, c = ks*4 + lg;
        bh[j] = *(const bf16x8*)(sBhi + swz(row,c)*8);
        if(three) bl[j] = *(const bf16x8*)(sBlo + swz(row,c)*8);
      }
      #pragma unroll
      for(int i=0;i<4;i++)
        #pragma unroll
        for(int j=0;j<2;j++){
          acc[i][j] = MFMA16(ah[i], bh[j], acc[i][j]);
          if(three){
            acc[i][j] = MFMA16(ah[i], bl[j], acc[i][j]);
            acc[i][j] = MFMA16(al[i], bh[j], acc[i][j]);
          }
        }
    }
  }
  // epilogue
  #pragma unroll
  for(int i=0;i<4;i++){
    #pragma unroll
    for(int j=0;j<2;j++){
      int row = m0 + wm + i*16 + lg*4;
      int col = n0 + wn + j*16 + lr;
      if(z == 2){
        int bb = row >> 11;
        int hh = col >> 6, cc = col & 63;
        short4v pk;
        #pragma unroll
        for(int r=0;r<4;r++) pk[r] = f2bf(acc[i][j][r]);
        long idx = ((long)((bb*8 + hh)*64 + cc) << 11) + (row & 2047);
        *(short4v*)(vt + idx) = pk;
      } else {
        short* O0 = z==0 ? qhHi : khHi;
        short* O1 = z==0 ? qhLo : khLo;
        #pragma unroll
        for(int r=0;r<4;r++){
          float v = acc[i][j][r] * scale;
          long idx = (long)(row + r) * 512 + col;
          short hh = f2bf(v);
          O0[idx] = hh;
          O1[idx] = f2bf(v - bf2f(hh));
        }
      }
    }
  }
}

// ---------------- GEMM template (used for the final GEMM) ----------------
template<int NPROD, int EPI>
__global__ __launch_bounds__(256) void gemm_k(
    const short* __restrict__ Ahi, const short* __restrict__ Alo,
    const short* __restrict__ Bhi, const short* __restrict__ Blo,
    short* __restrict__ O0, short* __restrict__ O1,
    float* __restrict__ Of, const float* __restrict__ bias, float scale)
{
  constexpr int K = 512;
  __shared__ __attribute__((aligned(16))) short sAhi[128*64];
  __shared__ __attribute__((aligned(16))) short sBhi[64*64];
  __shared__ __attribute__((aligned(16))) short sAlo[NPROD==3 ? 128*64 : 8];
  __shared__ __attribute__((aligned(16))) short sBlo[NPROD==3 ? 64*64 : 8];
  const int tid = threadIdx.x;
  const int m0 = blockIdx.x * 128, n0 = blockIdx.y * 64;
  const int w = tid >> 6, lane = tid & 63;
  const int wm = (w >> 1) * 64, wn = (w & 1) * 32;
  const int lr = lane & 15, lg = lane >> 4;

  f32x4 acc[4][2];
  for(int i=0;i<4;i++) for(int j=0;j<2;j++) acc[i][j] = f32x4{0.f,0.f,0.f,0.f};

  for(int kt = 0; kt < K; kt += 64){
    __syncthreads();
    for(int u = tid; u < 1024; u += 256){
      int row = u >> 3, c = u & 7;
      long ga = (long)(m0 + row) * K + kt + (c ^ (row & 7))*8;
      GLOAD_LDS16(Ahi + ga, sAhi + u*8);
      if(NPROD == 3) GLOAD_LDS16(Alo + ga, sAlo + u*8);
    }
    for(int u = tid; u < 512; u += 256){
      int row = u >> 3, c = u & 7;
      long ga = (long)(n0 + row) * K + kt + (c ^ (row & 7))*8;
      GLOAD_LDS16(Bhi + ga, sBhi + u*8);
      if(NPROD == 3) GLOAD_LDS16(Blo + ga, sBlo + u*8);
    }
    __syncthreads();
    #pragma unroll
    for(int ks = 0; ks < 2; ks++){
      bf16x8 ah[4], al[4], bh[2], bl[2];
      #pragma unroll
      for(int i=0;i<4;i++){
        int row = wm + i*16 + lr, c = ks*4 + lg;
        ah[i] = *(const bf16x8*)(sAhi + swz(row,c)*8);
        if(NPROD==3) al[i] = *(const bf16x8*)(sAlo + swz(row,c)*8);
      }
      #pragma unroll
      for(int j=0;j<2;j++){
        int row = wn + j*16 + lr, c = ks*4 + lg;
        bh[j] = *(const bf16x8*)(sBhi + swz(row,c)*8);
        if(NPROD==3) bl[j] = *(const bf16x8*)(sBlo + swz(row,c)*8);
      }
      #pragma unroll
      for(int i=0;i<4;i++)
        #pragma unroll
        for(int j=0;j<2;j++){
          acc[i][j] = MFMA16(ah[i], bh[j], acc[i][j]);
          if(NPROD==3){
            acc[i][j] = MFMA16(ah[i], bl[j], acc[i][j]);
            acc[i][j] = MFMA16(al[i], bh[j], acc[i][j]);
          }
        }
    }
  }
  #pragma unroll
  for(int i=0;i<4;i++){
    #pragma unroll
    for(int j=0;j<2;j++){
      int row = m0 + wm + i*16 + lg*4;
      int col = n0 + wn + j*16 + lr;
      if(EPI == 1){
        int bb = row >> 11;
        int hh = col >> 6, cc = col & 63;
        short4v pk;
        #pragma unroll
        for(int r=0;r<4;r++) pk[r] = f2bf(acc[i][j][r] * scale);
        long idx = ((long)((bb*8 + hh)*64 + cc) << 11) + (row & 2047);
        *(short4v*)(O0 + idx) = pk;
      } else {
        #pragma unroll
        for(int r=0;r<4;r++){
          float v = acc[i][j][r] * scale;
          long idx = (long)(row + r) * 512 + col;
          if(EPI == 0){
            short hh = f2bf(v);
            O0[idx] = hh;
            O1[idx] = f2bf(v - bf2f(hh));
          } else {
            Of[idx] = v + bias[col];
          }
        }
      }
    }
  }
}

// ---------------- fused attention (r11 skeleton; d^2 via hi/lo-packed MFMA) ----------------
struct SpreadArgs { float sig2[8]; float nine[8]; float inv2l[8]; };

__global__ __launch_bounds__(256) void attn_k(
    const short* __restrict__ qhHi, const short* __restrict__ qhLo,
    const short* __restrict__ khHi, const short* __restrict__ khLo,
    const short* __restrict__ vt,
    const float* __restrict__ coords,
    const unsigned char* __restrict__ kpm,
    short* __restrict__ Xhi, short* __restrict__ Xlo,
    SpreadArgs sa)
{
  __shared__ __attribute__((aligned(16))) short sKhi[64*64];
  __shared__ __attribute__((aligned(16))) short sKlo[64*64];
  __shared__ __attribute__((aligned(16))) short sV[64*64];
  __shared__ __attribute__((aligned(16))) short sCjPk[64*8];  // bf16 (hx,hy,hz,0,lx,ly,lz,0) per key
  __shared__ float sNj[64];                                   // |cj|^2 fp32 (+1e37 if masked)
  __shared__ __attribute__((aligned(16))) short sP[4][16][72]; // per-wave P tile, padded

  const int tid = threadIdx.x, w = tid >> 6, lane = tid & 63;
  const int lr = lane & 15, lg = lane >> 4;
  // XCD-locality swizzle (index-only): each XCD owns 2 (b,h) pairs, 32 i-blocks each.
  const int L = blockIdx.x;
  const int xcd = L & 7, ix = L >> 3;          // ix in [0,64)
  const int pair = xcd*2 + (ix >> 5);          // [0,16)
  const int b = pair >> 3, h = pair & 7, i0 = (ix & 31) * 64;
  const float sig2 = sa.sig2[h], nine = sa.nine[h], inv2l = sa.inv2l[h];
  bf16x8 ones8;
  #pragma unroll
  for(int i=0;i<8;i++) ones8[i] = (short)0x3F80;   // bf16 1.0

  // Q fragments resident in registers (A-frag: row = lane&15, k = (lane>>4)*8)
  long qrow = (long)(b*2048 + i0 + w*16 + lr) * 512 + h*64;
  bf16x8 qhi[2], qlo[2];
  #pragma unroll
  for(int ks=0; ks<2; ks++){
    qhi[ks] = *(const bf16x8*)(qhHi + qrow + ks*32 + lg*8);
    qlo[ks] = *(const bf16x8*)(qhLo + qrow + ks*32 + lg*8);
  }
  // coords A-fragment for d^2 MFMA: k-groups {lg0,lg1} carry -2*ciHi, {lg2,lg3} carry -2*ciLo.
  // Combined with B k-groups {hi,lo,hi,lo} this yields the full hihi+hilo+lohi+lolo dot.
  bf16x8 ciA;
  #pragma unroll
  for(int i=0;i<8;i++) ciA[i] = 0;
  {
    long cb = (long)(b*2048 + i0 + w*16 + lr)*3;
    #pragma unroll
    for(int e=0;e<3;e++){
      float c = coords[cb + e];
      short chi = f2bf(c);
      short clo = f2bf(c - bf2f(chi));
      ciA[e] = f2bf(-2.f * bf2f(lg < 2 ? chi : clo));
    }
  }
  // |ci|^2 for this lane's 4 C-rows (raw fp32 coords)
  float ni[4];
  {
    int r0 = b*2048 + i0 + w*16 + lg*4;
    #pragma unroll
    for(int r=0;r<4;r++){
      float cx = coords[(long)(r0+r)*3 + 0];
      float cy = coords[(long)(r0+r)*3 + 1];
      float cz = coords[(long)(r0+r)*3 + 2];
      ni[r] = cx*cx + cy*cy + cz*cz;
    }
  }
  f32x4 oacc[4];
  for(int c=0;c<4;c++) oacc[c] = f32x4{0.f,0.f,0.f,0.f};
  float m[4], l[4];
  for(int r=0;r<4;r++){ m[r] = -1e30f; l[r] = 0.f; }

  for(int jt=0; jt<32; jt++){
    int j0 = jt*64;
    // async staging (r10-proven mapping): LDS dest linear, source col inverse-swizzled
    for(int u=tid; u<512; u+=256){
      int row = u>>3, cc = u&7;
      int cs = cc ^ (row & 7);
      long gk = (long)(b*2048 + j0 + row)*512 + h*64 + cs*8;
      GLOAD_LDS16(khHi + gk, sKhi + u*8);
      GLOAD_LDS16(khLo + gk, sKlo + u*8);
      long gv = ((long)((b*8+h)*64 + row) << 11) + j0 + cs*8;
      GLOAD_LDS16(vt + gv, sV + u*8);
    }
    if(tid < 64){
      long cb = (long)(b*2048 + j0 + tid)*3;
      float cx = coords[cb], cy = coords[cb+1], cz = coords[cb+2];
      short hx = f2bf(cx), hy = f2bf(cy), hz = f2bf(cz);
      bf16x8 pk;
      pk[0] = hx; pk[1] = hy; pk[2] = hz; pk[3] = 0;
      pk[4] = f2bf(cx - bf2f(hx));
      pk[5] = f2bf(cy - bf2f(hy));
      pk[6] = f2bf(cz - bf2f(hz));
      pk[7] = 0;
      *(bf16x8*)(sCjPk + tid*8) = pk;
      sNj[tid] = cx*cx + cy*cy + cz*cz + (kpm[b*2048 + j0 + tid] ? 1e37f : 0.f);
    }
    __syncthreads();

    // S2 = (QK^T)/8*log2e, 3-product hi/lo split (scales folded into qh)
    f32x4 s[4];
    #pragma unroll
    for(int jf=0;jf<4;jf++){
      f32x4 t = f32x4{0.f,0.f,0.f,0.f};
      #pragma unroll
      for(int ks=0;ks<2;ks++){
        int row = jf*16 + lr, c = ks*4 + lg;
        bf16x8 bh = *(const bf16x8*)(sKhi + swz(row,c)*8);
        bf16x8 bl = *(const bf16x8*)(sKlo + swz(row,c)*8);
        t = MFMA16(qhi[ks], bh, t);
        t = MFMA16(qhi[ks], bl, t);
        t = MFMA16(qlo[ks], bh, t);
      }
      s[jf] = t;
    }
    // d^2 for the 16x64 tile via 4 MFMAs: acc = (ni+nj) + (-2ci)·cj  (full hi/lo dot)
    f32x4 d2t[4];
    #pragma unroll
    for(int jf=0;jf<4;jf++){
      bf16x8 cjB;
      #pragma unroll
      for(int i=0;i<8;i++) cjB[i] = 0;
      {
        short4v c4 = *(const short4v*)(sCjPk + (jf*16 + lr)*8 + (lg & 1)*4);
        cjB[0] = c4[0]; cjB[1] = c4[1]; cjB[2] = c4[2];
      }
      float njv = sNj[jf*16 + lr];
      f32x4 cin;
      #pragma unroll
      for(int r=0;r<4;r++) cin[r] = ni[r] + njv;
      d2t[jf] = MFMA16(ciA, cjB, cin);
    }
    // RBF modulation + mask (factor commutes with log2e scaling; kpm folded into d2)
    #pragma unroll
    for(int jf=0;jf<4;jf++){
      #pragma unroll
      for(int r=0;r<4;r++){
        float d2 = d2t[jf][r];
        float tt = fminf(fmaxf(d2, sig2), nine);
        float arg2 = tt * inv2l;
        float sv = s[jf][r];
        sv *= EXP2F(sv < 0.f ? arg2 : -arg2);
        if(d2 > nine) sv = -1e30f;
        s[jf][r] = sv;
      }
    }
    // online softmax in exp2 domain (logits pre-scaled by log2e)
    float pm[4];
    #pragma unroll
    for(int r=0;r<4;r++)
      pm[r] = fmaxf(fmaxf(s[0][r], s[1][r]), fmaxf(s[2][r], s[3][r]));
    #pragma unroll
    for(int d=1; d<16; d<<=1){
      #pragma unroll
      for(int r=0;r<4;r++) pm[r] = fmaxf(pm[r], __shfl_xor(pm[r], d));
    }
    float fr[4];
    #pragma unroll
    for(int r=0;r<4;r++){
      float mn = fmaxf(m[r], pm[r]);
      fr[r] = EXP2F(m[r] - mn);
      m[r] = mn;
      l[r] *= fr[r];
    }
    #pragma unroll
    for(int jf=0;jf<4;jf++)
      #pragma unroll
      for(int r=0;r<4;r++)
        s[jf][r] = EXP2F(s[jf][r] - m[r]);
    #pragma unroll
    for(int c=0;c<4;c++)
      #pragma unroll
      for(int r=0;r<4;r++) oacc[c][r] *= fr[r];
    // P -> per-wave LDS (C-layout write, A-layout read; same-wave so no barrier)
    #pragma unroll
    for(int jf=0;jf<4;jf++)
      #pragma unroll
      for(int r=0;r<4;r++)
        sP[w][lg*4 + r][jf*16 + lr] = f2bf(s[jf][r]);
    // PV + row-sum of P via a spare MFMA against an all-ones B fragment
    f32x4 psacc = f32x4{0.f,0.f,0.f,0.f};
    #pragma unroll
    for(int js=0;js<2;js++){
      union { bf16x8 v8; short4v h4[2]; } pa;
      pa.h4[0] = *(const short4v*)(&sP[w][lr][js*32 + lg*8]);
      pa.h4[1] = *(const short4v*)(&sP[w][lr][js*32 + lg*8 + 4]);
      #pragma unroll
      for(int cf=0; cf<4; cf++){
        int vrow = cf*16 + lr, vc = js*4 + lg;
        bf16x8 vb = *(const bf16x8*)(sV + swz(vrow,vc)*8);
        oacc[cf] = MFMA16(pa.v8, vb, oacc[cf]);
      }
      psacc = MFMA16(pa.v8, ones8, psacc);
    }
    #pragma unroll
    for(int r=0;r<4;r++) l[r] += psacc[r];
    __syncthreads();
  }
  // epilogue: X[b*2048+i][h*64+c] as hi/lo split for the final GEMM
  #pragma unroll
  for(int cf=0; cf<4; cf++){
    #pragma unroll
    for(int r=0;r<4;r++){
      float v = oacc[cf][r] / l[r];
      long idx = (long)(b*2048 + i0 + w*16 + lg*4 + r)*512 + h*64 + cf*16 + lr;
      short hh = f2bf(v);
      Xhi[idx] = hh;
      Xlo[idx] = f2bf(v - bf2f(hh));
    }
  }
}

// ---------------- host ----------------
extern "C" void kernel_launch(void* const* d_in, const int* in_sizes, int n_in,
                              void* d_out, int out_size, void* d_ws, size_t ws_size,
                              hipStream_t stream){
  const float* q  = (const float*)d_in[0];
  const float* k  = (const float*)d_in[1];
  const float* v  = (const float*)d_in[2];
  const float* coords = (const float*)d_in[3];
  const unsigned char* kpm = (const unsigned char*)d_in[4];
  const float* qp = (const float*)d_in[5];
  const float* kp = (const float*)d_in[6];
  const float* vp = (const float*)d_in[7];
  const float* ow = (const float*)d_in[8];
  const float* ob = (const float*)d_in[9];
  float* out = (float*)d_out;

  char* ws = (char*)d_ws;
  const size_t S = (size_t)4096*512*2;      // one bf16 [4096][512] plane
  const size_t P = (size_t)512*512*2;       // one bf16 [512][512] plane
  if(ws_size < 12*S + 7*P) return;
  short* q_hi = (short*)(ws + 0*S);
  short* q_lo = (short*)(ws + 1*S);
  short* k_hi = (short*)(ws + 2*S);
  short* k_lo = (short*)(ws + 3*S);
  short* v_hi = (short*)(ws + 4*S);
  short* qhHi = (short*)(ws + 5*S);
  short* qhLo = (short*)(ws + 6*S);
  short* khHi = (short*)(ws + 7*S);
  short* khLo = (short*)(ws + 8*S);
  short* vt   = (short*)(ws + 9*S);
  short* Xhi  = (short*)(ws + 10*S);
  short* Xlo  = (short*)(ws + 11*S);
  char* ws2 = ws + 12*S;
  short* BqHi = (short*)(ws2 + 0*P);
  short* BqLo = (short*)(ws2 + 1*P);
  short* BkHi = (short*)(ws2 + 2*P);
  short* BkLo = (short*)(ws2 + 3*P);
  short* BvHi = (short*)(ws2 + 4*P);
  short* WHi  = (short*)(ws2 + 5*P);
  short* WLo  = (short*)(ws2 + 6*P);

  SpreadArgs sa;
  for(int hh=0; hh<8; hh++){
    double t  = (1.0 - 0.02) * (double)hh / 7.0;
    double lg = pow(20.0, t);
    double sp = 3.7 + (lg - 1.0) / 19.0 * (20.0 - 3.7);
    float spf = (float)sp;
    sa.sig2[hh] = spf*spf;
    sa.nine[hh] = 9.f*spf*spf;
    sa.inv2l[hh] = 1.44269504f/(2.f*spf*spf);
  }

  const int NQ = 4096*512;
  split3<<<dim3(NQ/1024, 3), dim3(256), 0, stream>>>(q, k, v, q_hi, q_lo, k_hi, k_lo, v_hi);
  split_proj4<<<dim3(1024, 4), dim3(256), 0, stream>>>(qp, kp, vp, ow,
      BqHi, BqLo, BkHi, BkLo, BvHi, WHi, WLo);

  gemm_qkv<<<dim3(32, 8, 3), dim3(256), 0, stream>>>(
      q_hi, q_lo, k_hi, k_lo, v_hi,
      BqHi, BqLo, BkHi, BkLo, BvHi,
      qhHi, qhLo, khHi, khLo, vt);

  attn_k<<<dim3(512), dim3(256), 0, stream>>>(qhHi, qhLo, khHi, khLo, vt,
        coords, kpm, Xhi, Xlo, sa);

  gemm_k<3,2><<<dim3(32, 8), dim3(256), 0, stream>>>(Xhi, Xlo, WHi, WLo,
        nullptr, nullptr, out, ob, 1.f);
}

// Round 14
// 136.738 us; speedup vs baseline: 1.4257x; 1.0553x over previous
//
#include <hip/hip_runtime.h>
#include <hip/hip_bf16.h>
#include <cmath>

typedef __attribute__((ext_vector_type(8))) short bf16x8;
typedef __attribute__((ext_vector_type(4))) float f32x4;
typedef __attribute__((ext_vector_type(4))) short short4v;
typedef __attribute__((ext_vector_type(2))) unsigned int uint2v;

#define MFMA16(a,b,c) __builtin_amdgcn_mfma_f32_16x16x32_bf16((a),(b),(c),0,0,0)
#define EXP2F(x) __builtin_amdgcn_exp2f(x)
// async global->LDS 16B: LDS dest is lane-ordered linear; source carries the swizzle
#define GLOAD_LDS16(g, l) __builtin_amdgcn_global_load_lds( \
    (const __attribute__((address_space(1))) unsigned int*)(g), \
    (__attribute__((address_space(3))) unsigned int*)(l), 16, 0, 0)

__device__ __forceinline__ short f2bf(float x){
  unsigned u = __float_as_uint(x);
  u += 0x7fffu + ((u >> 16) & 1u);          // RNE
  return (short)(u >> 16);
}
__device__ __forceinline__ float bf2f(short h){
  return __uint_as_float(((unsigned)(unsigned short)h) << 16);
}
__device__ __forceinline__ unsigned cvtpk_bf16(float a, float b){
  unsigned r;
  asm("v_cvt_pk_bf16_f32 %0, %1, %2" : "=v"(r) : "v"(a), "v"(b));
  return r;                                  // lo16 = bf16(a), hi16 = bf16(b)
}
// 16B-chunk XOR swizzle within a [rows][64-short] tile; unit = 8 shorts
__device__ __forceinline__ int swz(int row, int c){ return (row << 3) | (c ^ (row & 7)); }

// ---------------- split kernels ----------------
// q,k,v -> hi/lo (v: hi only), one dispatch, float4-vectorized
__global__ void split3(const float* __restrict__ q, const float* __restrict__ k,
                       const float* __restrict__ v,
                       short* __restrict__ q_hi, short* __restrict__ q_lo,
                       short* __restrict__ k_hi, short* __restrict__ k_lo,
                       short* __restrict__ v_hi){
  int y = blockIdx.y;
  int i4 = (blockIdx.x * 256 + threadIdx.x) * 4;
  if(y == 0){
    float4 x = *(const float4*)(q + i4);
    short4v hi, lo;
    float xs[4] = {x.x, x.y, x.z, x.w};
    #pragma unroll
    for(int r=0;r<4;r++){ short h = f2bf(xs[r]); hi[r]=h; lo[r]=f2bf(xs[r]-bf2f(h)); }
    *(short4v*)(q_hi + i4) = hi; *(short4v*)(q_lo + i4) = lo;
  } else if(y == 1){
    float4 x = *(const float4*)(k + i4);
    short4v hi, lo;
    float xs[4] = {x.x, x.y, x.z, x.w};
    #pragma unroll
    for(int r=0;r<4;r++){ short h = f2bf(xs[r]); hi[r]=h; lo[r]=f2bf(xs[r]-bf2f(h)); }
    *(short4v*)(k_hi + i4) = hi; *(short4v*)(k_lo + i4) = lo;
  } else {
    float4 x = *(const float4*)(v + i4);
    short4v hi;
    float xs[4] = {x.x, x.y, x.z, x.w};
    #pragma unroll
    for(int r=0;r<4;r++) hi[r] = f2bf(xs[r]);
    *(short4v*)(v_hi + i4) = hi;
  }
}

// proj [8][512][64] -> BT [512][512], BT[h*64+c][d] = proj[h][d][c]; + ow split (y=3)
__global__ void split_proj4(const float* __restrict__ qp, const float* __restrict__ kp,
                            const float* __restrict__ vp, const float* __restrict__ ow,
                            short* __restrict__ BqHi, short* __restrict__ BqLo,
                            short* __restrict__ BkHi, short* __restrict__ BkLo,
                            short* __restrict__ BvHi,
                            short* __restrict__ WHi,  short* __restrict__ WLo){
  int y = blockIdx.y;
  int i = blockIdx.x * 256 + threadIdx.x;   // i = n*512 + d
  int n = i >> 9, d = i & 511;
  int h = n >> 6, c = n & 63;
  long si = (long)((h << 15) | (d << 6) | c);
  if(y == 0){
    float x = qp[si]; short hh = f2bf(x);
    BqHi[i] = hh; BqLo[i] = f2bf(x - bf2f(hh));
  } else if(y == 1){
    float x = kp[si]; short hh = f2bf(x);
    BkHi[i] = hh; BkLo[i] = f2bf(x - bf2f(hh));
  } else if(y == 2){
    BvHi[i] = f2bf(vp[si]);
  } else {
    float x = ow[i]; short hh = f2bf(x);    // ow [512][512] row-major used as BT directly
    WHi[i] = hh; WLo[i] = f2bf(x - bf2f(hh));
  }
}

// ---------------- fused projection GEMM (q,k,v in one dispatch via z) ----------------
// C[4096x512] = A[4096x512] * BT[512x512]^T
// z=0: q (3-prod, hi/lo out, scale 0.125*log2e); z=1: k (3-prod, hi/lo out); z=2: v (1-prod, vt out)
__global__ __launch_bounds__(256) void gemm_qkv(
    const short* __restrict__ q_hi, const short* __restrict__ q_lo,
    const short* __restrict__ k_hi, const short* __restrict__ k_lo,
    const short* __restrict__ v_hi,
    const short* __restrict__ BqHi, const short* __restrict__ BqLo,
    const short* __restrict__ BkHi, const short* __restrict__ BkLo,
    const short* __restrict__ BvHi,
    short* __restrict__ qhHi, short* __restrict__ qhLo,
    short* __restrict__ khHi, short* __restrict__ khLo,
    short* __restrict__ vt)
{
  constexpr int K = 512;
  __shared__ __attribute__((aligned(16))) short sAhi[128*64];
  __shared__ __attribute__((aligned(16))) short sBhi[64*64];
  __shared__ __attribute__((aligned(16))) short sAlo[128*64];
  __shared__ __attribute__((aligned(16))) short sBlo[64*64];
  const int tid = threadIdx.x;
  const int z = blockIdx.z;
  const bool three = (z < 2);
  const short* Ahi = z==0 ? q_hi : z==1 ? k_hi : v_hi;
  const short* Alo = z==0 ? q_lo : k_lo;
  const short* Bhi = z==0 ? BqHi : z==1 ? BkHi : BvHi;
  const short* Blo = z==0 ? BqLo : BkLo;
  const float scale = z==0 ? 0.125f*1.44269504f : 1.f;   // fold log2(e) -> exp2 softmax domain
  const int m0 = blockIdx.x * 128, n0 = blockIdx.y * 64;
  const int w = tid >> 6, lane = tid & 63;
  const int wm = (w >> 1) * 64, wn = (w & 1) * 32;
  const int lr = lane & 15, lg = lane >> 4;

  f32x4 acc[4][2];
  for(int i=0;i<4;i++) for(int j=0;j<2;j++) acc[i][j] = f32x4{0.f,0.f,0.f,0.f};

  for(int kt = 0; kt < K; kt += 64){
    __syncthreads();
    // async staging: LDS written linearly (lane order); source column pre-swizzled
    for(int u = tid; u < 1024; u += 256){
      int row = u >> 3, c = u & 7;
      long ga = (long)(m0 + row) * K + kt + (c ^ (row & 7))*8;
      GLOAD_LDS16(Ahi + ga, sAhi + u*8);
      if(three) GLOAD_LDS16(Alo + ga, sAlo + u*8);
    }
    for(int u = tid; u < 512; u += 256){
      int row = u >> 3, c = u & 7;
      long ga = (long)(n0 + row) * K + kt + (c ^ (row & 7))*8;
      GLOAD_LDS16(Bhi + ga, sBhi + u*8);
      if(three) GLOAD_LDS16(Blo + ga, sBlo + u*8);
    }
    __syncthreads();
    #pragma unroll
    for(int ks = 0; ks < 2; ks++){
      bf16x8 ah[4], al[4], bh[2], bl[2];
      #pragma unroll
      for(int i=0;i<4;i++){
        int row = wm + i*16 + lr, c = ks*4 + lg;
        ah[i] = *(const bf16x8*)(sAhi + swz(row,c)*8);
        if(three) al[i] = *(const bf16x8*)(sAlo + swz(row,c)*8);
      }
      #pragma unroll
      for(int j=0;j<2;j++){
        int row = wn + j*16 + lr, c = ks*4 + lg;
        bh[j] = *(const bf16x8*)(sBhi + swz(row,c)*8);
        if(three) bl[j] = *(const bf16x8*)(sBlo + swz(row,c)*8);
      }
      #pragma unroll
      for(int i=0;i<4;i++)
        #pragma unroll
        for(int j=0;j<2;j++){
          acc[i][j] = MFMA16(ah[i], bh[j], acc[i][j]);
          if(three){
            acc[i][j] = MFMA16(ah[i], bl[j], acc[i][j]);
            acc[i][j] = MFMA16(al[i], bh[j], acc[i][j]);
          }
        }
    }
  }
  // epilogue
  #pragma unroll
  for(int i=0;i<4;i++){
    #pragma unroll
    for(int j=0;j<2;j++){
      int row = m0 + wm + i*16 + lg*4;
      int col = n0 + wn + j*16 + lr;
      if(z == 2){
        int bb = row >> 11;
        int hh = col >> 6, cc = col & 63;
        short4v pk;
        #pragma unroll
        for(int r=0;r<4;r++) pk[r] = f2bf(acc[i][j][r]);
        long idx = ((long)((bb*8 + hh)*64 + cc) << 11) + (row & 2047);
        *(short4v*)(vt + idx) = pk;
      } else {
        short* O0 = z==0 ? qhHi : khHi;
        short* O1 = z==0 ? qhLo : khLo;
        #pragma unroll
        for(int r=0;r<4;r++){
          float v = acc[i][j][r] * scale;
          long idx = (long)(row + r) * 512 + col;
          short hh = f2bf(v);
          O0[idx] = hh;
          O1[idx] = f2bf(v - bf2f(hh));
        }
      }
    }
  }
}

// ---------------- GEMM template (used for the final GEMM) ----------------
template<int NPROD, int EPI>
__global__ __launch_bounds__(256) void gemm_k(
    const short* __restrict__ Ahi, const short* __restrict__ Alo,
    const short* __restrict__ Bhi, const short* __restrict__ Blo,
    short* __restrict__ O0, short* __restrict__ O1,
    float* __restrict__ Of, const float* __restrict__ bias, float scale)
{
  constexpr int K = 512;
  __shared__ __attribute__((aligned(16))) short sAhi[128*64];
  __shared__ __attribute__((aligned(16))) short sBhi[64*64];
  __shared__ __attribute__((aligned(16))) short sAlo[NPROD==3 ? 128*64 : 8];
  __shared__ __attribute__((aligned(16))) short sBlo[NPROD==3 ? 64*64 : 8];
  const int tid = threadIdx.x;
  const int m0 = blockIdx.x * 128, n0 = blockIdx.y * 64;
  const int w = tid >> 6, lane = tid & 63;
  const int wm = (w >> 1) * 64, wn = (w & 1) * 32;
  const int lr = lane & 15, lg = lane >> 4;

  f32x4 acc[4][2];
  for(int i=0;i<4;i++) for(int j=0;j<2;j++) acc[i][j] = f32x4{0.f,0.f,0.f,0.f};

  for(int kt = 0; kt < K; kt += 64){
    __syncthreads();
    for(int u = tid; u < 1024; u += 256){
      int row = u >> 3, c = u & 7;
      long ga = (long)(m0 + row) * K + kt + (c ^ (row & 7))*8;
      GLOAD_LDS16(Ahi + ga, sAhi + u*8);
      if(NPROD == 3) GLOAD_LDS16(Alo + ga, sAlo + u*8);
    }
    for(int u = tid; u < 512; u += 256){
      int row = u >> 3, c = u & 7;
      long ga = (long)(n0 + row) * K + kt + (c ^ (row & 7))*8;
      GLOAD_LDS16(Bhi + ga, sBhi + u*8);
      if(NPROD == 3) GLOAD_LDS16(Blo + ga, sBlo + u*8);
    }
    __syncthreads();
    #pragma unroll
    for(int ks = 0; ks < 2; ks++){
      bf16x8 ah[4], al[4], bh[2], bl[2];
      #pragma unroll
      for(int i=0;i<4;i++){
        int row = wm + i*16 + lr, c = ks*4 + lg;
        ah[i] = *(const bf16x8*)(sAhi + swz(row,c)*8);
        if(NPROD==3) al[i] = *(const bf16x8*)(sAlo + swz(row,c)*8);
      }
      #pragma unroll
      for(int j=0;j<2;j++){
        int row = wn + j*16 + lr, c = ks*4 + lg;
        bh[j] = *(const bf16x8*)(sBhi + swz(row,c)*8);
        if(NPROD==3) bl[j] = *(const bf16x8*)(sBlo + swz(row,c)*8);
      }
      #pragma unroll
      for(int i=0;i<4;i++)
        #pragma unroll
        for(int j=0;j<2;j++){
          acc[i][j] = MFMA16(ah[i], bh[j], acc[i][j]);
          if(NPROD==3){
            acc[i][j] = MFMA16(ah[i], bl[j], acc[i][j]);
            acc[i][j] = MFMA16(al[i], bh[j], acc[i][j]);
          }
        }
    }
  }
  #pragma unroll
  for(int i=0;i<4;i++){
    #pragma unroll
    for(int j=0;j<2;j++){
      int row = m0 + wm + i*16 + lg*4;
      int col = n0 + wn + j*16 + lr;
      if(EPI == 1){
        int bb = row >> 11;
        int hh = col >> 6, cc = col & 63;
        short4v pk;
        #pragma unroll
        for(int r=0;r<4;r++) pk[r] = f2bf(acc[i][j][r] * scale);
        long idx = ((long)((bb*8 + hh)*64 + cc) << 11) + (row & 2047);
        *(short4v*)(O0 + idx) = pk;
      } else {
        #pragma unroll
        for(int r=0;r<4;r++){
          float v = acc[i][j][r] * scale;
          long idx = (long)(row + r) * 512 + col;
          if(EPI == 0){
            short hh = f2bf(v);
            O0[idx] = hh;
            O1[idx] = f2bf(v - bf2f(hh));
          } else {
            Of[idx] = v + bias[col];
          }
        }
      }
    }
  }
}

// ---------------- fused attention (swapped QK^T: scalar softmax, vector P path) ----------------
struct SpreadArgs { float sig2[8]; float nine[8]; float inv2l[8]; };

__global__ __launch_bounds__(256) void attn_k(
    const short* __restrict__ qhHi, const short* __restrict__ qhLo,
    const short* __restrict__ khHi, const short* __restrict__ khLo,
    const short* __restrict__ vt,
    const float* __restrict__ coords,
    const unsigned char* __restrict__ kpm,
    short* __restrict__ Xhi, short* __restrict__ Xlo,
    SpreadArgs sa)
{
  __shared__ __attribute__((aligned(16))) short sKhi[64*64];
  __shared__ __attribute__((aligned(16))) short sKlo[64*64];
  __shared__ __attribute__((aligned(16))) short sV[64*64];
  __shared__ __attribute__((aligned(16))) short sCjPk[64*8];  // bf16 (-2cj: hx,hy,hz,0,lx,ly,lz,0)
  __shared__ __attribute__((aligned(16))) float sNj[64];      // |cj|^2 fp32 (+1e37 if masked)
  __shared__ __attribute__((aligned(16))) short sP[4][16][72]; // [wave][q-row][k], padded

  const int tid = threadIdx.x, w = tid >> 6, lane = tid & 63;
  const int lr = lane & 15, lg = lane >> 4;
  // XCD-locality swizzle (index-only): each XCD owns 2 (b,h) pairs, 32 i-blocks each.
  const int L = blockIdx.x;
  const int xcd = L & 7, ix = L >> 3;          // ix in [0,64)
  const int pair = xcd*2 + (ix >> 5);          // [0,16)
  const int b = pair >> 3, h = pair & 7, i0 = (ix & 31) * 64;
  const float sig2 = sa.sig2[h], nine = sa.nine[h], inv2l = sa.inv2l[h];

  // Q fragments (B-operand now; same data/layout as before: col=lr, k=lg*8+e)
  long qrow = (long)(b*2048 + i0 + w*16 + lr) * 512 + h*64;
  bf16x8 qhi[2], qlo[2];
  #pragma unroll
  for(int ks=0; ks<2; ks++){
    qhi[ks] = *(const bf16x8*)(qhHi + qrow + ks*32 + lg*8);
    qlo[ks] = *(const bf16x8*)(qhLo + qrow + ks*32 + lg*8);
  }
  // ci B-fragment for d^2 MFMA: col=lr -> q-row lr; k-groups (lg&1)==0 -> hi, ==1 -> lo
  bf16x8 ciB;
  #pragma unroll
  for(int i=0;i<8;i++) ciB[i] = 0;
  float ni;   // |ci|^2 of q-row lr (raw fp32)
  {
    long cb = (long)(b*2048 + i0 + w*16 + lr)*3;
    float c0 = coords[cb], c1 = coords[cb+1], c2 = coords[cb+2];
    float cs[3] = {c0, c1, c2};
    #pragma unroll
    for(int e=0;e<3;e++){
      short chi = f2bf(cs[e]);
      short clo = f2bf(cs[e] - bf2f(chi));
      ciB[e] = ((lg & 1) == 0) ? chi : clo;
    }
    ni = c0*c0 + c1*c1 + c2*c2;
  }
  f32x4 oacc[4];
  for(int c=0;c<4;c++) oacc[c] = f32x4{0.f,0.f,0.f,0.f};
  float m = -1e30f, l = 0.f;

  for(int jt=0; jt<32; jt++){
    int j0 = jt*64;
    // async staging (r10-proven mapping): LDS dest linear, source col inverse-swizzled
    for(int u=tid; u<512; u+=256){
      int row = u>>3, cc = u&7;
      int cs = cc ^ (row & 7);
      long gk = (long)(b*2048 + j0 + row)*512 + h*64 + cs*8;
      GLOAD_LDS16(khHi + gk, sKhi + u*8);
      GLOAD_LDS16(khLo + gk, sKlo + u*8);
      long gv = ((long)((b*8+h)*64 + row) << 11) + j0 + cs*8;
      GLOAD_LDS16(vt + gv, sV + u*8);
    }
    if(tid < 64){
      long cb = (long)(b*2048 + j0 + tid)*3;
      float cx = coords[cb], cy = coords[cb+1], cz = coords[cb+2];
      float mx = -2.f*cx, my = -2.f*cy, mz = -2.f*cz;
      short hx = f2bf(mx), hy = f2bf(my), hz = f2bf(mz);
      bf16x8 pk;
      pk[0] = hx; pk[1] = hy; pk[2] = hz; pk[3] = 0;
      pk[4] = f2bf(mx - bf2f(hx));
      pk[5] = f2bf(my - bf2f(hy));
      pk[6] = f2bf(mz - bf2f(hz));
      pk[7] = 0;
      *(bf16x8*)(sCjPk + tid*8) = pk;
      sNj[tid] = cx*cx + cy*cy + cz*cz + (kpm[b*2048 + j0 + tid] ? 1e37f : 0.f);
    }
    __syncthreads();

    // S^T via swapped MFMA: s[jf][r] = S[k = jf*16 + lg*4 + r][q = lr]
    f32x4 s[4];
    #pragma unroll
    for(int jf=0;jf<4;jf++){
      f32x4 t = f32x4{0.f,0.f,0.f,0.f};
      #pragma unroll
      for(int ks=0;ks<2;ks++){
        int row = jf*16 + lr, c = ks*4 + lg;
        bf16x8 bh = *(const bf16x8*)(sKhi + swz(row,c)*8);
        bf16x8 bl = *(const bf16x8*)(sKlo + swz(row,c)*8);
        t = MFMA16(bh, qhi[ks], t);
        t = MFMA16(bl, qhi[ks], t);
        t = MFMA16(bh, qlo[ks], t);
      }
      s[jf] = t;
    }
    // d^2 via swapped MFMA: d2[k][q] = (ni+nj) + (-2cj)·ci  (full hi/lo dot), then RBF
    #pragma unroll
    for(int jf=0;jf<4;jf++){
      bf16x8 cjA;
      #pragma unroll
      for(int i=0;i<8;i++) cjA[i] = 0;
      {
        short4v c4 = *(const short4v*)(sCjPk + (jf*16 + lr)*8 + (lg >> 1)*4);
        cjA[0] = c4[0]; cjA[1] = c4[1]; cjA[2] = c4[2];
      }
      f32x4 nj4 = *(const f32x4*)(sNj + jf*16 + lg*4);
      f32x4 cin;
      #pragma unroll
      for(int r=0;r<4;r++) cin[r] = ni + nj4[r];
      f32x4 d2t = MFMA16(cjA, ciB, cin);
      #pragma unroll
      for(int r=0;r<4;r++){
        float d2 = d2t[r];
        float tt = fminf(fmaxf(d2, sig2), nine);
        float arg2 = tt * inv2l;
        float sv = s[jf][r];
        sv *= EXP2F(sv < 0.f ? arg2 : -arg2);
        if(d2 > nine) sv = -1e30f;
        s[jf][r] = sv;
      }
    }
    // scalar online softmax for q = lr (values spread over {jf,r} regs and lg-lanes)
    float pm = s[0][0];
    #pragma unroll
    for(int jf=0;jf<4;jf++)
      #pragma unroll
      for(int r=0;r<4;r++) pm = fmaxf(pm, s[jf][r]);
    pm = fmaxf(pm, __shfl_xor(pm, 16));
    pm = fmaxf(pm, __shfl_xor(pm, 32));
    float mn = fmaxf(m, pm);
    float fr = EXP2F(m - mn);
    m = mn;
    float ps = 0.f;
    #pragma unroll
    for(int jf=0;jf<4;jf++)
      #pragma unroll
      for(int r=0;r<4;r++){
        float p = EXP2F(s[jf][r] - m);
        s[jf][r] = p;
        ps += p;
      }
    ps += __shfl_xor(ps, 16);
    ps += __shfl_xor(ps, 32);
    l = l*fr + ps;
    // rescale oacc rows (q = lg*4 + r): fetch fr of those q's
    float frq[4];
    #pragma unroll
    for(int r=0;r<4;r++) frq[r] = __shfl(fr, lg*4 + r);
    #pragma unroll
    for(int c=0;c<4;c++)
      #pragma unroll
      for(int r=0;r<4;r++) oacc[c][r] *= frq[r];
    // P -> sP[q][k]: lane owns 4 consecutive k per jf -> pack + one b64 store each
    #pragma unroll
    for(int jf=0;jf<4;jf++){
      uint2v wds;
      wds.x = cvtpk_bf16(s[jf][0], s[jf][1]);
      wds.y = cvtpk_bf16(s[jf][2], s[jf][3]);
      *(uint2v*)(&sP[w][lr][jf*16 + lg*4]) = wds;
    }
    // PV: A = P (rows q) from contiguous sP, B = V^T (unchanged)
    #pragma unroll
    for(int js=0;js<2;js++){
      bf16x8 pa = *(const bf16x8*)(&sP[w][lr][js*32 + lg*8]);
      #pragma unroll
      for(int cf=0; cf<4; cf++){
        int vrow = cf*16 + lr, vc = js*4 + lg;
        bf16x8 vb = *(const bf16x8*)(sV + swz(vrow,vc)*8);
        oacc[cf] = MFMA16(pa, vb, oacc[cf]);
      }
    }
    __syncthreads();
  }
  // epilogue: X[b*2048+i][h*64+c] hi/lo split; l for q = lg*4+r via shfl
  float lq[4];
  #pragma unroll
  for(int r=0;r<4;r++) lq[r] = __shfl(l, lg*4 + r);
  #pragma unroll
  for(int cf=0; cf<4; cf++){
    #pragma unroll
    for(int r=0;r<4;r++){
      float v = oacc[cf][r] / lq[r];
      long idx = (long)(b*2048 + i0 + w*16 + lg*4 + r)*512 + h*64 + cf*16 + lr;
      short hh = f2bf(v);
      Xhi[idx] = hh;
      Xlo[idx] = f2bf(v - bf2f(hh));
    }
  }
}

// ---------------- host ----------------
extern "C" void kernel_launch(void* const* d_in, const int* in_sizes, int n_in,
                              void* d_out, int out_size, void* d_ws, size_t ws_size,
                              hipStream_t stream){
  const float* q  = (const float*)d_in[0];
  const float* k  = (const float*)d_in[1];
  const float* v  = (const float*)d_in[2];
  const float* coords = (const float*)d_in[3];
  const unsigned char* kpm = (const unsigned char*)d_in[4];
  const float* qp = (const float*)d_in[5];
  const float* kp = (const float*)d_in[6];
  const float* vp = (const float*)d_in[7];
  const float* ow = (const float*)d_in[8];
  const float* ob = (const float*)d_in[9];
  float* out = (float*)d_out;

  char* ws = (char*)d_ws;
  const size_t S = (size_t)4096*512*2;      // one bf16 [4096][512] plane
  const size_t P = (size_t)512*512*2;       // one bf16 [512][512] plane
  if(ws_size < 12*S + 7*P) return;
  short* q_hi = (short*)(ws + 0*S);
  short* q_lo = (short*)(ws + 1*S);
  short* k_hi = (short*)(ws + 2*S);
  short* k_lo = (short*)(ws + 3*S);
  short* v_hi = (short*)(ws + 4*S);
  short* qhHi = (short*)(ws + 5*S);
  short* qhLo = (short*)(ws + 6*S);
  short* khHi = (short*)(ws + 7*S);
  short* khLo = (short*)(ws + 8*S);
  short* vt   = (short*)(ws + 9*S);
  short* Xhi  = (short*)(ws + 10*S);
  short* Xlo  = (short*)(ws + 11*S);
  char* ws2 = ws + 12*S;
  short* BqHi = (short*)(ws2 + 0*P);
  short* BqLo = (short*)(ws2 + 1*P);
  short* BkHi = (short*)(ws2 + 2*P);
  short* BkLo = (short*)(ws2 + 3*P);
  short* BvHi = (short*)(ws2 + 4*P);
  short* WHi  = (short*)(ws2 + 5*P);
  short* WLo  = (short*)(ws2 + 6*P);

  SpreadArgs sa;
  for(int hh=0; hh<8; hh++){
    double t  = (1.0 - 0.02) * (double)hh / 7.0;
    double lg = pow(20.0, t);
    double sp = 3.7 + (lg - 1.0) / 19.0 * (20.0 - 3.7);
    float spf = (float)sp;
    sa.sig2[hh] = spf*spf;
    sa.nine[hh] = 9.f*spf*spf;
    sa.inv2l[hh] = 1.44269504f/(2.f*spf*spf);
  }

  const int NQ = 4096*512;
  split3<<<dim3(NQ/1024, 3), dim3(256), 0, stream>>>(q, k, v, q_hi, q_lo, k_hi, k_lo, v_hi);
  split_proj4<<<dim3(1024, 4), dim3(256), 0, stream>>>(qp, kp, vp, ow,
      BqHi, BqLo, BkHi, BkLo, BvHi, WHi, WLo);

  gemm_qkv<<<dim3(32, 8, 3), dim3(256), 0, stream>>>(
      q_hi, q_lo, k_hi, k_lo, v_hi,
      BqHi, BqLo, BkHi, BkLo, BvHi,
      qhHi, qhLo, khHi, khLo, vt);

  attn_k<<<dim3(512), dim3(256), 0, stream>>>(qhHi, qhLo, khHi, khLo, vt,
        coords, kpm, Xhi, Xlo, sa);

  gemm_k<3,2><<<dim3(32, 8), dim3(256), 0, stream>>>(Xhi, Xlo, WHi, WLo,
        nullptr, nullptr, out, ob, 1.f);
}

// Round 15
// 136.103 us; speedup vs baseline: 1.4323x; 1.0047x over previous
//
#include <hip/hip_runtime.h>
#include <hip/hip_bf16.h>
#include <cmath>

typedef __attribute__((ext_vector_type(8))) short bf16x8;
typedef __attribute__((ext_vector_type(4))) float f32x4;
typedef __attribute__((ext_vector_type(4))) short short4v;
typedef __attribute__((ext_vector_type(2))) unsigned int uint2v;

#define MFMA16(a,b,c) __builtin_amdgcn_mfma_f32_16x16x32_bf16((a),(b),(c),0,0,0)
#define EXP2F(x) __builtin_amdgcn_exp2f(x)
// async global->LDS 16B: LDS dest is lane-ordered linear; source carries the swizzle
#define GLOAD_LDS16(g, l) __builtin_amdgcn_global_load_lds( \
    (const __attribute__((address_space(1))) unsigned int*)(g), \
    (__attribute__((address_space(3))) unsigned int*)(l), 16, 0, 0)

__device__ __forceinline__ short f2bf(float x){
  unsigned u = __float_as_uint(x);
  u += 0x7fffu + ((u >> 16) & 1u);          // RNE
  return (short)(u >> 16);
}
__device__ __forceinline__ float bf2f(short h){
  return __uint_as_float(((unsigned)(unsigned short)h) << 16);
}
__device__ __forceinline__ unsigned cvtpk_bf16(float a, float b){
  unsigned r;
  asm("v_cvt_pk_bf16_f32 %0, %1, %2" : "=v"(r) : "v"(a), "v"(b));
  return r;                                  // lo16 = bf16(a), hi16 = bf16(b)
}
// 16B-chunk XOR swizzle within a [rows][64-short] tile; unit = 8 shorts
__device__ __forceinline__ int swz(int row, int c){ return (row << 3) | (c ^ (row & 7)); }

// ---------------- split kernels ----------------
// q,k,v -> hi/lo (v: hi only), one dispatch, float4-vectorized
__global__ void split3(const float* __restrict__ q, const float* __restrict__ k,
                       const float* __restrict__ v,
                       short* __restrict__ q_hi, short* __restrict__ q_lo,
                       short* __restrict__ k_hi, short* __restrict__ k_lo,
                       short* __restrict__ v_hi){
  int y = blockIdx.y;
  int i4 = (blockIdx.x * 256 + threadIdx.x) * 4;
  if(y == 0){
    float4 x = *(const float4*)(q + i4);
    short4v hi, lo;
    float xs[4] = {x.x, x.y, x.z, x.w};
    #pragma unroll
    for(int r=0;r<4;r++){ short h = f2bf(xs[r]); hi[r]=h; lo[r]=f2bf(xs[r]-bf2f(h)); }
    *(short4v*)(q_hi + i4) = hi; *(short4v*)(q_lo + i4) = lo;
  } else if(y == 1){
    float4 x = *(const float4*)(k + i4);
    short4v hi, lo;
    float xs[4] = {x.x, x.y, x.z, x.w};
    #pragma unroll
    for(int r=0;r<4;r++){ short h = f2bf(xs[r]); hi[r]=h; lo[r]=f2bf(xs[r]-bf2f(h)); }
    *(short4v*)(k_hi + i4) = hi; *(short4v*)(k_lo + i4) = lo;
  } else {
    float4 x = *(const float4*)(v + i4);
    short4v hi;
    float xs[4] = {x.x, x.y, x.z, x.w};
    #pragma unroll
    for(int r=0;r<4;r++) hi[r] = f2bf(xs[r]);
    *(short4v*)(v_hi + i4) = hi;
  }
}

// proj [8][512][64] -> BT [512][512], BT[h*64+c][d] = proj[h][d][c]; + ow split (y=3)
__global__ void split_proj4(const float* __restrict__ qp, const float* __restrict__ kp,
                            const float* __restrict__ vp, const float* __restrict__ ow,
                            short* __restrict__ BqHi, short* __restrict__ BqLo,
                            short* __restrict__ BkHi, short* __restrict__ BkLo,
                            short* __restrict__ BvHi,
                            short* __restrict__ WHi,  short* __restrict__ WLo){
  int y = blockIdx.y;
  int i = blockIdx.x * 256 + threadIdx.x;   // i = n*512 + d
  int n = i >> 9, d = i & 511;
  int h = n >> 6, c = n & 63;
  long si = (long)((h << 15) | (d << 6) | c);
  if(y == 0){
    float x = qp[si]; short hh = f2bf(x);
    BqHi[i] = hh; BqLo[i] = f2bf(x - bf2f(hh));
  } else if(y == 1){
    float x = kp[si]; short hh = f2bf(x);
    BkHi[i] = hh; BkLo[i] = f2bf(x - bf2f(hh));
  } else if(y == 2){
    BvHi[i] = f2bf(vp[si]);
  } else {
    float x = ow[i]; short hh = f2bf(x);    // ow [512][512] row-major used as BT directly
    WHi[i] = hh; WLo[i] = f2bf(x - bf2f(hh));
  }
}

// ---------------- fused projection GEMM (q,k,v in one dispatch via z) ----------------
// C[4096x512] = A[4096x512] * BT[512x512]^T
// z=0: q (3-prod, hi/lo out, scale 0.125*log2e); z=1: k (3-prod, hi/lo out); z=2: v (1-prod, vt out)
__global__ __launch_bounds__(256) void gemm_qkv(
    const short* __restrict__ q_hi, const short* __restrict__ q_lo,
    const short* __restrict__ k_hi, const short* __restrict__ k_lo,
    const short* __restrict__ v_hi,
    const short* __restrict__ BqHi, const short* __restrict__ BqLo,
    const short* __restrict__ BkHi, const short* __restrict__ BkLo,
    const short* __restrict__ BvHi,
    short* __restrict__ qhHi, short* __restrict__ qhLo,
    short* __restrict__ khHi, short* __restrict__ khLo,
    short* __restrict__ vt)
{
  constexpr int K = 512;
  __shared__ __attribute__((aligned(16))) short sAhi[128*64];
  __shared__ __attribute__((aligned(16))) short sBhi[64*64];
  __shared__ __attribute__((aligned(16))) short sAlo[128*64];
  __shared__ __attribute__((aligned(16))) short sBlo[64*64];
  const int tid = threadIdx.x;
  const int z = blockIdx.z;
  const bool three = (z < 2);
  const short* Ahi = z==0 ? q_hi : z==1 ? k_hi : v_hi;
  const short* Alo = z==0 ? q_lo : k_lo;
  const short* Bhi = z==0 ? BqHi : z==1 ? BkHi : BvHi;
  const short* Blo = z==0 ? BqLo : BkLo;
  const float scale = z==0 ? 0.125f*1.44269504f : 1.f;   // fold log2(e) -> exp2 softmax domain
  const int m0 = blockIdx.x * 128, n0 = blockIdx.y * 64;
  const int w = tid >> 6, lane = tid & 63;
  const int wm = (w >> 1) * 64, wn = (w & 1) * 32;
  const int lr = lane & 15, lg = lane >> 4;

  f32x4 acc[4][2];
  for(int i=0;i<4;i++) for(int j=0;j<2;j++) acc[i][j] = f32x4{0.f,0.f,0.f,0.f};

  for(int kt = 0; kt < K; kt += 64){
    __syncthreads();
    // async staging: LDS written linearly (lane order); source column pre-swizzled
    for(int u = tid; u < 1024; u += 256){
      int row = u >> 3, c = u & 7;
      long ga = (long)(m0 + row) * K + kt + (c ^ (row & 7))*8;
      GLOAD_LDS16(Ahi + ga, sAhi + u*8);
      if(three) GLOAD_LDS16(Alo + ga, sAlo + u*8);
    }
    for(int u = tid; u < 512; u += 256){
      int row = u >> 3, c = u & 7;
      long ga = (long)(n0 + row) * K + kt + (c ^ (row & 7))*8;
      GLOAD_LDS16(Bhi + ga, sBhi + u*8);
      if(three) GLOAD_LDS16(Blo + ga, sBlo + u*8);
    }
    __syncthreads();
    #pragma unroll
    for(int ks = 0; ks < 2; ks++){
      bf16x8 ah[4], al[4], bh[2], bl[2];
      #pragma unroll
      for(int i=0;i<4;i++){
        int row = wm + i*16 + lr, c = ks*4 + lg;
        ah[i] = *(const bf16x8*)(sAhi + swz(row,c)*8);
        if(three) al[i] = *(const bf16x8*)(sAlo + swz(row,c)*8);
      }
      #pragma unroll
      for(int j=0;j<2;j++){
        int row = wn + j*16 + lr, c = ks*4 + lg;
        bh[j] = *(const bf16x8*)(sBhi + swz(row,c)*8);
        if(three) bl[j] = *(const bf16x8*)(sBlo + swz(row,c)*8);
      }
      #pragma unroll
      for(int i=0;i<4;i++)
        #pragma unroll
        for(int j=0;j<2;j++){
          acc[i][j] = MFMA16(ah[i], bh[j], acc[i][j]);
          if(three){
            acc[i][j] = MFMA16(ah[i], bl[j], acc[i][j]);
            acc[i][j] = MFMA16(al[i], bh[j], acc[i][j]);
          }
        }
    }
  }
  // epilogue
  #pragma unroll
  for(int i=0;i<4;i++){
    #pragma unroll
    for(int j=0;j<2;j++){
      int row = m0 + wm + i*16 + lg*4;
      int col = n0 + wn + j*16 + lr;
      if(z == 2){
        int bb = row >> 11;
        int hh = col >> 6, cc = col & 63;
        short4v pk;
        #pragma unroll
        for(int r=0;r<4;r++) pk[r] = f2bf(acc[i][j][r]);
        long idx = ((long)((bb*8 + hh)*64 + cc) << 11) + (row & 2047);
        *(short4v*)(vt + idx) = pk;
      } else {
        short* O0 = z==0 ? qhHi : khHi;
        short* O1 = z==0 ? qhLo : khLo;
        #pragma unroll
        for(int r=0;r<4;r++){
          float v = acc[i][j][r] * scale;
          long idx = (long)(row + r) * 512 + col;
          short hh = f2bf(v);
          O0[idx] = hh;
          O1[idx] = f2bf(v - bf2f(hh));
        }
      }
    }
  }
}

// ---------------- GEMM template (used for the final GEMM) ----------------
template<int NPROD, int EPI>
__global__ __launch_bounds__(256) void gemm_k(
    const short* __restrict__ Ahi, const short* __restrict__ Alo,
    const short* __restrict__ Bhi, const short* __restrict__ Blo,
    short* __restrict__ O0, short* __restrict__ O1,
    float* __restrict__ Of, const float* __restrict__ bias, float scale)
{
  constexpr int K = 512;
  __shared__ __attribute__((aligned(16))) short sAhi[128*64];
  __shared__ __attribute__((aligned(16))) short sBhi[64*64];
  __shared__ __attribute__((aligned(16))) short sAlo[NPROD==3 ? 128*64 : 8];
  __shared__ __attribute__((aligned(16))) short sBlo[NPROD==3 ? 64*64 : 8];
  const int tid = threadIdx.x;
  const int m0 = blockIdx.x * 128, n0 = blockIdx.y * 64;
  const int w = tid >> 6, lane = tid & 63;
  const int wm = (w >> 1) * 64, wn = (w & 1) * 32;
  const int lr = lane & 15, lg = lane >> 4;

  f32x4 acc[4][2];
  for(int i=0;i<4;i++) for(int j=0;j<2;j++) acc[i][j] = f32x4{0.f,0.f,0.f,0.f};

  for(int kt = 0; kt < K; kt += 64){
    __syncthreads();
    for(int u = tid; u < 1024; u += 256){
      int row = u >> 3, c = u & 7;
      long ga = (long)(m0 + row) * K + kt + (c ^ (row & 7))*8;
      GLOAD_LDS16(Ahi + ga, sAhi + u*8);
      if(NPROD == 3) GLOAD_LDS16(Alo + ga, sAlo + u*8);
    }
    for(int u = tid; u < 512; u += 256){
      int row = u >> 3, c = u & 7;
      long ga = (long)(n0 + row) * K + kt + (c ^ (row & 7))*8;
      GLOAD_LDS16(Bhi + ga, sBhi + u*8);
      if(NPROD == 3) GLOAD_LDS16(Blo + ga, sBlo + u*8);
    }
    __syncthreads();
    #pragma unroll
    for(int ks = 0; ks < 2; ks++){
      bf16x8 ah[4], al[4], bh[2], bl[2];
      #pragma unroll
      for(int i=0;i<4;i++){
        int row = wm + i*16 + lr, c = ks*4 + lg;
        ah[i] = *(const bf16x8*)(sAhi + swz(row,c)*8);
        if(NPROD==3) al[i] = *(const bf16x8*)(sAlo + swz(row,c)*8);
      }
      #pragma unroll
      for(int j=0;j<2;j++){
        int row = wn + j*16 + lr, c = ks*4 + lg;
        bh[j] = *(const bf16x8*)(sBhi + swz(row,c)*8);
        if(NPROD==3) bl[j] = *(const bf16x8*)(sBlo + swz(row,c)*8);
      }
      #pragma unroll
      for(int i=0;i<4;i++)
        #pragma unroll
        for(int j=0;j<2;j++){
          acc[i][j] = MFMA16(ah[i], bh[j], acc[i][j]);
          if(NPROD==3){
            acc[i][j] = MFMA16(ah[i], bl[j], acc[i][j]);
            acc[i][j] = MFMA16(al[i], bh[j], acc[i][j]);
          }
        }
    }
  }
  #pragma unroll
  for(int i=0;i<4;i++){
    #pragma unroll
    for(int j=0;j<2;j++){
      int row = m0 + wm + i*16 + lg*4;
      int col = n0 + wn + j*16 + lr;
      if(EPI == 1){
        int bb = row >> 11;
        int hh = col >> 6, cc = col & 63;
        short4v pk;
        #pragma unroll
        for(int r=0;r<4;r++) pk[r] = f2bf(acc[i][j][r] * scale);
        long idx = ((long)((bb*8 + hh)*64 + cc) << 11) + (row & 2047);
        *(short4v*)(O0 + idx) = pk;
      } else {
        #pragma unroll
        for(int r=0;r<4;r++){
          float v = acc[i][j][r] * scale;
          long idx = (long)(row + r) * 512 + col;
          if(EPI == 0){
            short hh = f2bf(v);
            O0[idx] = hh;
            O1[idx] = f2bf(v - bf2f(hh));
          } else {
            Of[idx] = v + bias[col];
          }
        }
      }
    }
  }
}

// ---------------- fused attention (swapped QK^T; sP chunk-XOR swizzled) ----------------
struct SpreadArgs { float sig2[8]; float nine[8]; float inv2l[8]; };

__global__ __launch_bounds__(256) void attn_k(
    const short* __restrict__ qhHi, const short* __restrict__ qhLo,
    const short* __restrict__ khHi, const short* __restrict__ khLo,
    const short* __restrict__ vt,
    const float* __restrict__ coords,
    const unsigned char* __restrict__ kpm,
    short* __restrict__ Xhi, short* __restrict__ Xlo,
    SpreadArgs sa)
{
  __shared__ __attribute__((aligned(16))) short sKhi[64*64];
  __shared__ __attribute__((aligned(16))) short sKlo[64*64];
  __shared__ __attribute__((aligned(16))) short sV[64*64];
  __shared__ __attribute__((aligned(16))) short sCjPk[64*8];  // bf16 (-2cj: hx,hy,hz,0,lx,ly,lz,0)
  __shared__ __attribute__((aligned(16))) float sNj[64];      // |cj|^2 fp32 (+1e37 if masked)
  __shared__ __attribute__((aligned(16))) short sP[4][16*64]; // [wave][q-row 16 x k 64], chunk-XOR

  const int tid = threadIdx.x, w = tid >> 6, lane = tid & 63;
  const int lr = lane & 15, lg = lane >> 4;
  // XCD-locality swizzle (index-only): each XCD owns 2 (b,h) pairs, 32 i-blocks each.
  const int L = blockIdx.x;
  const int xcd = L & 7, ix = L >> 3;          // ix in [0,64)
  const int pair = xcd*2 + (ix >> 5);          // [0,16)
  const int b = pair >> 3, h = pair & 7, i0 = (ix & 31) * 64;
  const float sig2 = sa.sig2[h], nine = sa.nine[h], inv2l = sa.inv2l[h];

  // Q fragments (B-operand now; same data/layout as before: col=lr, k=lg*8+e)
  long qrow = (long)(b*2048 + i0 + w*16 + lr) * 512 + h*64;
  bf16x8 qhi[2], qlo[2];
  #pragma unroll
  for(int ks=0; ks<2; ks++){
    qhi[ks] = *(const bf16x8*)(qhHi + qrow + ks*32 + lg*8);
    qlo[ks] = *(const bf16x8*)(qhLo + qrow + ks*32 + lg*8);
  }
  // ci B-fragment for d^2 MFMA: col=lr -> q-row lr; k-groups (lg&1)==0 -> hi, ==1 -> lo
  bf16x8 ciB;
  #pragma unroll
  for(int i=0;i<8;i++) ciB[i] = 0;
  float ni;   // |ci|^2 of q-row lr (raw fp32)
  {
    long cb = (long)(b*2048 + i0 + w*16 + lr)*3;
    float c0 = coords[cb], c1 = coords[cb+1], c2 = coords[cb+2];
    float cs[3] = {c0, c1, c2};
    #pragma unroll
    for(int e=0;e<3;e++){
      short chi = f2bf(cs[e]);
      short clo = f2bf(cs[e] - bf2f(chi));
      ciB[e] = ((lg & 1) == 0) ? chi : clo;
    }
    ni = c0*c0 + c1*c1 + c2*c2;
  }
  f32x4 oacc[4];
  for(int c=0;c<4;c++) oacc[c] = f32x4{0.f,0.f,0.f,0.f};
  float m = -1e30f, l = 0.f;

  for(int jt=0; jt<32; jt++){
    int j0 = jt*64;
    // async staging (r10-proven mapping): LDS dest linear, source col inverse-swizzled
    for(int u=tid; u<512; u+=256){
      int row = u>>3, cc = u&7;
      int cs = cc ^ (row & 7);
      long gk = (long)(b*2048 + j0 + row)*512 + h*64 + cs*8;
      GLOAD_LDS16(khHi + gk, sKhi + u*8);
      GLOAD_LDS16(khLo + gk, sKlo + u*8);
      long gv = ((long)((b*8+h)*64 + row) << 11) + j0 + cs*8;
      GLOAD_LDS16(vt + gv, sV + u*8);
    }
    if(tid < 64){
      long cb = (long)(b*2048 + j0 + tid)*3;
      float cx = coords[cb], cy = coords[cb+1], cz = coords[cb+2];
      float mx = -2.f*cx, my = -2.f*cy, mz = -2.f*cz;
      short hx = f2bf(mx), hy = f2bf(my), hz = f2bf(mz);
      bf16x8 pk;
      pk[0] = hx; pk[1] = hy; pk[2] = hz; pk[3] = 0;
      pk[4] = f2bf(mx - bf2f(hx));
      pk[5] = f2bf(my - bf2f(hy));
      pk[6] = f2bf(mz - bf2f(hz));
      pk[7] = 0;
      *(bf16x8*)(sCjPk + tid*8) = pk;
      sNj[tid] = cx*cx + cy*cy + cz*cz + (kpm[b*2048 + j0 + tid] ? 1e37f : 0.f);
    }
    __syncthreads();

    // S^T via swapped MFMA: s[jf][r] = S[k = jf*16 + lg*4 + r][q = lr]
    f32x4 s[4];
    #pragma unroll
    for(int jf=0;jf<4;jf++){
      f32x4 t = f32x4{0.f,0.f,0.f,0.f};
      #pragma unroll
      for(int ks=0;ks<2;ks++){
        int row = jf*16 + lr, c = ks*4 + lg;
        bf16x8 bh = *(const bf16x8*)(sKhi + swz(row,c)*8);
        bf16x8 bl = *(const bf16x8*)(sKlo + swz(row,c)*8);
        t = MFMA16(bh, qhi[ks], t);
        t = MFMA16(bl, qhi[ks], t);
        t = MFMA16(bh, qlo[ks], t);
      }
      s[jf] = t;
    }
    // d^2 via swapped MFMA: d2[k][q] = (ni+nj) + (-2cj)·ci  (full hi/lo dot), then RBF
    #pragma unroll
    for(int jf=0;jf<4;jf++){
      bf16x8 cjA;
      #pragma unroll
      for(int i=0;i<8;i++) cjA[i] = 0;
      {
        short4v c4 = *(const short4v*)(sCjPk + (jf*16 + lr)*8 + (lg >> 1)*4);
        cjA[0] = c4[0]; cjA[1] = c4[1]; cjA[2] = c4[2];
      }
      f32x4 nj4 = *(const f32x4*)(sNj + jf*16 + lg*4);
      f32x4 cin;
      #pragma unroll
      for(int r=0;r<4;r++) cin[r] = ni + nj4[r];
      f32x4 d2t = MFMA16(cjA, ciB, cin);
      #pragma unroll
      for(int r=0;r<4;r++){
        float d2 = d2t[r];
        float tt = fminf(fmaxf(d2, sig2), nine);
        float arg2 = tt * inv2l;
        float sv = s[jf][r];
        sv *= EXP2F(sv < 0.f ? arg2 : -arg2);
        if(d2 > nine) sv = -1e30f;
        s[jf][r] = sv;
      }
    }
    // scalar online softmax for q = lr (values spread over {jf,r} regs and lg-lanes)
    float pm = s[0][0];
    #pragma unroll
    for(int jf=0;jf<4;jf++)
      #pragma unroll
      for(int r=0;r<4;r++) pm = fmaxf(pm, s[jf][r]);
    pm = fmaxf(pm, __shfl_xor(pm, 16));
    pm = fmaxf(pm, __shfl_xor(pm, 32));
    float mn = fmaxf(m, pm);
    float fr = EXP2F(m - mn);
    m = mn;
    float ps = 0.f;
    #pragma unroll
    for(int jf=0;jf<4;jf++)
      #pragma unroll
      for(int r=0;r<4;r++){
        float p = EXP2F(s[jf][r] - m);
        s[jf][r] = p;
        ps += p;
      }
    ps += __shfl_xor(ps, 16);
    ps += __shfl_xor(ps, 32);
    l = l*fr + ps;
    // rescale oacc rows (q = lg*4 + r): fetch fr of those q's
    float frq[4];
    #pragma unroll
    for(int r=0;r<4;r++) frq[r] = __shfl(fr, lg*4 + r);
    #pragma unroll
    for(int c=0;c<4;c++)
      #pragma unroll
      for(int r=0;r<4;r++) oacc[c][r] *= frq[r];
    // P -> sP[q][k] with the proven 16B-chunk XOR swizzle (write 8B halves)
    #pragma unroll
    for(int jf=0;jf<4;jf++){
      uint2v wds;
      wds.x = cvtpk_bf16(s[jf][0], s[jf][1]);
      wds.y = cvtpk_bf16(s[jf][2], s[jf][3]);
      int pc = (jf*2 + (lg >> 1)) ^ (lr & 7);
      *(uint2v*)(&sP[w][lr*64 + pc*8 + (lg & 1)*4]) = wds;
    }
    // PV: A = P (rows q) read with matching swizzle, B = V^T (unchanged)
    #pragma unroll
    for(int js=0;js<2;js++){
      bf16x8 pa = *(const bf16x8*)(&sP[w][lr*64 + (((js*4 + lg) ^ (lr & 7)) << 3)]);
      #pragma unroll
      for(int cf=0; cf<4; cf++){
        int vrow = cf*16 + lr, vc = js*4 + lg;
        bf16x8 vb = *(const bf16x8*)(sV + swz(vrow,vc)*8);
        oacc[cf] = MFMA16(pa, vb, oacc[cf]);
      }
    }
    __syncthreads();
  }
  // epilogue: X[b*2048+i][h*64+c] hi/lo split; 1/l broadcast for q = lg*4+r
  float rl = 1.f / l;
  float lq[4];
  #pragma unroll
  for(int r=0;r<4;r++) lq[r] = __shfl(rl, lg*4 + r);
  #pragma unroll
  for(int cf=0; cf<4; cf++){
    #pragma unroll
    for(int r=0;r<4;r++){
      float v = oacc[cf][r] * lq[r];
      long idx = (long)(b*2048 + i0 + w*16 + lg*4 + r)*512 + h*64 + cf*16 + lr;
      short hh = f2bf(v);
      Xhi[idx] = hh;
      Xlo[idx] = f2bf(v - bf2f(hh));
    }
  }
}

// ---------------- host ----------------
extern "C" void kernel_launch(void* const* d_in, const int* in_sizes, int n_in,
                              void* d_out, int out_size, void* d_ws, size_t ws_size,
                              hipStream_t stream){
  const float* q  = (const float*)d_in[0];
  const float* k  = (const float*)d_in[1];
  const float* v  = (const float*)d_in[2];
  const float* coords = (const float*)d_in[3];
  const unsigned char* kpm = (const unsigned char*)d_in[4];
  const float* qp = (const float*)d_in[5];
  const float* kp = (const float*)d_in[6];
  const float* vp = (const float*)d_in[7];
  const float* ow = (const float*)d_in[8];
  const float* ob = (const float*)d_in[9];
  float* out = (float*)d_out;

  char* ws = (char*)d_ws;
  const size_t S = (size_t)4096*512*2;      // one bf16 [4096][512] plane
  const size_t P = (size_t)512*512*2;       // one bf16 [512][512] plane
  if(ws_size < 12*S + 7*P) return;
  short* q_hi = (short*)(ws + 0*S);
  short* q_lo = (short*)(ws + 1*S);
  short* k_hi = (short*)(ws + 2*S);
  short* k_lo = (short*)(ws + 3*S);
  short* v_hi = (short*)(ws + 4*S);
  short* qhHi = (short*)(ws + 5*S);
  short* qhLo = (short*)(ws + 6*S);
  short* khHi = (short*)(ws + 7*S);
  short* khLo = (short*)(ws + 8*S);
  short* vt   = (short*)(ws + 9*S);
  short* Xhi  = (short*)(ws + 10*S);
  short* Xlo  = (short*)(ws + 11*S);
  char* ws2 = ws + 12*S;
  short* BqHi = (short*)(ws2 + 0*P);
  short* BqLo = (short*)(ws2 + 1*P);
  short* BkHi = (short*)(ws2 + 2*P);
  short* BkLo = (short*)(ws2 + 3*P);
  short* BvHi = (short*)(ws2 + 4*P);
  short* WHi  = (short*)(ws2 + 5*P);
  short* WLo  = (short*)(ws2 + 6*P);

  SpreadArgs sa;
  for(int hh=0; hh<8; hh++){
    double t  = (1.0 - 0.02) * (double)hh / 7.0;
    double lg = pow(20.0, t);
    double sp = 3.7 + (lg - 1.0) / 19.0 * (20.0 - 3.7);
    float spf = (float)sp;
    sa.sig2[hh] = spf*spf;
    sa.nine[hh] = 9.f*spf*spf;
    sa.inv2l[hh] = 1.44269504f/(2.f*spf*spf);
  }

  const int NQ = 4096*512;
  split3<<<dim3(NQ/1024, 3), dim3(256), 0, stream>>>(q, k, v, q_hi, q_lo, k_hi, k_lo, v_hi);
  split_proj4<<<dim3(1024, 4), dim3(256), 0, stream>>>(qp, kp, vp, ow,
      BqHi, BqLo, BkHi, BkLo, BvHi, WHi, WLo);

  gemm_qkv<<<dim3(32, 8, 3), dim3(256), 0, stream>>>(
      q_hi, q_lo, k_hi, k_lo, v_hi,
      BqHi, BqLo, BkHi, BkLo, BvHi,
      qhHi, qhLo, khHi, khLo, vt);

  attn_k<<<dim3(512), dim3(256), 0, stream>>>(qhHi, qhLo, khHi, khLo, vt,
        coords, kpm, Xhi, Xlo, sa);

  gemm_k<3,2><<<dim3(32, 8), dim3(256), 0, stream>>>(Xhi, Xlo, WHi, WLo,
        nullptr, nullptr, out, ob, 1.f);
}

// Round 17
// 129.818 us; speedup vs baseline: 1.5017x; 1.0484x over previous
//
#include <hip/hip_runtime.h>
#include <hip/hip_bf16.h>
#include <cmath>

typedef __attribute__((ext_vector_type(8))) short bf16x8;
typedef __attribute__((ext_vector_type(4))) float f32x4;
typedef __attribute__((ext_vector_type(4))) short short4v;
typedef __attribute__((ext_vector_type(2))) unsigned int uint2v;

#define MFMA16(a,b,c) __builtin_amdgcn_mfma_f32_16x16x32_bf16((a),(b),(c),0,0,0)
#define EXP2F(x) __builtin_amdgcn_exp2f(x)
// async global->LDS 16B: LDS dest is lane-ordered linear; source carries the swizzle
#define GLOAD_LDS16(g, l) __builtin_amdgcn_global_load_lds( \
    (const __attribute__((address_space(1))) unsigned int*)(g), \
    (__attribute__((address_space(3))) unsigned int*)(l), 16, 0, 0)

__device__ __forceinline__ short f2bf(float x){
  unsigned u = __float_as_uint(x);
  u += 0x7fffu + ((u >> 16) & 1u);          // RNE
  return (short)(u >> 16);
}
__device__ __forceinline__ float bf2f(short h){
  return __uint_as_float(((unsigned)(unsigned short)h) << 16);
}
__device__ __forceinline__ unsigned cvtpk_bf16(float a, float b){
  unsigned r;
  asm("v_cvt_pk_bf16_f32 %0, %1, %2" : "=v"(r) : "v"(a), "v"(b));
  return r;                                  // lo16 = bf16(a), hi16 = bf16(b)
}
// 16B-chunk XOR swizzle within a [rows][64-short] tile; unit = 8 shorts
__device__ __forceinline__ int swz(int row, int c){ return (row << 3) | (c ^ (row & 7)); }

// ---------------- split kernels ----------------
// q,k,v -> hi/lo (v: hi only), one dispatch, float4-vectorized
__global__ void split3(const float* __restrict__ q, const float* __restrict__ k,
                       const float* __restrict__ v,
                       short* __restrict__ q_hi, short* __restrict__ q_lo,
                       short* __restrict__ k_hi, short* __restrict__ k_lo,
                       short* __restrict__ v_hi){
  int y = blockIdx.y;
  int i4 = (blockIdx.x * 256 + threadIdx.x) * 4;
  if(y == 0){
    float4 x = *(const float4*)(q + i4);
    short4v hi, lo;
    float xs[4] = {x.x, x.y, x.z, x.w};
    #pragma unroll
    for(int r=0;r<4;r++){ short h = f2bf(xs[r]); hi[r]=h; lo[r]=f2bf(xs[r]-bf2f(h)); }
    *(short4v*)(q_hi + i4) = hi; *(short4v*)(q_lo + i4) = lo;
  } else if(y == 1){
    float4 x = *(const float4*)(k + i4);
    short4v hi, lo;
    float xs[4] = {x.x, x.y, x.z, x.w};
    #pragma unroll
    for(int r=0;r<4;r++){ short h = f2bf(xs[r]); hi[r]=h; lo[r]=f2bf(xs[r]-bf2f(h)); }
    *(short4v*)(k_hi + i4) = hi; *(short4v*)(k_lo + i4) = lo;
  } else {
    float4 x = *(const float4*)(v + i4);
    short4v hi;
    float xs[4] = {x.x, x.y, x.z, x.w};
    #pragma unroll
    for(int r=0;r<4;r++) hi[r] = f2bf(xs[r]);
    *(short4v*)(v_hi + i4) = hi;
  }
}

// proj [8][512][64] -> BT [512][512], BT[h*64+c][d] = proj[h][d][c]; + ow split (y=3)
__global__ void split_proj4(const float* __restrict__ qp, const float* __restrict__ kp,
                            const float* __restrict__ vp, const float* __restrict__ ow,
                            short* __restrict__ BqHi, short* __restrict__ BqLo,
                            short* __restrict__ BkHi, short* __restrict__ BkLo,
                            short* __restrict__ BvHi,
                            short* __restrict__ WHi,  short* __restrict__ WLo){
  int y = blockIdx.y;
  int i = blockIdx.x * 256 + threadIdx.x;   // i = n*512 + d
  int n = i >> 9, d = i & 511;
  int h = n >> 6, c = n & 63;
  long si = (long)((h << 15) | (d << 6) | c);
  if(y == 0){
    float x = qp[si]; short hh = f2bf(x);
    BqHi[i] = hh; BqLo[i] = f2bf(x - bf2f(hh));
  } else if(y == 1){
    float x = kp[si]; short hh = f2bf(x);
    BkHi[i] = hh; BkLo[i] = f2bf(x - bf2f(hh));
  } else if(y == 2){
    BvHi[i] = f2bf(vp[si]);
  } else {
    float x = ow[i]; short hh = f2bf(x);    // ow [512][512] row-major used as BT directly
    WHi[i] = hh; WLo[i] = f2bf(x - bf2f(hh));
  }
}

// ---------------- fused projection GEMM (q,k,v in one dispatch via z) ----------------
// C[4096x512] = A[4096x512] * BT[512x512]^T
// z=0: q (3-prod, hi/lo out, scale 0.125*log2e); z=1: k (3-prod, hi/lo out); z=2: v (1-prod, vt out)
__global__ __launch_bounds__(256) void gemm_qkv(
    const short* __restrict__ q_hi, const short* __restrict__ q_lo,
    const short* __restrict__ k_hi, const short* __restrict__ k_lo,
    const short* __restrict__ v_hi,
    const short* __restrict__ BqHi, const short* __restrict__ BqLo,
    const short* __restrict__ BkHi, const short* __restrict__ BkLo,
    const short* __restrict__ BvHi,
    short* __restrict__ qhHi, short* __restrict__ qhLo,
    short* __restrict__ khHi, short* __restrict__ khLo,
    short* __restrict__ vt)
{
  constexpr int K = 512;
  __shared__ __attribute__((aligned(16))) short sAhi[128*64];
  __shared__ __attribute__((aligned(16))) short sBhi[64*64];
  __shared__ __attribute__((aligned(16))) short sAlo[128*64];
  __shared__ __attribute__((aligned(16))) short sBlo[64*64];
  const int tid = threadIdx.x;
  const int z = blockIdx.z;
  const bool three = (z < 2);
  const short* Ahi = z==0 ? q_hi : z==1 ? k_hi : v_hi;
  const short* Alo = z==0 ? q_lo : k_lo;
  const short* Bhi = z==0 ? BqHi : z==1 ? BkHi : BvHi;
  const short* Blo = z==0 ? BqLo : BkLo;
  const float scale = z==0 ? 0.125f*1.44269504f : 1.f;   // fold log2(e) -> exp2 softmax domain
  const int m0 = blockIdx.x * 128, n0 = blockIdx.y * 64;
  const int w = tid >> 6, lane = tid & 63;
  const int wm = (w >> 1) * 64, wn = (w & 1) * 32;
  const int lr = lane & 15, lg = lane >> 4;

  f32x4 acc[4][2];
  for(int i=0;i<4;i++) for(int j=0;j<2;j++) acc[i][j] = f32x4{0.f,0.f,0.f,0.f};

  for(int kt = 0; kt < K; kt += 64){
    __syncthreads();
    // async staging: LDS written linearly (lane order); source column pre-swizzled
    for(int u = tid; u < 1024; u += 256){
      int row = u >> 3, c = u & 7;
      long ga = (long)(m0 + row) * K + kt + (c ^ (row & 7))*8;
      GLOAD_LDS16(Ahi + ga, sAhi + u*8);
      if(three) GLOAD_LDS16(Alo + ga, sAlo + u*8);
    }
    for(int u = tid; u < 512; u += 256){
      int row = u >> 3, c = u & 7;
      long ga = (long)(n0 + row) * K + kt + (c ^ (row & 7))*8;
      GLOAD_LDS16(Bhi + ga, sBhi + u*8);
      if(three) GLOAD_LDS16(Blo + ga, sBlo + u*8);
    }
    __syncthreads();
    #pragma unroll
    for(int ks = 0; ks < 2; ks++){
      bf16x8 ah[4], al[4], bh[2], bl[2];
      #pragma unroll
      for(int i=0;i<4;i++){
        int row = wm + i*16 + lr, c = ks*4 + lg;
        ah[i] = *(const bf16x8*)(sAhi + swz(row,c)*8);
        if(three) al[i] = *(const bf16x8*)(sAlo + swz(row,c)*8);
      }
      #pragma unroll
      for(int j=0;j<2;j++){
        int row = wn + j*16 + lr, c = ks*4 + lg;
        bh[j] = *(const bf16x8*)(sBhi + swz(row,c)*8);
        if(three) bl[j] = *(const bf16x8*)(sBlo + swz(row,c)*8);
      }
      #pragma unroll
      for(int i=0;i<4;i++)
        #pragma unroll
        for(int j=0;j<2;j++){
          acc[i][j] = MFMA16(ah[i], bh[j], acc[i][j]);
          if(three){
            acc[i][j] = MFMA16(ah[i], bl[j], acc[i][j]);
            acc[i][j] = MFMA16(al[i], bh[j], acc[i][j]);
          }
        }
    }
  }
  // epilogue
  #pragma unroll
  for(int i=0;i<4;i++){
    #pragma unroll
    for(int j=0;j<2;j++){
      int row = m0 + wm + i*16 + lg*4;
      int col = n0 + wn + j*16 + lr;
      if(z == 2){
        int bb = row >> 11;
        int hh = col >> 6, cc = col & 63;
        short4v pk;
        #pragma unroll
        for(int r=0;r<4;r++) pk[r] = f2bf(acc[i][j][r]);
        long idx = ((long)((bb*8 + hh)*64 + cc) << 11) + (row & 2047);
        *(short4v*)(vt + idx) = pk;
      } else {
        short* O0 = z==0 ? qhHi : khHi;
        short* O1 = z==0 ? qhLo : khLo;
        #pragma unroll
        for(int r=0;r<4;r++){
          float v = acc[i][j][r] * scale;
          long idx = (long)(row + r) * 512 + col;
          short hh = f2bf(v);
          O0[idx] = hh;
          O1[idx] = f2bf(v - bf2f(hh));
        }
      }
    }
  }
}

// ---------------- GEMM template (used for the final GEMM) ----------------
template<int NPROD, int EPI>
__global__ __launch_bounds__(256) void gemm_k(
    const short* __restrict__ Ahi, const short* __restrict__ Alo,
    const short* __restrict__ Bhi, const short* __restrict__ Blo,
    short* __restrict__ O0, short* __restrict__ O1,
    float* __restrict__ Of, const float* __restrict__ bias, float scale)
{
  constexpr int K = 512;
  __shared__ __attribute__((aligned(16))) short sAhi[128*64];
  __shared__ __attribute__((aligned(16))) short sBhi[64*64];
  __shared__ __attribute__((aligned(16))) short sAlo[NPROD==3 ? 128*64 : 8];
  __shared__ __attribute__((aligned(16))) short sBlo[NPROD==3 ? 64*64 : 8];
  const int tid = threadIdx.x;
  const int m0 = blockIdx.x * 128, n0 = blockIdx.y * 64;
  const int w = tid >> 6, lane = tid & 63;
  const int wm = (w >> 1) * 64, wn = (w & 1) * 32;
  const int lr = lane & 15, lg = lane >> 4;

  f32x4 acc[4][2];
  for(int i=0;i<4;i++) for(int j=0;j<2;j++) acc[i][j] = f32x4{0.f,0.f,0.f,0.f};

  for(int kt = 0; kt < K; kt += 64){
    __syncthreads();
    for(int u = tid; u < 1024; u += 256){
      int row = u >> 3, c = u & 7;
      long ga = (long)(m0 + row) * K + kt + (c ^ (row & 7))*8;
      GLOAD_LDS16(Ahi + ga, sAhi + u*8);
      if(NPROD == 3) GLOAD_LDS16(Alo + ga, sAlo + u*8);
    }
    for(int u = tid; u < 512; u += 256){
      int row = u >> 3, c = u & 7;
      long ga = (long)(n0 + row) * K + kt + (c ^ (row & 7))*8;
      GLOAD_LDS16(Bhi + ga, sBhi + u*8);
      if(NPROD == 3) GLOAD_LDS16(Blo + ga, sBlo + u*8);
    }
    __syncthreads();
    #pragma unroll
    for(int ks = 0; ks < 2; ks++){
      bf16x8 ah[4], al[4], bh[2], bl[2];
      #pragma unroll
      for(int i=0;i<4;i++){
        int row = wm + i*16 + lr, c = ks*4 + lg;
        ah[i] = *(const bf16x8*)(sAhi + swz(row,c)*8);
        if(NPROD==3) al[i] = *(const bf16x8*)(sAlo + swz(row,c)*8);
      }
      #pragma unroll
      for(int j=0;j<2;j++){
        int row = wn + j*16 + lr, c = ks*4 + lg;
        bh[j] = *(const bf16x8*)(sBhi + swz(row,c)*8);
        if(NPROD==3) bl[j] = *(const bf16x8*)(sBlo + swz(row,c)*8);
      }
      #pragma unroll
      for(int i=0;i<4;i++)
        #pragma unroll
        for(int j=0;j<2;j++){
          acc[i][j] = MFMA16(ah[i], bh[j], acc[i][j]);
          if(NPROD==3){
            acc[i][j] = MFMA16(ah[i], bl[j], acc[i][j]);
            acc[i][j] = MFMA16(al[i], bh[j], acc[i][j]);
          }
        }
    }
  }
  #pragma unroll
  for(int i=0;i<4;i++){
    #pragma unroll
    for(int j=0;j<2;j++){
      int row = m0 + wm + i*16 + lg*4;
      int col = n0 + wn + j*16 + lr;
      if(EPI == 1){
        int bb = row >> 11;
        int hh = col >> 6, cc = col & 63;
        short4v pk;
        #pragma unroll
        for(int r=0;r<4;r++) pk[r] = f2bf(acc[i][j][r] * scale);
        long idx = ((long)((bb*8 + hh)*64 + cc) << 11) + (row & 2047);
        *(short4v*)(O0 + idx) = pk;
      } else {
        #pragma unroll
        for(int r=0;r<4;r++){
          float v = acc[i][j][r] * scale;
          long idx = (long)(row + r) * 512 + col;
          if(EPI == 0){
            short hh = f2bf(v);
            O0[idx] = hh;
            O1[idx] = f2bf(v - bf2f(hh));
          } else {
            Of[idx] = v + bias[col];
          }
        }
      }
    }
  }
}

// ---------------- fused attention (r15 + med3/copysign/hoisting, offsets fixed) ----------------
struct SpreadArgs { float sig2[8]; float nine[8]; float inv2l[8]; };

__global__ __launch_bounds__(256) void attn_k(
    const short* __restrict__ qhHi, const short* __restrict__ qhLo,
    const short* __restrict__ khHi, const short* __restrict__ khLo,
    const short* __restrict__ vt,
    const float* __restrict__ coords,
    const unsigned char* __restrict__ kpm,
    short* __restrict__ Xhi, short* __restrict__ Xlo,
    SpreadArgs sa)
{
  __shared__ __attribute__((aligned(16))) short sKhi[64*64];
  __shared__ __attribute__((aligned(16))) short sKlo[64*64];
  __shared__ __attribute__((aligned(16))) short sV[64*64];
  __shared__ __attribute__((aligned(16))) short sCjPk[64*8];  // bf16 (-2cj: hx,hy,hz,0,lx,ly,lz,0)
  __shared__ __attribute__((aligned(16))) float sNj[64];      // |cj|^2 fp32 (+1e37 if masked)
  __shared__ __attribute__((aligned(16))) short sP[4][16*64]; // [wave][q 16 x k 64], chunk-XOR

  const int tid = threadIdx.x, w = tid >> 6, lane = tid & 63;
  const int lr = lane & 15, lg = lane >> 4;
  // XCD-locality swizzle (index-only): each XCD owns 2 (b,h) pairs, 32 i-blocks each.
  const int L = blockIdx.x;
  const int xcd = L & 7, ix = L >> 3;          // ix in [0,64)
  const int pair = xcd*2 + (ix >> 5);          // [0,16)
  const int b = pair >> 3, h = pair & 7, i0 = (ix & 31) * 64;
  const float sig2 = sa.sig2[h], nine = sa.nine[h], inv2l = sa.inv2l[h];

  // Q fragments (B-operand; col=lr, k=lg*8+e)
  long qrow = (long)(b*2048 + i0 + w*16 + lr) * 512 + h*64;
  bf16x8 qhi[2], qlo[2];
  #pragma unroll
  for(int ks=0; ks<2; ks++){
    qhi[ks] = *(const bf16x8*)(qhHi + qrow + ks*32 + lg*8);
    qlo[ks] = *(const bf16x8*)(qhLo + qrow + ks*32 + lg*8);
  }
  // ci B-fragment for d^2 MFMA: col=lr -> q-row lr; k-groups (lg&1)==0 -> hi, ==1 -> lo
  bf16x8 ciB;
  #pragma unroll
  for(int i=0;i<8;i++) ciB[i] = 0;
  float ni;   // |ci|^2 of q-row lr (raw fp32)
  {
    long cb = (long)(b*2048 + i0 + w*16 + lr)*3;
    float c0 = coords[cb], c1 = coords[cb+1], c2 = coords[cb+2];
    float cs[3] = {c0, c1, c2};
    #pragma unroll
    for(int e=0;e<3;e++){
      short chi = f2bf(cs[e]);
      short clo = f2bf(cs[e] - bf2f(chi));
      ciB[e] = ((lg & 1) == 0) ? chi : clo;
    }
    ni = c0*c0 + c1*c1 + c2*c2;
  }
  // ---- loop-invariant staging pointers / LDS offsets ----
  const short* pKh[2]; const short* pKl[2]; const short* pVt[2];
  #pragma unroll
  for(int it=0; it<2; ++it){
    int u = tid + it*256;
    int row = u >> 3, cc = u & 7;
    int cs = cc ^ (row & 7);
    pKh[it] = khHi + (long)(b*2048 + row)*512 + h*64 + cs*8;
    pKl[it] = khLo + (long)(b*2048 + row)*512 + h*64 + cs*8;
    pVt[it] = vt + (((long)((b*8+h)*64 + row)) << 11) + cs*8;
  }
  const float* pCo = coords + (long)(b*2048 + tid)*3;
  const unsigned char* pKp = kpm + b*2048 + tid;
  int ko[2];
  #pragma unroll
  for(int ks=0; ks<2; ks++)
    ko[ks] = lr*64 + (((ks*4 + lg) ^ (lr & 7)) << 3);   // + jf*1024 (K) / + cf*1024 (V) at use
  const int cjo = lr*8 + (lg >> 1)*4;                   // + jf*128 at use (8-short rows)
  int pwo[4];
  #pragma unroll
  for(int jf=0;jf<4;jf++)
    pwo[jf] = lr*64 + (((jf*2 + (lg >> 1)) ^ (lr & 7)) << 3) + (lg & 1)*4;
  int pro[2];
  #pragma unroll
  for(int js=0;js<2;js++)
    pro[js] = lr*64 + (((js*4 + lg) ^ (lr & 7)) << 3);

  f32x4 oacc[4];
  for(int c=0;c<4;c++) oacc[c] = f32x4{0.f,0.f,0.f,0.f};
  float m = -1e30f, l = 0.f;

  for(int jt=0; jt<32; jt++){
    // async staging (r10-proven mapping): LDS dest linear, source col inverse-swizzled
    #pragma unroll
    for(int it=0; it<2; ++it){
      int u8 = (tid + it*256)*8;
      GLOAD_LDS16(pKh[it], sKhi + u8);
      GLOAD_LDS16(pKl[it], sKlo + u8);
      GLOAD_LDS16(pVt[it], sV + u8);
      pKh[it] += 64*512; pKl[it] += 64*512; pVt[it] += 64;
    }
    if(tid < 64){
      float cx = pCo[0], cy = pCo[1], cz = pCo[2];
      float mx = -2.f*cx, my = -2.f*cy, mz = -2.f*cz;
      short hx = f2bf(mx), hy = f2bf(my), hz = f2bf(mz);
      bf16x8 pk;
      pk[0] = hx; pk[1] = hy; pk[2] = hz; pk[3] = 0;
      pk[4] = f2bf(mx - bf2f(hx));
      pk[5] = f2bf(my - bf2f(hy));
      pk[6] = f2bf(mz - bf2f(hz));
      pk[7] = 0;
      *(bf16x8*)(sCjPk + tid*8) = pk;
      sNj[tid] = cx*cx + cy*cy + cz*cz + (pKp[0] ? 1e37f : 0.f);
    }
    pCo += 64*3; pKp += 64;
    __syncthreads();

    // S^T via swapped MFMA: s[jf][r] = S[k = jf*16 + lg*4 + r][q = lr]
    f32x4 s[4];
    #pragma unroll
    for(int jf=0;jf<4;jf++){
      f32x4 t = f32x4{0.f,0.f,0.f,0.f};
      #pragma unroll
      for(int ks=0;ks<2;ks++){
        bf16x8 bh = *(const bf16x8*)(sKhi + ko[ks] + jf*1024);
        bf16x8 bl = *(const bf16x8*)(sKlo + ko[ks] + jf*1024);
        t = MFMA16(bh, qhi[ks], t);
        t = MFMA16(bl, qhi[ks], t);
        t = MFMA16(bh, qlo[ks], t);
      }
      s[jf] = t;
    }
    // d^2 via swapped MFMA: d2[k][q] = (ni+nj) + (-2cj)·ci  (full hi/lo dot), then RBF
    #pragma unroll
    for(int jf=0;jf<4;jf++){
      bf16x8 cjA;
      #pragma unroll
      for(int i=0;i<8;i++) cjA[i] = 0;
      {
        short4v c4 = *(const short4v*)(sCjPk + cjo + jf*128);
        cjA[0] = c4[0]; cjA[1] = c4[1]; cjA[2] = c4[2];
      }
      f32x4 nj4 = *(const f32x4*)(sNj + jf*16 + lg*4);
      f32x4 cin;
      #pragma unroll
      for(int r=0;r<4;r++) cin[r] = ni + nj4[r];
      f32x4 d2t = MFMA16(cjA, ciB, cin);
      #pragma unroll
      for(int r=0;r<4;r++){
        float d2 = d2t[r];
        float arg2 = __builtin_amdgcn_fmed3f(d2, sig2, nine) * inv2l;
        float sv = s[jf][r];
        sv *= EXP2F(-__builtin_copysignf(arg2, sv));
        if(d2 > nine) sv = -1e30f;
        s[jf][r] = sv;
      }
    }
    // scalar online softmax for q = lr (values spread over {jf,r} regs and lg-lanes)
    float pm = s[0][0];
    #pragma unroll
    for(int jf=0;jf<4;jf++)
      #pragma unroll
      for(int r=0;r<4;r++) pm = fmaxf(pm, s[jf][r]);
    pm = fmaxf(pm, __shfl_xor(pm, 16));
    pm = fmaxf(pm, __shfl_xor(pm, 32));
    float mn = fmaxf(m, pm);
    float fr = EXP2F(m - mn);
    m = mn;
    float ps = 0.f;
    #pragma unroll
    for(int jf=0;jf<4;jf++)
      #pragma unroll
      for(int r=0;r<4;r++){
        float p = EXP2F(s[jf][r] - m);
        s[jf][r] = p;
        ps += p;
      }
    ps += __shfl_xor(ps, 16);
    ps += __shfl_xor(ps, 32);
    l = l*fr + ps;
    // rescale oacc rows (q = lg*4 + r): fetch fr of those q's
    float frq[4];
    #pragma unroll
    for(int r=0;r<4;r++) frq[r] = __shfl(fr, lg*4 + r);
    #pragma unroll
    for(int c=0;c<4;c++)
      #pragma unroll
      for(int r=0;r<4;r++) oacc[c][r] *= frq[r];
    // P -> sP[q][k] with the proven 16B-chunk XOR swizzle (8B halves)
    #pragma unroll
    for(int jf=0;jf<4;jf++){
      uint2v wds;
      wds.x = cvtpk_bf16(s[jf][0], s[jf][1]);
      wds.y = cvtpk_bf16(s[jf][2], s[jf][3]);
      *(uint2v*)(&sP[w][pwo[jf]]) = wds;
    }
    // PV: A = P (rows q) read with matching swizzle, B = V^T
    #pragma unroll
    for(int js=0;js<2;js++){
      bf16x8 pa = *(const bf16x8*)(&sP[w][pro[js]]);
      #pragma unroll
      for(int cf=0; cf<4; cf++){
        bf16x8 vb = *(const bf16x8*)(sV + ko[js] + cf*1024);
        oacc[cf] = MFMA16(pa, vb, oacc[cf]);
      }
    }
    __syncthreads();
  }
  // epilogue: X[b*2048+i][h*64+c] hi/lo split; 1/l broadcast for q = lg*4+r
  float rl = 1.f / l;
  float lq[4];
  #pragma unroll
  for(int r=0;r<4;r++) lq[r] = __shfl(rl, lg*4 + r);
  #pragma unroll
  for(int cf=0; cf<4; cf++){
    #pragma unroll
    for(int r=0;r<4;r++){
      float v = oacc[cf][r] * lq[r];
      long idx = (long)(b*2048 + i0 + w*16 + lg*4 + r)*512 + h*64 + cf*16 + lr;
      short hh = f2bf(v);
      Xhi[idx] = hh;
      Xlo[idx] = f2bf(v - bf2f(hh));
    }
  }
}

// ---------------- host ----------------
extern "C" void kernel_launch(void* const* d_in, const int* in_sizes, int n_in,
                              void* d_out, int out_size, void* d_ws, size_t ws_size,
                              hipStream_t stream){
  const float* q  = (const float*)d_in[0];
  const float* k  = (const float*)d_in[1];
  const float* v  = (const float*)d_in[2];
  const float* coords = (const float*)d_in[3];
  const unsigned char* kpm = (const unsigned char*)d_in[4];
  const float* qp = (const float*)d_in[5];
  const float* kp = (const float*)d_in[6];
  const float* vp = (const float*)d_in[7];
  const float* ow = (const float*)d_in[8];
  const float* ob = (const float*)d_in[9];
  float* out = (float*)d_out;

  char* ws = (char*)d_ws;
  const size_t S = (size_t)4096*512*2;      // one bf16 [4096][512] plane
  const size_t P = (size_t)512*512*2;       // one bf16 [512][512] plane
  if(ws_size < 12*S + 7*P) return;
  short* q_hi = (short*)(ws + 0*S);
  short* q_lo = (short*)(ws + 1*S);
  short* k_hi = (short*)(ws + 2*S);
  short* k_lo = (short*)(ws + 3*S);
  short* v_hi = (short*)(ws + 4*S);
  short* qhHi = (short*)(ws + 5*S);
  short* qhLo = (short*)(ws + 6*S);
  short* khHi = (short*)(ws + 7*S);
  short* khLo = (short*)(ws + 8*S);
  short* vt   = (short*)(ws + 9*S);
  short* Xhi  = (short*)(ws + 10*S);
  short* Xlo  = (short*)(ws + 11*S);
  char* ws2 = ws + 12*S;
  short* BqHi = (short*)(ws2 + 0*P);
  short* BqLo = (short*)(ws2 + 1*P);
  short* BkHi = (short*)(ws2 + 2*P);
  short* BkLo = (short*)(ws2 + 3*P);
  short* BvHi = (short*)(ws2 + 4*P);
  short* WHi  = (short*)(ws2 + 5*P);
  short* WLo  = (short*)(ws2 + 6*P);

  SpreadArgs sa;
  for(int hh=0; hh<8; hh++){
    double t  = (1.0 - 0.02) * (double)hh / 7.0;
    double lg = pow(20.0, t);
    double sp = 3.7 + (lg - 1.0) / 19.0 * (20.0 - 3.7);
    float spf = (float)sp;
    sa.sig2[hh] = spf*spf;
    sa.nine[hh] = 9.f*spf*spf;
    sa.inv2l[hh] = 1.44269504f/(2.f*spf*spf);
  }

  const int NQ = 4096*512;
  split3<<<dim3(NQ/1024, 3), dim3(256), 0, stream>>>(q, k, v, q_hi, q_lo, k_hi, k_lo, v_hi);
  split_proj4<<<dim3(1024, 4), dim3(256), 0, stream>>>(qp, kp, vp, ow,
      BqHi, BqLo, BkHi, BkLo, BvHi, WHi, WLo);

  gemm_qkv<<<dim3(32, 8, 3), dim3(256), 0, stream>>>(
      q_hi, q_lo, k_hi, k_lo, v_hi,
      BqHi, BqLo, BkHi, BkLo, BvHi,
      qhHi, qhLo, khHi, khLo, vt);

  attn_k<<<dim3(512), dim3(256), 0, stream>>>(qhHi, qhLo, khHi, khLo, vt,
        coords, kpm, Xhi, Xlo, sa);

  gemm_k<3,2><<<dim3(32, 8), dim3(256), 0, stream>>>(Xhi, Xlo, WHi, WLo,
        nullptr, nullptr, out, ob, 1.f);
}

// Round 18
// 128.415 us; speedup vs baseline: 1.5181x; 1.0109x over previous
//
#include <hip/hip_runtime.h>
#include <hip/hip_bf16.h>
#include <cmath>

typedef __attribute__((ext_vector_type(8))) short bf16x8;
typedef __attribute__((ext_vector_type(4))) float f32x4;
typedef __attribute__((ext_vector_type(4))) short short4v;
typedef __attribute__((ext_vector_type(2))) unsigned int uint2v;

#define MFMA16(a,b,c) __builtin_amdgcn_mfma_f32_16x16x32_bf16((a),(b),(c),0,0,0)
#define EXP2F(x) __builtin_amdgcn_exp2f(x)
// async global->LDS 16B: LDS dest is lane-ordered linear; source carries the swizzle
#define GLOAD_LDS16(g, l) __builtin_amdgcn_global_load_lds( \
    (const __attribute__((address_space(1))) unsigned int*)(g), \
    (__attribute__((address_space(3))) unsigned int*)(l), 16, 0, 0)

__device__ __forceinline__ short f2bf(float x){
  unsigned u = __float_as_uint(x);
  u += 0x7fffu + ((u >> 16) & 1u);          // RNE
  return (short)(u >> 16);
}
__device__ __forceinline__ float bf2f(short h){
  return __uint_as_float(((unsigned)(unsigned short)h) << 16);
}
__device__ __forceinline__ unsigned cvtpk_bf16(float a, float b){
  unsigned r;
  asm("v_cvt_pk_bf16_f32 %0, %1, %2" : "=v"(r) : "v"(a), "v"(b));
  return r;                                  // lo16 = bf16(a), hi16 = bf16(b)
}
// 16B-chunk XOR swizzle within a [rows][64-short] tile; unit = 8 shorts
__device__ __forceinline__ int swz(int row, int c){ return (row << 3) | (c ^ (row & 7)); }

// ---------------- split kernels ----------------
// q,k,v -> hi/lo (v: hi only), one dispatch, float4-vectorized
__global__ void split3(const float* __restrict__ q, const float* __restrict__ k,
                       const float* __restrict__ v,
                       short* __restrict__ q_hi, short* __restrict__ q_lo,
                       short* __restrict__ k_hi, short* __restrict__ k_lo,
                       short* __restrict__ v_hi){
  int y = blockIdx.y;
  int i4 = (blockIdx.x * 256 + threadIdx.x) * 4;
  if(y == 0){
    float4 x = *(const float4*)(q + i4);
    short4v hi, lo;
    float xs[4] = {x.x, x.y, x.z, x.w};
    #pragma unroll
    for(int r=0;r<4;r++){ short h = f2bf(xs[r]); hi[r]=h; lo[r]=f2bf(xs[r]-bf2f(h)); }
    *(short4v*)(q_hi + i4) = hi; *(short4v*)(q_lo + i4) = lo;
  } else if(y == 1){
    float4 x = *(const float4*)(k + i4);
    short4v hi, lo;
    float xs[4] = {x.x, x.y, x.z, x.w};
    #pragma unroll
    for(int r=0;r<4;r++){ short h = f2bf(xs[r]); hi[r]=h; lo[r]=f2bf(xs[r]-bf2f(h)); }
    *(short4v*)(k_hi + i4) = hi; *(short4v*)(k_lo + i4) = lo;
  } else {
    float4 x = *(const float4*)(v + i4);
    short4v hi;
    float xs[4] = {x.x, x.y, x.z, x.w};
    #pragma unroll
    for(int r=0;r<4;r++) hi[r] = f2bf(xs[r]);
    *(short4v*)(v_hi + i4) = hi;
  }
}

// proj [8][512][64] -> BT [512][512], BT[h*64+c][d] = proj[h][d][c]; + ow split (y=3)
__global__ void split_proj4(const float* __restrict__ qp, const float* __restrict__ kp,
                            const float* __restrict__ vp, const float* __restrict__ ow,
                            short* __restrict__ BqHi, short* __restrict__ BqLo,
                            short* __restrict__ BkHi, short* __restrict__ BkLo,
                            short* __restrict__ BvHi,
                            short* __restrict__ WHi,  short* __restrict__ WLo){
  int y = blockIdx.y;
  int i = blockIdx.x * 256 + threadIdx.x;   // i = n*512 + d
  int n = i >> 9, d = i & 511;
  int h = n >> 6, c = n & 63;
  long si = (long)((h << 15) | (d << 6) | c);
  if(y == 0){
    float x = qp[si]; short hh = f2bf(x);
    BqHi[i] = hh; BqLo[i] = f2bf(x - bf2f(hh));
  } else if(y == 1){
    float x = kp[si]; short hh = f2bf(x);
    BkHi[i] = hh; BkLo[i] = f2bf(x - bf2f(hh));
  } else if(y == 2){
    BvHi[i] = f2bf(vp[si]);
  } else {
    float x = ow[i]; short hh = f2bf(x);    // ow [512][512] row-major used as BT directly
    WHi[i] = hh; WLo[i] = f2bf(x - bf2f(hh));
  }
}

// ---------------- fused projection GEMM (q,k,v in one dispatch via z) ----------------
// C[4096x512] = A[4096x512] * BT[512x512]^T
// z=0: q (3-prod, hi/lo out, scale 0.125*log2e); z=1: k (3-prod, hi/lo out); z=2: v (1-prod, vt out)
__global__ __launch_bounds__(256) void gemm_qkv(
    const short* __restrict__ q_hi, const short* __restrict__ q_lo,
    const short* __restrict__ k_hi, const short* __restrict__ k_lo,
    const short* __restrict__ v_hi,
    const short* __restrict__ BqHi, const short* __restrict__ BqLo,
    const short* __restrict__ BkHi, const short* __restrict__ BkLo,
    const short* __restrict__ BvHi,
    short* __restrict__ qhHi, short* __restrict__ qhLo,
    short* __restrict__ khHi, short* __restrict__ khLo,
    short* __restrict__ vt)
{
  constexpr int K = 512;
  __shared__ __attribute__((aligned(16))) short sAhi[128*64];
  __shared__ __attribute__((aligned(16))) short sBhi[64*64];
  __shared__ __attribute__((aligned(16))) short sAlo[128*64];
  __shared__ __attribute__((aligned(16))) short sBlo[64*64];
  const int tid = threadIdx.x;
  const int z = blockIdx.z;
  const bool three = (z < 2);
  const short* Ahi = z==0 ? q_hi : z==1 ? k_hi : v_hi;
  const short* Alo = z==0 ? q_lo : k_lo;
  const short* Bhi = z==0 ? BqHi : z==1 ? BkHi : BvHi;
  const short* Blo = z==0 ? BqLo : BkLo;
  const float scale = z==0 ? 0.125f*1.44269504f : 1.f;   // fold log2(e) -> exp2 softmax domain
  const int m0 = blockIdx.x * 128, n0 = blockIdx.y * 64;
  const int w = tid >> 6, lane = tid & 63;
  const int wm = (w >> 1) * 64, wn = (w & 1) * 32;
  const int lr = lane & 15, lg = lane >> 4;

  f32x4 acc[4][2];
  for(int i=0;i<4;i++) for(int j=0;j<2;j++) acc[i][j] = f32x4{0.f,0.f,0.f,0.f};

  for(int kt = 0; kt < K; kt += 64){
    __syncthreads();
    // async staging: LDS written linearly (lane order); source column pre-swizzled
    for(int u = tid; u < 1024; u += 256){
      int row = u >> 3, c = u & 7;
      long ga = (long)(m0 + row) * K + kt + (c ^ (row & 7))*8;
      GLOAD_LDS16(Ahi + ga, sAhi + u*8);
      if(three) GLOAD_LDS16(Alo + ga, sAlo + u*8);
    }
    for(int u = tid; u < 512; u += 256){
      int row = u >> 3, c = u & 7;
      long ga = (long)(n0 + row) * K + kt + (c ^ (row & 7))*8;
      GLOAD_LDS16(Bhi + ga, sBhi + u*8);
      if(three) GLOAD_LDS16(Blo + ga, sBlo + u*8);
    }
    __syncthreads();
    #pragma unroll
    for(int ks = 0; ks < 2; ks++){
      bf16x8 ah[4], al[4], bh[2], bl[2];
      #pragma unroll
      for(int i=0;i<4;i++){
        int row = wm + i*16 + lr, c = ks*4 + lg;
        ah[i] = *(const bf16x8*)(sAhi + swz(row,c)*8);
        if(three) al[i] = *(const bf16x8*)(sAlo + swz(row,c)*8);
      }
      #pragma unroll
      for(int j=0;j<2;j++){
        int row = wn + j*16 + lr, c = ks*4 + lg;
        bh[j] = *(const bf16x8*)(sBhi + swz(row,c)*8);
        if(three) bl[j] = *(const bf16x8*)(sBlo + swz(row,c)*8);
      }
      #pragma unroll
      for(int i=0;i<4;i++)
        #pragma unroll
        for(int j=0;j<2;j++){
          acc[i][j] = MFMA16(ah[i], bh[j], acc[i][j]);
          if(three){
            acc[i][j] = MFMA16(ah[i], bl[j], acc[i][j]);
            acc[i][j] = MFMA16(al[i], bh[j], acc[i][j]);
          }
        }
    }
  }
  // epilogue
  #pragma unroll
  for(int i=0;i<4;i++){
    #pragma unroll
    for(int j=0;j<2;j++){
      int row = m0 + wm + i*16 + lg*4;
      int col = n0 + wn + j*16 + lr;
      if(z == 2){
        int bb = row >> 11;
        int hh = col >> 6, cc = col & 63;
        short4v pk;
        #pragma unroll
        for(int r=0;r<4;r++) pk[r] = f2bf(acc[i][j][r]);
        long idx = ((long)((bb*8 + hh)*64 + cc) << 11) + (row & 2047);
        *(short4v*)(vt + idx) = pk;
      } else {
        short* O0 = z==0 ? qhHi : khHi;
        short* O1 = z==0 ? qhLo : khLo;
        #pragma unroll
        for(int r=0;r<4;r++){
          float v = acc[i][j][r] * scale;
          long idx = (long)(row + r) * 512 + col;
          short hh = f2bf(v);
          O0[idx] = hh;
          O1[idx] = f2bf(v - bf2f(hh));
        }
      }
    }
  }
}

// ---------------- GEMM template (used for the final GEMM) ----------------
template<int NPROD, int EPI>
__global__ __launch_bounds__(256) void gemm_k(
    const short* __restrict__ Ahi, const short* __restrict__ Alo,
    const short* __restrict__ Bhi, const short* __restrict__ Blo,
    short* __restrict__ O0, short* __restrict__ O1,
    float* __restrict__ Of, const float* __restrict__ bias, float scale)
{
  constexpr int K = 512;
  __shared__ __attribute__((aligned(16))) short sAhi[128*64];
  __shared__ __attribute__((aligned(16))) short sBhi[64*64];
  __shared__ __attribute__((aligned(16))) short sAlo[NPROD==3 ? 128*64 : 8];
  __shared__ __attribute__((aligned(16))) short sBlo[NPROD==3 ? 64*64 : 8];
  const int tid = threadIdx.x;
  const int m0 = blockIdx.x * 128, n0 = blockIdx.y * 64;
  const int w = tid >> 6, lane = tid & 63;
  const int wm = (w >> 1) * 64, wn = (w & 1) * 32;
  const int lr = lane & 15, lg = lane >> 4;

  f32x4 acc[4][2];
  for(int i=0;i<4;i++) for(int j=0;j<2;j++) acc[i][j] = f32x4{0.f,0.f,0.f,0.f};

  for(int kt = 0; kt < K; kt += 64){
    __syncthreads();
    for(int u = tid; u < 1024; u += 256){
      int row = u >> 3, c = u & 7;
      long ga = (long)(m0 + row) * K + kt + (c ^ (row & 7))*8;
      GLOAD_LDS16(Ahi + ga, sAhi + u*8);
      if(NPROD == 3) GLOAD_LDS16(Alo + ga, sAlo + u*8);
    }
    for(int u = tid; u < 512; u += 256){
      int row = u >> 3, c = u & 7;
      long ga = (long)(n0 + row) * K + kt + (c ^ (row & 7))*8;
      GLOAD_LDS16(Bhi + ga, sBhi + u*8);
      if(NPROD == 3) GLOAD_LDS16(Blo + ga, sBlo + u*8);
    }
    __syncthreads();
    #pragma unroll
    for(int ks = 0; ks < 2; ks++){
      bf16x8 ah[4], al[4], bh[2], bl[2];
      #pragma unroll
      for(int i=0;i<4;i++){
        int row = wm + i*16 + lr, c = ks*4 + lg;
        ah[i] = *(const bf16x8*)(sAhi + swz(row,c)*8);
        if(NPROD==3) al[i] = *(const bf16x8*)(sAlo + swz(row,c)*8);
      }
      #pragma unroll
      for(int j=0;j<2;j++){
        int row = wn + j*16 + lr, c = ks*4 + lg;
        bh[j] = *(const bf16x8*)(sBhi + swz(row,c)*8);
        if(NPROD==3) bl[j] = *(const bf16x8*)(sBlo + swz(row,c)*8);
      }
      #pragma unroll
      for(int i=0;i<4;i++)
        #pragma unroll
        for(int j=0;j<2;j++){
          acc[i][j] = MFMA16(ah[i], bh[j], acc[i][j]);
          if(NPROD==3){
            acc[i][j] = MFMA16(ah[i], bl[j], acc[i][j]);
            acc[i][j] = MFMA16(al[i], bh[j], acc[i][j]);
          }
        }
    }
  }
  #pragma unroll
  for(int i=0;i<4;i++){
    #pragma unroll
    for(int j=0;j<2;j++){
      int row = m0 + wm + i*16 + lg*4;
      int col = n0 + wn + j*16 + lr;
      if(EPI == 1){
        int bb = row >> 11;
        int hh = col >> 6, cc = col & 63;
        short4v pk;
        #pragma unroll
        for(int r=0;r<4;r++) pk[r] = f2bf(acc[i][j][r] * scale);
        long idx = ((long)((bb*8 + hh)*64 + cc) << 11) + (row & 2047);
        *(short4v*)(O0 + idx) = pk;
      } else {
        #pragma unroll
        for(int r=0;r<4;r++){
          float v = acc[i][j][r] * scale;
          long idx = (long)(row + r) * 512 + col;
          if(EPI == 0){
            short hh = f2bf(v);
            O0[idx] = hh;
            O1[idx] = f2bf(v - bf2f(hh));
          } else {
            Of[idx] = v + bias[col];
          }
        }
      }
    }
  }
}

// ---------------- fused attention (r17 + inv2l folded into d^2 MFMA) ----------------
struct SpreadArgs { float inv2l[8]; };

__global__ __launch_bounds__(256) void attn_k(
    const short* __restrict__ qhHi, const short* __restrict__ qhLo,
    const short* __restrict__ khHi, const short* __restrict__ khLo,
    const short* __restrict__ vt,
    const float* __restrict__ coords,
    const unsigned char* __restrict__ kpm,
    short* __restrict__ Xhi, short* __restrict__ Xlo,
    SpreadArgs sa)
{
  __shared__ __attribute__((aligned(16))) short sKhi[64*64];
  __shared__ __attribute__((aligned(16))) short sKlo[64*64];
  __shared__ __attribute__((aligned(16))) short sV[64*64];
  __shared__ __attribute__((aligned(16))) short sCjPk[64*8];  // bf16 (-2cj*inv2l hi/lo)
  __shared__ __attribute__((aligned(16))) float sNj[64];      // |cj|^2*inv2l (+1e37 if masked)
  __shared__ __attribute__((aligned(16))) short sP[4][16*64]; // [wave][q 16 x k 64], chunk-XOR

  // pre-scaled clamp bounds: sig2*inv2l = log2e/2, nine*inv2l = 9*log2e/2 (head-independent)
  const float C1 = 0.72134752f, C2 = 6.49212769f;

  const int tid = threadIdx.x, w = tid >> 6, lane = tid & 63;
  const int lr = lane & 15, lg = lane >> 4;
  // XCD-locality swizzle (index-only): each XCD owns 2 (b,h) pairs, 32 i-blocks each.
  const int L = blockIdx.x;
  const int xcd = L & 7, ix = L >> 3;          // ix in [0,64)
  const int pair = xcd*2 + (ix >> 5);          // [0,16)
  const int b = pair >> 3, h = pair & 7, i0 = (ix & 31) * 64;
  const float inv2l = sa.inv2l[h];

  // Q fragments (B-operand; col=lr, k=lg*8+e)
  long qrow = (long)(b*2048 + i0 + w*16 + lr) * 512 + h*64;
  bf16x8 qhi[2], qlo[2];
  #pragma unroll
  for(int ks=0; ks<2; ks++){
    qhi[ks] = *(const bf16x8*)(qhHi + qrow + ks*32 + lg*8);
    qlo[ks] = *(const bf16x8*)(qhLo + qrow + ks*32 + lg*8);
  }
  // ci B-fragment for d^2 MFMA: col=lr -> q-row lr; k-groups (lg&1)==0 -> hi, ==1 -> lo
  bf16x8 ciB;
  #pragma unroll
  for(int i=0;i<8;i++) ciB[i] = 0;
  float nis;  // |ci|^2 * inv2l of q-row lr
  {
    long cb = (long)(b*2048 + i0 + w*16 + lr)*3;
    float c0 = coords[cb], c1 = coords[cb+1], c2 = coords[cb+2];
    float cs[3] = {c0, c1, c2};
    #pragma unroll
    for(int e=0;e<3;e++){
      short chi = f2bf(cs[e]);
      short clo = f2bf(cs[e] - bf2f(chi));
      ciB[e] = ((lg & 1) == 0) ? chi : clo;
    }
    nis = (c0*c0 + c1*c1 + c2*c2) * inv2l;
  }
  // ---- loop-invariant staging pointers / LDS offsets ----
  const short* pKh[2]; const short* pKl[2]; const short* pVt[2];
  #pragma unroll
  for(int it=0; it<2; ++it){
    int u = tid + it*256;
    int row = u >> 3, cc = u & 7;
    int cs = cc ^ (row & 7);
    pKh[it] = khHi + (long)(b*2048 + row)*512 + h*64 + cs*8;
    pKl[it] = khLo + (long)(b*2048 + row)*512 + h*64 + cs*8;
    pVt[it] = vt + (((long)((b*8+h)*64 + row)) << 11) + cs*8;
  }
  const float* pCo = coords + (long)(b*2048 + tid)*3;
  const unsigned char* pKp = kpm + b*2048 + tid;
  int ko[2];
  #pragma unroll
  for(int ks=0; ks<2; ks++)
    ko[ks] = lr*64 + (((ks*4 + lg) ^ (lr & 7)) << 3);   // + jf*1024 (K) / + cf*1024 (V) at use
  const int cjo = lr*8 + (lg >> 1)*4;                   // + jf*128 at use (8-short rows)
  int pwo[4];
  #pragma unroll
  for(int jf=0;jf<4;jf++)
    pwo[jf] = lr*64 + (((jf*2 + (lg >> 1)) ^ (lr & 7)) << 3) + (lg & 1)*4;
  int pro[2];
  #pragma unroll
  for(int js=0;js<2;js++)
    pro[js] = lr*64 + (((js*4 + lg) ^ (lr & 7)) << 3);

  f32x4 oacc[4];
  for(int c=0;c<4;c++) oacc[c] = f32x4{0.f,0.f,0.f,0.f};
  float m = -1e30f, l = 0.f;

  for(int jt=0; jt<32; jt++){
    // async staging (r10-proven mapping): LDS dest linear, source col inverse-swizzled
    #pragma unroll
    for(int it=0; it<2; ++it){
      int u8 = (tid + it*256)*8;
      GLOAD_LDS16(pKh[it], sKhi + u8);
      GLOAD_LDS16(pKl[it], sKlo + u8);
      GLOAD_LDS16(pVt[it], sV + u8);
      pKh[it] += 64*512; pKl[it] += 64*512; pVt[it] += 64;
    }
    if(tid < 64){
      float cx = pCo[0], cy = pCo[1], cz = pCo[2];
      float sc = -2.f * inv2l;
      float mx = sc*cx, my = sc*cy, mz = sc*cz;
      short hx = f2bf(mx), hy = f2bf(my), hz = f2bf(mz);
      bf16x8 pk;
      pk[0] = hx; pk[1] = hy; pk[2] = hz; pk[3] = 0;
      pk[4] = f2bf(mx - bf2f(hx));
      pk[5] = f2bf(my - bf2f(hy));
      pk[6] = f2bf(mz - bf2f(hz));
      pk[7] = 0;
      *(bf16x8*)(sCjPk + tid*8) = pk;
      sNj[tid] = (cx*cx + cy*cy + cz*cz) * inv2l + (pKp[0] ? 1e37f : 0.f);
    }
    pCo += 64*3; pKp += 64;
    __syncthreads();

    // S^T via swapped MFMA: s[jf][r] = S[k = jf*16 + lg*4 + r][q = lr]
    f32x4 s[4];
    #pragma unroll
    for(int jf=0;jf<4;jf++){
      f32x4 t = f32x4{0.f,0.f,0.f,0.f};
      #pragma unroll
      for(int ks=0;ks<2;ks++){
        bf16x8 bh = *(const bf16x8*)(sKhi + ko[ks] + jf*1024);
        bf16x8 bl = *(const bf16x8*)(sKlo + ko[ks] + jf*1024);
        t = MFMA16(bh, qhi[ks], t);
        t = MFMA16(bl, qhi[ks], t);
        t = MFMA16(bh, qlo[ks], t);
      }
      s[jf] = t;
    }
    // d2' = d^2*inv2l via swapped MFMA: (nis+njs) + (-2cj*inv2l)·ci; then RBF with const bounds
    #pragma unroll
    for(int jf=0;jf<4;jf++){
      bf16x8 cjA;
      #pragma unroll
      for(int i=0;i<8;i++) cjA[i] = 0;
      {
        short4v c4 = *(const short4v*)(sCjPk + cjo + jf*128);
        cjA[0] = c4[0]; cjA[1] = c4[1]; cjA[2] = c4[2];
      }
      f32x4 nj4 = *(const f32x4*)(sNj + jf*16 + lg*4);
      f32x4 cin;
      #pragma unroll
      for(int r=0;r<4;r++) cin[r] = nis + nj4[r];
      f32x4 d2t = MFMA16(cjA, ciB, cin);
      #pragma unroll
      for(int r=0;r<4;r++){
        float d2 = d2t[r];
        float arg2 = __builtin_amdgcn_fmed3f(d2, C1, C2);
        float sv = s[jf][r];
        sv *= EXP2F(-__builtin_copysignf(arg2, sv));
        if(d2 > C2) sv = -1e30f;
        s[jf][r] = sv;
      }
    }
    // scalar online softmax for q = lr (values spread over {jf,r} regs and lg-lanes)
    float pm = s[0][0];
    #pragma unroll
    for(int jf=0;jf<4;jf++)
      #pragma unroll
      for(int r=0;r<4;r++) pm = fmaxf(pm, s[jf][r]);
    pm = fmaxf(pm, __shfl_xor(pm, 16));
    pm = fmaxf(pm, __shfl_xor(pm, 32));
    float mn = fmaxf(m, pm);
    float fr = EXP2F(m - mn);
    m = mn;
    float ps = 0.f;
    #pragma unroll
    for(int jf=0;jf<4;jf++)
      #pragma unroll
      for(int r=0;r<4;r++){
        float p = EXP2F(s[jf][r] - m);
        s[jf][r] = p;
        ps += p;
      }
    ps += __shfl_xor(ps, 16);
    ps += __shfl_xor(ps, 32);
    l = l*fr + ps;
    // rescale oacc rows (q = lg*4 + r): fetch fr of those q's
    float frq[4];
    #pragma unroll
    for(int r=0;r<4;r++) frq[r] = __shfl(fr, lg*4 + r);
    #pragma unroll
    for(int c=0;c<4;c++)
      #pragma unroll
      for(int r=0;r<4;r++) oacc[c][r] *= frq[r];
    // P -> sP[q][k] with the proven 16B-chunk XOR swizzle (8B halves)
    #pragma unroll
    for(int jf=0;jf<4;jf++){
      uint2v wds;
      wds.x = cvtpk_bf16(s[jf][0], s[jf][1]);
      wds.y = cvtpk_bf16(s[jf][2], s[jf][3]);
      *(uint2v*)(&sP[w][pwo[jf]]) = wds;
    }
    // PV: A = P (rows q) read with matching swizzle, B = V^T
    #pragma unroll
    for(int js=0;js<2;js++){
      bf16x8 pa = *(const bf16x8*)(&sP[w][pro[js]]);
      #pragma unroll
      for(int cf=0; cf<4; cf++){
        bf16x8 vb = *(const bf16x8*)(sV + ko[js] + cf*1024);
        oacc[cf] = MFMA16(pa, vb, oacc[cf]);
      }
    }
    __syncthreads();
  }
  // epilogue: X[b*2048+i][h*64+c] hi/lo split; 1/l broadcast for q = lg*4+r
  float rl = 1.f / l;
  float lq[4];
  #pragma unroll
  for(int r=0;r<4;r++) lq[r] = __shfl(rl, lg*4 + r);
  #pragma unroll
  for(int cf=0; cf<4; cf++){
    #pragma unroll
    for(int r=0;r<4;r++){
      float v = oacc[cf][r] * lq[r];
      long idx = (long)(b*2048 + i0 + w*16 + lg*4 + r)*512 + h*64 + cf*16 + lr;
      short hh = f2bf(v);
      Xhi[idx] = hh;
      Xlo[idx] = f2bf(v - bf2f(hh));
    }
  }
}

// ---------------- host ----------------
extern "C" void kernel_launch(void* const* d_in, const int* in_sizes, int n_in,
                              void* d_out, int out_size, void* d_ws, size_t ws_size,
                              hipStream_t stream){
  const float* q  = (const float*)d_in[0];
  const float* k  = (const float*)d_in[1];
  const float* v  = (const float*)d_in[2];
  const float* coords = (const float*)d_in[3];
  const unsigned char* kpm = (const unsigned char*)d_in[4];
  const float* qp = (const float*)d_in[5];
  const float* kp = (const float*)d_in[6];
  const float* vp = (const float*)d_in[7];
  const float* ow = (const float*)d_in[8];
  const float* ob = (const float*)d_in[9];
  float* out = (float*)d_out;

  char* ws = (char*)d_ws;
  const size_t S = (size_t)4096*512*2;      // one bf16 [4096][512] plane
  const size_t P = (size_t)512*512*2;       // one bf16 [512][512] plane
  if(ws_size < 12*S + 7*P) return;
  short* q_hi = (short*)(ws + 0*S);
  short* q_lo = (short*)(ws + 1*S);
  short* k_hi = (short*)(ws + 2*S);
  short* k_lo = (short*)(ws + 3*S);
  short* v_hi = (short*)(ws + 4*S);
  short* qhHi = (short*)(ws + 5*S);
  short* qhLo = (short*)(ws + 6*S);
  short* khHi = (short*)(ws + 7*S);
  short* khLo = (short*)(ws + 8*S);
  short* vt   = (short*)(ws + 9*S);
  short* Xhi  = (short*)(ws + 10*S);
  short* Xlo  = (short*)(ws + 11*S);
  char* ws2 = ws + 12*S;
  short* BqHi = (short*)(ws2 + 0*P);
  short* BqLo = (short*)(ws2 + 1*P);
  short* BkHi = (short*)(ws2 + 2*P);
  short* BkLo = (short*)(ws2 + 3*P);
  short* BvHi = (short*)(ws2 + 4*P);
  short* WHi  = (short*)(ws2 + 5*P);
  short* WLo  = (short*)(ws2 + 6*P);

  SpreadArgs sa;
  for(int hh=0; hh<8; hh++){
    double t  = (1.0 - 0.02) * (double)hh / 7.0;
    double lg = pow(20.0, t);
    double sp = 3.7 + (lg - 1.0) / 19.0 * (20.0 - 3.7);
    float spf = (float)sp;
    sa.inv2l[hh] = 1.44269504f/(2.f*spf*spf);
  }

  const int NQ = 4096*512;
  split3<<<dim3(NQ/1024, 3), dim3(256), 0, stream>>>(q, k, v, q_hi, q_lo, k_hi, k_lo, v_hi);
  split_proj4<<<dim3(1024, 4), dim3(256), 0, stream>>>(qp, kp, vp, ow,
      BqHi, BqLo, BkHi, BkLo, BvHi, WHi, WLo);

  gemm_qkv<<<dim3(32, 8, 3), dim3(256), 0, stream>>>(
      q_hi, q_lo, k_hi, k_lo, v_hi,
      BqHi, BqLo, BkHi, BkLo, BvHi,
      qhHi, qhLo, khHi, khLo, vt);

  attn_k<<<dim3(512), dim3(256), 0, stream>>>(qhHi, qhLo, khHi, khLo, vt,
        coords, kpm, Xhi, Xlo, sa);

  gemm_k<3,2><<<dim3(32, 8), dim3(256), 0, stream>>>(Xhi, Xlo, WHi, WLo,
        nullptr, nullptr, out, ob, 1.f);
}

// Round 19
// 127.339 us; speedup vs baseline: 1.5309x; 1.0085x over previous
//
#include <hip/hip_runtime.h>
#include <hip/hip_bf16.h>
#include <cmath>

typedef __attribute__((ext_vector_type(8))) short bf16x8;
typedef __attribute__((ext_vector_type(4))) float f32x4;
typedef __attribute__((ext_vector_type(4))) short short4v;
typedef __attribute__((ext_vector_type(2))) unsigned int uint2v;

#define MFMA16(a,b,c) __builtin_amdgcn_mfma_f32_16x16x32_bf16((a),(b),(c),0,0,0)
#define EXP2F(x) __builtin_amdgcn_exp2f(x)
// async global->LDS 16B: LDS dest is lane-ordered linear; source carries the swizzle
#define GLOAD_LDS16(g, l) __builtin_amdgcn_global_load_lds( \
    (const __attribute__((address_space(1))) unsigned int*)(g), \
    (__attribute__((address_space(3))) unsigned int*)(l), 16, 0, 0)

__device__ __forceinline__ short f2bf(float x){
  unsigned u = __float_as_uint(x);
  u += 0x7fffu + ((u >> 16) & 1u);          // RNE
  return (short)(u >> 16);
}
__device__ __forceinline__ float bf2f(short h){
  return __uint_as_float(((unsigned)(unsigned short)h) << 16);
}
__device__ __forceinline__ unsigned cvtpk_bf16(float a, float b){
  unsigned r;
  asm("v_cvt_pk_bf16_f32 %0, %1, %2" : "=v"(r) : "v"(a), "v"(b));
  return r;                                  // lo16 = bf16(a), hi16 = bf16(b)
}
// 16B-chunk XOR swizzle within a [rows][64-short] tile; unit = 8 shorts
__device__ __forceinline__ int swz(int row, int c){ return (row << 3) | (c ^ (row & 7)); }

// ---------------- split kernels ----------------
// q,k,v -> hi/lo (v: hi only), one dispatch, float4-vectorized
__global__ void split3(const float* __restrict__ q, const float* __restrict__ k,
                       const float* __restrict__ v,
                       short* __restrict__ q_hi, short* __restrict__ q_lo,
                       short* __restrict__ k_hi, short* __restrict__ k_lo,
                       short* __restrict__ v_hi){
  int y = blockIdx.y;
  int i4 = (blockIdx.x * 256 + threadIdx.x) * 4;
  if(y == 0){
    float4 x = *(const float4*)(q + i4);
    short4v hi, lo;
    float xs[4] = {x.x, x.y, x.z, x.w};
    #pragma unroll
    for(int r=0;r<4;r++){ short h = f2bf(xs[r]); hi[r]=h; lo[r]=f2bf(xs[r]-bf2f(h)); }
    *(short4v*)(q_hi + i4) = hi; *(short4v*)(q_lo + i4) = lo;
  } else if(y == 1){
    float4 x = *(const float4*)(k + i4);
    short4v hi, lo;
    float xs[4] = {x.x, x.y, x.z, x.w};
    #pragma unroll
    for(int r=0;r<4;r++){ short h = f2bf(xs[r]); hi[r]=h; lo[r]=f2bf(xs[r]-bf2f(h)); }
    *(short4v*)(k_hi + i4) = hi; *(short4v*)(k_lo + i4) = lo;
  } else {
    float4 x = *(const float4*)(v + i4);
    short4v hi;
    float xs[4] = {x.x, x.y, x.z, x.w};
    #pragma unroll
    for(int r=0;r<4;r++) hi[r] = f2bf(xs[r]);
    *(short4v*)(v_hi + i4) = hi;
  }
}

// proj [8][512][64] -> BT [512][512], BT[h*64+c][d] = proj[h][d][c]; + ow split (y=3)
__global__ void split_proj4(const float* __restrict__ qp, const float* __restrict__ kp,
                            const float* __restrict__ vp, const float* __restrict__ ow,
                            short* __restrict__ BqHi, short* __restrict__ BqLo,
                            short* __restrict__ BkHi, short* __restrict__ BkLo,
                            short* __restrict__ BvHi,
                            short* __restrict__ WHi,  short* __restrict__ WLo){
  int y = blockIdx.y;
  int i = blockIdx.x * 256 + threadIdx.x;   // i = n*512 + d
  int n = i >> 9, d = i & 511;
  int h = n >> 6, c = n & 63;
  long si = (long)((h << 15) | (d << 6) | c);
  if(y == 0){
    float x = qp[si]; short hh = f2bf(x);
    BqHi[i] = hh; BqLo[i] = f2bf(x - bf2f(hh));
  } else if(y == 1){
    float x = kp[si]; short hh = f2bf(x);
    BkHi[i] = hh; BkLo[i] = f2bf(x - bf2f(hh));
  } else if(y == 2){
    BvHi[i] = f2bf(vp[si]);
  } else {
    float x = ow[i]; short hh = f2bf(x);    // ow [512][512] row-major used as BT directly
    WHi[i] = hh; WLo[i] = f2bf(x - bf2f(hh));
  }
}

// ---------------- fused projection GEMM (q,k,v in one dispatch via z) ----------------
// C[4096x512] = A[4096x512] * BT[512x512]^T
// z=0: q (3-prod, hi/lo out, scale 0.125*log2e); z=1: k (3-prod, hi/lo out); z=2: v (1-prod, vt out)
__global__ __launch_bounds__(256) void gemm_qkv(
    const short* __restrict__ q_hi, const short* __restrict__ q_lo,
    const short* __restrict__ k_hi, const short* __restrict__ k_lo,
    const short* __restrict__ v_hi,
    const short* __restrict__ BqHi, const short* __restrict__ BqLo,
    const short* __restrict__ BkHi, const short* __restrict__ BkLo,
    const short* __restrict__ BvHi,
    short* __restrict__ qhHi, short* __restrict__ qhLo,
    short* __restrict__ khHi, short* __restrict__ khLo,
    short* __restrict__ vt)
{
  constexpr int K = 512;
  __shared__ __attribute__((aligned(16))) short sAhi[128*64];
  __shared__ __attribute__((aligned(16))) short sBhi[64*64];
  __shared__ __attribute__((aligned(16))) short sAlo[128*64];
  __shared__ __attribute__((aligned(16))) short sBlo[64*64];
  const int tid = threadIdx.x;
  const int z = blockIdx.z;
  const bool three = (z < 2);
  const short* Ahi = z==0 ? q_hi : z==1 ? k_hi : v_hi;
  const short* Alo = z==0 ? q_lo : k_lo;
  const short* Bhi = z==0 ? BqHi : z==1 ? BkHi : BvHi;
  const short* Blo = z==0 ? BqLo : BkLo;
  const float scale = z==0 ? 0.125f*1.44269504f : 1.f;   // fold log2(e) -> exp2 softmax domain
  const int m0 = blockIdx.x * 128, n0 = blockIdx.y * 64;
  const int w = tid >> 6, lane = tid & 63;
  const int wm = (w >> 1) * 64, wn = (w & 1) * 32;
  const int lr = lane & 15, lg = lane >> 4;

  f32x4 acc[4][2];
  for(int i=0;i<4;i++) for(int j=0;j<2;j++) acc[i][j] = f32x4{0.f,0.f,0.f,0.f};

  for(int kt = 0; kt < K; kt += 64){
    __syncthreads();
    // async staging: LDS written linearly (lane order); source column pre-swizzled
    for(int u = tid; u < 1024; u += 256){
      int row = u >> 3, c = u & 7;
      long ga = (long)(m0 + row) * K + kt + (c ^ (row & 7))*8;
      GLOAD_LDS16(Ahi + ga, sAhi + u*8);
      if(three) GLOAD_LDS16(Alo + ga, sAlo + u*8);
    }
    for(int u = tid; u < 512; u += 256){
      int row = u >> 3, c = u & 7;
      long ga = (long)(n0 + row) * K + kt + (c ^ (row & 7))*8;
      GLOAD_LDS16(Bhi + ga, sBhi + u*8);
      if(three) GLOAD_LDS16(Blo + ga, sBlo + u*8);
    }
    __syncthreads();
    #pragma unroll
    for(int ks = 0; ks < 2; ks++){
      bf16x8 ah[4], al[4], bh[2], bl[2];
      #pragma unroll
      for(int i=0;i<4;i++){
        int row = wm + i*16 + lr, c = ks*4 + lg;
        ah[i] = *(const bf16x8*)(sAhi + swz(row,c)*8);
        if(three) al[i] = *(const bf16x8*)(sAlo + swz(row,c)*8);
      }
      #pragma unroll
      for(int j=0;j<2;j++){
        int row = wn + j*16 + lr, c = ks*4 + lg;
        bh[j] = *(const bf16x8*)(sBhi + swz(row,c)*8);
        if(three) bl[j] = *(const bf16x8*)(sBlo + swz(row,c)*8);
      }
      #pragma unroll
      for(int i=0;i<4;i++)
        #pragma unroll
        for(int j=0;j<2;j++){
          acc[i][j] = MFMA16(ah[i], bh[j], acc[i][j]);
          if(three){
            acc[i][j] = MFMA16(ah[i], bl[j], acc[i][j]);
            acc[i][j] = MFMA16(al[i], bh[j], acc[i][j]);
          }
        }
    }
  }
  // epilogue
  #pragma unroll
  for(int i=0;i<4;i++){
    #pragma unroll
    for(int j=0;j<2;j++){
      int row = m0 + wm + i*16 + lg*4;
      int col = n0 + wn + j*16 + lr;
      if(z == 2){
        int bb = row >> 11;
        int hh = col >> 6, cc = col & 63;
        short4v pk;
        #pragma unroll
        for(int r=0;r<4;r++) pk[r] = f2bf(acc[i][j][r]);
        long idx = ((long)((bb*8 + hh)*64 + cc) << 11) + (row & 2047);
        *(short4v*)(vt + idx) = pk;
      } else {
        short* O0 = z==0 ? qhHi : khHi;
        short* O1 = z==0 ? qhLo : khLo;
        #pragma unroll
        for(int r=0;r<4;r++){
          float v = acc[i][j][r] * scale;
          long idx = (long)(row + r) * 512 + col;
          short hh = f2bf(v);
          O0[idx] = hh;
          O1[idx] = f2bf(v - bf2f(hh));
        }
      }
    }
  }
}

// ---------------- GEMM template (used for the final GEMM) ----------------
template<int NPROD, int EPI>
__global__ __launch_bounds__(256) void gemm_k(
    const short* __restrict__ Ahi, const short* __restrict__ Alo,
    const short* __restrict__ Bhi, const short* __restrict__ Blo,
    short* __restrict__ O0, short* __restrict__ O1,
    float* __restrict__ Of, const float* __restrict__ bias, float scale)
{
  constexpr int K = 512;
  __shared__ __attribute__((aligned(16))) short sAhi[128*64];
  __shared__ __attribute__((aligned(16))) short sBhi[64*64];
  __shared__ __attribute__((aligned(16))) short sAlo[NPROD==3 ? 128*64 : 8];
  __shared__ __attribute__((aligned(16))) short sBlo[NPROD==3 ? 64*64 : 8];
  const int tid = threadIdx.x;
  const int m0 = blockIdx.x * 128, n0 = blockIdx.y * 64;
  const int w = tid >> 6, lane = tid & 63;
  const int wm = (w >> 1) * 64, wn = (w & 1) * 32;
  const int lr = lane & 15, lg = lane >> 4;

  f32x4 acc[4][2];
  for(int i=0;i<4;i++) for(int j=0;j<2;j++) acc[i][j] = f32x4{0.f,0.f,0.f,0.f};

  for(int kt = 0; kt < K; kt += 64){
    __syncthreads();
    for(int u = tid; u < 1024; u += 256){
      int row = u >> 3, c = u & 7;
      long ga = (long)(m0 + row) * K + kt + (c ^ (row & 7))*8;
      GLOAD_LDS16(Ahi + ga, sAhi + u*8);
      if(NPROD == 3) GLOAD_LDS16(Alo + ga, sAlo + u*8);
    }
    for(int u = tid; u < 512; u += 256){
      int row = u >> 3, c = u & 7;
      long ga = (long)(n0 + row) * K + kt + (c ^ (row & 7))*8;
      GLOAD_LDS16(Bhi + ga, sBhi + u*8);
      if(NPROD == 3) GLOAD_LDS16(Blo + ga, sBlo + u*8);
    }
    __syncthreads();
    #pragma unroll
    for(int ks = 0; ks < 2; ks++){
      bf16x8 ah[4], al[4], bh[2], bl[2];
      #pragma unroll
      for(int i=0;i<4;i++){
        int row = wm + i*16 + lr, c = ks*4 + lg;
        ah[i] = *(const bf16x8*)(sAhi + swz(row,c)*8);
        if(NPROD==3) al[i] = *(const bf16x8*)(sAlo + swz(row,c)*8);
      }
      #pragma unroll
      for(int j=0;j<2;j++){
        int row = wn + j*16 + lr, c = ks*4 + lg;
        bh[j] = *(const bf16x8*)(sBhi + swz(row,c)*8);
        if(NPROD==3) bl[j] = *(const bf16x8*)(sBlo + swz(row,c)*8);
      }
      #pragma unroll
      for(int i=0;i<4;i++)
        #pragma unroll
        for(int j=0;j<2;j++){
          acc[i][j] = MFMA16(ah[i], bh[j], acc[i][j]);
          if(NPROD==3){
            acc[i][j] = MFMA16(ah[i], bl[j], acc[i][j]);
            acc[i][j] = MFMA16(al[i], bh[j], acc[i][j]);
          }
        }
    }
  }
  #pragma unroll
  for(int i=0;i<4;i++){
    #pragma unroll
    for(int j=0;j<2;j++){
      int row = m0 + wm + i*16 + lg*4;
      int col = n0 + wn + j*16 + lr;
      if(EPI == 1){
        int bb = row >> 11;
        int hh = col >> 6, cc = col & 63;
        short4v pk;
        #pragma unroll
        for(int r=0;r<4;r++) pk[r] = f2bf(acc[i][j][r] * scale);
        long idx = ((long)((bb*8 + hh)*64 + cc) << 11) + (row & 2047);
        *(short4v*)(O0 + idx) = pk;
      } else {
        #pragma unroll
        for(int r=0;r<4;r++){
          float v = acc[i][j][r] * scale;
          long idx = (long)(row + r) * 512 + col;
          if(EPI == 0){
            short hh = f2bf(v);
            O0[idx] = hh;
            O1[idx] = f2bf(v - bf2f(hh));
          } else {
            Of[idx] = v + bias[col];
          }
        }
      }
    }
  }
}

// ---------------- fused attention (r18 + s_setprio around MFMA clusters) ----------------
struct SpreadArgs { float inv2l[8]; };

__global__ __launch_bounds__(256) void attn_k(
    const short* __restrict__ qhHi, const short* __restrict__ qhLo,
    const short* __restrict__ khHi, const short* __restrict__ khLo,
    const short* __restrict__ vt,
    const float* __restrict__ coords,
    const unsigned char* __restrict__ kpm,
    short* __restrict__ Xhi, short* __restrict__ Xlo,
    SpreadArgs sa)
{
  __shared__ __attribute__((aligned(16))) short sKhi[64*64];
  __shared__ __attribute__((aligned(16))) short sKlo[64*64];
  __shared__ __attribute__((aligned(16))) short sV[64*64];
  __shared__ __attribute__((aligned(16))) short sCjPk[64*8];  // bf16 (-2cj*inv2l hi/lo)
  __shared__ __attribute__((aligned(16))) float sNj[64];      // |cj|^2*inv2l (+1e37 if masked)
  __shared__ __attribute__((aligned(16))) short sP[4][16*64]; // [wave][q 16 x k 64], chunk-XOR

  // pre-scaled clamp bounds: sig2*inv2l = log2e/2, nine*inv2l = 9*log2e/2 (head-independent)
  const float C1 = 0.72134752f, C2 = 6.49212769f;

  const int tid = threadIdx.x, w = tid >> 6, lane = tid & 63;
  const int lr = lane & 15, lg = lane >> 4;
  // XCD-locality swizzle (index-only): each XCD owns 2 (b,h) pairs, 32 i-blocks each.
  const int L = blockIdx.x;
  const int xcd = L & 7, ix = L >> 3;          // ix in [0,64)
  const int pair = xcd*2 + (ix >> 5);          // [0,16)
  const int b = pair >> 3, h = pair & 7, i0 = (ix & 31) * 64;
  const float inv2l = sa.inv2l[h];

  // Q fragments (B-operand; col=lr, k=lg*8+e)
  long qrow = (long)(b*2048 + i0 + w*16 + lr) * 512 + h*64;
  bf16x8 qhi[2], qlo[2];
  #pragma unroll
  for(int ks=0; ks<2; ks++){
    qhi[ks] = *(const bf16x8*)(qhHi + qrow + ks*32 + lg*8);
    qlo[ks] = *(const bf16x8*)(qhLo + qrow + ks*32 + lg*8);
  }
  // ci B-fragment for d^2 MFMA: col=lr -> q-row lr; k-groups (lg&1)==0 -> hi, ==1 -> lo
  bf16x8 ciB;
  #pragma unroll
  for(int i=0;i<8;i++) ciB[i] = 0;
  float nis;  // |ci|^2 * inv2l of q-row lr
  {
    long cb = (long)(b*2048 + i0 + w*16 + lr)*3;
    float c0 = coords[cb], c1 = coords[cb+1], c2 = coords[cb+2];
    float cs[3] = {c0, c1, c2};
    #pragma unroll
    for(int e=0;e<3;e++){
      short chi = f2bf(cs[e]);
      short clo = f2bf(cs[e] - bf2f(chi));
      ciB[e] = ((lg & 1) == 0) ? chi : clo;
    }
    nis = (c0*c0 + c1*c1 + c2*c2) * inv2l;
  }
  // ---- loop-invariant staging pointers / LDS offsets ----
  const short* pKh[2]; const short* pKl[2]; const short* pVt[2];
  #pragma unroll
  for(int it=0; it<2; ++it){
    int u = tid + it*256;
    int row = u >> 3, cc = u & 7;
    int cs = cc ^ (row & 7);
    pKh[it] = khHi + (long)(b*2048 + row)*512 + h*64 + cs*8;
    pKl[it] = khLo + (long)(b*2048 + row)*512 + h*64 + cs*8;
    pVt[it] = vt + (((long)((b*8+h)*64 + row)) << 11) + cs*8;
  }
  const float* pCo = coords + (long)(b*2048 + tid)*3;
  const unsigned char* pKp = kpm + b*2048 + tid;
  int ko[2];
  #pragma unroll
  for(int ks=0; ks<2; ks++)
    ko[ks] = lr*64 + (((ks*4 + lg) ^ (lr & 7)) << 3);   // + jf*1024 (K) / + cf*1024 (V) at use
  const int cjo = lr*8 + (lg >> 1)*4;                   // + jf*128 at use (8-short rows)
  int pwo[4];
  #pragma unroll
  for(int jf=0;jf<4;jf++)
    pwo[jf] = lr*64 + (((jf*2 + (lg >> 1)) ^ (lr & 7)) << 3) + (lg & 1)*4;
  int pro[2];
  #pragma unroll
  for(int js=0;js<2;js++)
    pro[js] = lr*64 + (((js*4 + lg) ^ (lr & 7)) << 3);

  f32x4 oacc[4];
  for(int c=0;c<4;c++) oacc[c] = f32x4{0.f,0.f,0.f,0.f};
  float m = -1e30f, l = 0.f;

  for(int jt=0; jt<32; jt++){
    // async staging (r10-proven mapping): LDS dest linear, source col inverse-swizzled
    #pragma unroll
    for(int it=0; it<2; ++it){
      int u8 = (tid + it*256)*8;
      GLOAD_LDS16(pKh[it], sKhi + u8);
      GLOAD_LDS16(pKl[it], sKlo + u8);
      GLOAD_LDS16(pVt[it], sV + u8);
      pKh[it] += 64*512; pKl[it] += 64*512; pVt[it] += 64;
    }
    if(tid < 64){
      float cx = pCo[0], cy = pCo[1], cz = pCo[2];
      float sc = -2.f * inv2l;
      float mx = sc*cx, my = sc*cy, mz = sc*cz;
      short hx = f2bf(mx), hy = f2bf(my), hz = f2bf(mz);
      bf16x8 pk;
      pk[0] = hx; pk[1] = hy; pk[2] = hz; pk[3] = 0;
      pk[4] = f2bf(mx - bf2f(hx));
      pk[5] = f2bf(my - bf2f(hy));
      pk[6] = f2bf(mz - bf2f(hz));
      pk[7] = 0;
      *(bf16x8*)(sCjPk + tid*8) = pk;
      sNj[tid] = (cx*cx + cy*cy + cz*cz) * inv2l + (pKp[0] ? 1e37f : 0.f);
    }
    pCo += 64*3; pKp += 64;
    __syncthreads();

    // S^T via swapped MFMA: s[jf][r] = S[k = jf*16 + lg*4 + r][q = lr]
    f32x4 s[4];
    __builtin_amdgcn_s_setprio(1);
    #pragma unroll
    for(int jf=0;jf<4;jf++){
      f32x4 t = f32x4{0.f,0.f,0.f,0.f};
      #pragma unroll
      for(int ks=0;ks<2;ks++){
        bf16x8 bh = *(const bf16x8*)(sKhi + ko[ks] + jf*1024);
        bf16x8 bl = *(const bf16x8*)(sKlo + ko[ks] + jf*1024);
        t = MFMA16(bh, qhi[ks], t);
        t = MFMA16(bl, qhi[ks], t);
        t = MFMA16(bh, qlo[ks], t);
      }
      s[jf] = t;
    }
    __builtin_amdgcn_s_setprio(0);
    // d2' = d^2*inv2l via swapped MFMA: (nis+njs) + (-2cj*inv2l)·ci; then RBF with const bounds
    #pragma unroll
    for(int jf=0;jf<4;jf++){
      bf16x8 cjA;
      #pragma unroll
      for(int i=0;i<8;i++) cjA[i] = 0;
      {
        short4v c4 = *(const short4v*)(sCjPk + cjo + jf*128);
        cjA[0] = c4[0]; cjA[1] = c4[1]; cjA[2] = c4[2];
      }
      f32x4 nj4 = *(const f32x4*)(sNj + jf*16 + lg*4);
      f32x4 cin;
      #pragma unroll
      for(int r=0;r<4;r++) cin[r] = nis + nj4[r];
      f32x4 d2t = MFMA16(cjA, ciB, cin);
      #pragma unroll
      for(int r=0;r<4;r++){
        float d2 = d2t[r];
        float arg2 = __builtin_amdgcn_fmed3f(d2, C1, C2);
        float sv = s[jf][r];
        sv *= EXP2F(-__builtin_copysignf(arg2, sv));
        if(d2 > C2) sv = -1e30f;
        s[jf][r] = sv;
      }
    }
    // scalar online softmax for q = lr (values spread over {jf,r} regs and lg-lanes)
    float pm = s[0][0];
    #pragma unroll
    for(int jf=0;jf<4;jf++)
      #pragma unroll
      for(int r=0;r<4;r++) pm = fmaxf(pm, s[jf][r]);
    pm = fmaxf(pm, __shfl_xor(pm, 16));
    pm = fmaxf(pm, __shfl_xor(pm, 32));
    float mn = fmaxf(m, pm);
    float fr = EXP2F(m - mn);
    m = mn;
    float ps = 0.f;
    #pragma unroll
    for(int jf=0;jf<4;jf++)
      #pragma unroll
      for(int r=0;r<4;r++){
        float p = EXP2F(s[jf][r] - m);
        s[jf][r] = p;
        ps += p;
      }
    ps += __shfl_xor(ps, 16);
    ps += __shfl_xor(ps, 32);
    l = l*fr + ps;
    // rescale oacc rows (q = lg*4 + r): fetch fr of those q's
    float frq[4];
    #pragma unroll
    for(int r=0;r<4;r++) frq[r] = __shfl(fr, lg*4 + r);
    #pragma unroll
    for(int c=0;c<4;c++)
      #pragma unroll
      for(int r=0;r<4;r++) oacc[c][r] *= frq[r];
    // P -> sP[q][k] with the proven 16B-chunk XOR swizzle (8B halves)
    #pragma unroll
    for(int jf=0;jf<4;jf++){
      uint2v wds;
      wds.x = cvtpk_bf16(s[jf][0], s[jf][1]);
      wds.y = cvtpk_bf16(s[jf][2], s[jf][3]);
      *(uint2v*)(&sP[w][pwo[jf]]) = wds;
    }
    // PV: A = P (rows q) read with matching swizzle, B = V^T
    __builtin_amdgcn_s_setprio(1);
    #pragma unroll
    for(int js=0;js<2;js++){
      bf16x8 pa = *(const bf16x8*)(&sP[w][pro[js]]);
      #pragma unroll
      for(int cf=0; cf<4; cf++){
        bf16x8 vb = *(const bf16x8*)(sV + ko[js] + cf*1024);
        oacc[cf] = MFMA16(pa, vb, oacc[cf]);
      }
    }
    __builtin_amdgcn_s_setprio(0);
    __syncthreads();
  }
  // epilogue: X[b*2048+i][h*64+c] hi/lo split; 1/l broadcast for q = lg*4+r
  float rl = 1.f / l;
  float lq[4];
  #pragma unroll
  for(int r=0;r<4;r++) lq[r] = __shfl(rl, lg*4 + r);
  #pragma unroll
  for(int cf=0; cf<4; cf++){
    #pragma unroll
    for(int r=0;r<4;r++){
      float v = oacc[cf][r] * lq[r];
      long idx = (long)(b*2048 + i0 + w*16 + lg*4 + r)*512 + h*64 + cf*16 + lr;
      short hh = f2bf(v);
      Xhi[idx] = hh;
      Xlo[idx] = f2bf(v - bf2f(hh));
    }
  }
}

// ---------------- host ----------------
extern "C" void kernel_launch(void* const* d_in, const int* in_sizes, int n_in,
                              void* d_out, int out_size, void* d_ws, size_t ws_size,
                              hipStream_t stream){
  const float* q  = (const float*)d_in[0];
  const float* k  = (const float*)d_in[1];
  const float* v  = (const float*)d_in[2];
  const float* coords = (const float*)d_in[3];
  const unsigned char* kpm = (const unsigned char*)d_in[4];
  const float* qp = (const float*)d_in[5];
  const float* kp = (const float*)d_in[6];
  const float* vp = (const float*)d_in[7];
  const float* ow = (const float*)d_in[8];
  const float* ob = (const float*)d_in[9];
  float* out = (float*)d_out;

  char* ws = (char*)d_ws;
  const size_t S = (size_t)4096*512*2;      // one bf16 [4096][512] plane
  const size_t P = (size_t)512*512*2;       // one bf16 [512][512] plane
  if(ws_size < 12*S + 7*P) return;
  short* q_hi = (short*)(ws + 0*S);
  short* q_lo = (short*)(ws + 1*S);
  short* k_hi = (short*)(ws + 2*S);
  short* k_lo = (short*)(ws + 3*S);
  short* v_hi = (short*)(ws + 4*S);
  short* qhHi = (short*)(ws + 5*S);
  short* qhLo = (short*)(ws + 6*S);
  short* khHi = (short*)(ws + 7*S);
  short* khLo = (short*)(ws + 8*S);
  short* vt   = (short*)(ws + 9*S);
  short* Xhi  = (short*)(ws + 10*S);
  short* Xlo  = (short*)(ws + 11*S);
  char* ws2 = ws + 12*S;
  short* BqHi = (short*)(ws2 + 0*P);
  short* BqLo = (short*)(ws2 + 1*P);
  short* BkHi = (short*)(ws2 + 2*P);
  short* BkLo = (short*)(ws2 + 3*P);
  short* BvHi = (short*)(ws2 + 4*P);
  short* WHi  = (short*)(ws2 + 5*P);
  short* WLo  = (short*)(ws2 + 6*P);

  SpreadArgs sa;
  for(int hh=0; hh<8; hh++){
    double t  = (1.0 - 0.02) * (double)hh / 7.0;
    double lg = pow(20.0, t);
    double sp = 3.7 + (lg - 1.0) / 19.0 * (20.0 - 3.7);
    float spf = (float)sp;
    sa.inv2l[hh] = 1.44269504f/(2.f*spf*spf);
  }

  const int NQ = 4096*512;
  split3<<<dim3(NQ/1024, 3), dim3(256), 0, stream>>>(q, k, v, q_hi, q_lo, k_hi, k_lo, v_hi);
  split_proj4<<<dim3(1024, 4), dim3(256), 0, stream>>>(qp, kp, vp, ow,
      BqHi, BqLo, BkHi, BkLo, BvHi, WHi, WLo);

  gemm_qkv<<<dim3(32, 8, 3), dim3(256), 0, stream>>>(
      q_hi, q_lo, k_hi, k_lo, v_hi,
      BqHi, BqLo, BkHi, BkLo, BvHi,
      qhHi, qhLo, khHi, khLo, vt);

  attn_k<<<dim3(512), dim3(256), 0, stream>>>(qhHi, qhLo, khHi, khLo, vt,
        coords, kpm, Xhi, Xlo, sa);

  gemm_k<3,2><<<dim3(32, 8), dim3(256), 0, stream>>>(Xhi, Xlo, WHi, WLo,
        nullptr, nullptr, out, ob, 1.f);
}